// Round 21
// baseline (495.912 us; speedup 1.0000x reference)
//
#include <hip/hip_runtime.h>
#include <stdint.h>
#include <string.h>
#include <math.h>

// ---------------------------------------------------------------------------
// IAF_PointNetFeaturePropagation: bf16-MFMA fused GEMM chain + split flash attn.
// B=4, N=8192, S=2048, K=20, D1=D2=256, CO=128, CLS=21, H=1638+409=2047
// ---------------------------------------------------------------------------

namespace {

constexpr int BB   = 4;
constexpr int NN   = 8192;
constexpr int SS   = 2048;
constexpr int KNB  = 20;
constexpr int CO   = 128;
constexpr int CLS  = 21;
constexpr int HH   = 2047;
constexpr int OUTER= 1638;
constexpr int INNER= 409;

typedef unsigned short u16;
typedef short bf8 __attribute__((ext_vector_type(8)));   // 8 bf16 in 4 VGPRs
typedef float f4  __attribute__((ext_vector_type(4)));   // MFMA accumulator

__device__ inline u16 f2bf(float f) {                    // round-nearest-even
  uint32_t x = __float_as_uint(f);
  return (u16)((x + 0x7FFFu + ((x >> 16) & 1u)) >> 16);
}
__device__ inline float bf2f(u16 v) {
  return __uint_as_float((uint32_t)v << 16);
}

// ======================= numpy default_rng(0).choice(8192,409) on the HOST
struct InnerArgs { int v[INNER]; };

static void compute_inner_host(int* out) {
  uint32_t pool[4];
  uint32_t hc = 0x43b0d7e5u;
  auto hashmix = [&hc](uint32_t v) -> uint32_t {
    v ^= hc; hc *= 0x931e8875u; v *= hc; v ^= v >> 16; return v;
  };
  auto mixf = [](uint32_t x, uint32_t y) -> uint32_t {
    uint32_t r = x * 0xca01f9ddu; r ^= y * 0x4973f715u; r ^= r >> 16; return r;
  };
  pool[0] = hashmix(0u); pool[1] = hashmix(0u);
  pool[2] = hashmix(0u); pool[3] = hashmix(0u);
  for (int s = 0; s < 4; ++s)
    for (int d = 0; d < 4; ++d)
      if (s != d) pool[d] = mixf(pool[d], hashmix(pool[s]));

  uint32_t st32[8];
  uint32_t hb = 0x8b51f9ddu;
  for (int i = 0; i < 8; ++i) {
    uint32_t dv = pool[i & 3];
    dv ^= hb; hb *= 0x58f38dedu; dv *= hb; dv ^= dv >> 16;
    st32[i] = dv;
  }
  uint64_t s64[4];
  for (int i = 0; i < 4; ++i)
    s64[i] = (uint64_t)st32[2*i] | ((uint64_t)st32[2*i+1] << 32);

  typedef unsigned __int128 u128;
  const u128 MUL = ((u128)2549297995355413924ull << 64) | (u128)4865540595714422341ull;
  u128 inc   = (((((u128)s64[2]) << 64) | (u128)s64[3]) << 1) | 1;
  u128 state = inc;
  state += (((u128)s64[0]) << 64) | (u128)s64[1];
  state = state * MUL + inc;

  bool has32 = false; uint32_t buf32 = 0;
  auto next32 = [&]() -> uint32_t {
    if (has32) { has32 = false; return buf32; }
    state = state * MUL + inc;
    uint64_t hi = (uint64_t)(state >> 64), lo = (uint64_t)state;
    uint64_t x = hi ^ lo;
    unsigned rot = (unsigned)(state >> 122);
    uint64_t v = (x >> rot) | (x << ((64u - rot) & 63u));
    has32 = true; buf32 = (uint32_t)(v >> 32);
    return (uint32_t)v;
  };

  uint64_t hs[512];
  memset(hs, 0xFF, sizeof(hs));
  for (int j = NN - INNER; j < NN; ++j) {
    uint32_t rng = (uint32_t)j, rng_excl = rng + 1u;
    uint64_t m = (uint64_t)next32() * (uint64_t)rng_excl;
    uint32_t leftover = (uint32_t)m;
    if (leftover < rng_excl) {
      uint32_t threshold = (0xFFFFFFFFu - rng) % rng_excl;
      while (leftover < threshold) {
        m = (uint64_t)next32() * (uint64_t)rng_excl;
        leftover = (uint32_t)m;
      }
    }
    uint64_t val = m >> 32;
    uint32_t loc = (uint32_t)val & 511u;
    while (hs[loc] != ~0ull && hs[loc] != val) loc = (loc + 1u) & 511u;
    uint64_t chosen;
    if (hs[loc] == ~0ull) { hs[loc] = val; chosen = val; }
    else                  { hs[loc] = (uint64_t)j; chosen = (uint64_t)j; }
    out[j - (NN - INNER)] = (int)chosen;
  }
}

// ======================= weight f32 -> bf16 descriptor
struct WcvP { const float* src; u16* dst; int rows; int K; int Kpad; };
struct WcvAll { WcvP e[8]; };

// ======================= merged prep: transpose2 | tcvt | wcvt (one dispatch)
__global__ __launch_bounds__(256) void prep1_k(const float* __restrict__ points2,
                                               float* __restrict__ p2t,
                                               const float* __restrict__ points1,
                                               u16* __restrict__ A0,
                                               WcvAll wa) {
  const int t = blockIdx.x;
  const int tid = threadIdx.x;
  __shared__ float sh[64][33];
  if (t < 2048) {
    const int b = t >> 9, rest = t & 511;
    const int c0 = (rest & 63) * 32, r0 = (rest >> 6) * 32;
    const float* ib = points2 + (size_t)b * 256 * SS;
    float*       ob = p2t    + (size_t)b * SS * 256;
    const int tx = tid & 31, ty = tid >> 5;
    #pragma unroll
    for (int i = 0; i < 32; i += 8)
      sh[ty + i][tx] = ib[(size_t)(r0 + ty + i) * SS + c0 + tx];
    __syncthreads();
    #pragma unroll
    for (int i = 0; i < 32; i += 8)
      ob[(size_t)(c0 + ty + i) * 256 + r0 + tx] = sh[tx][ty + i];
  } else if (t < 6144) {
    const int u = t - 2048;
    const int b = u >> 10, c0 = ((u >> 8) & 3) * 64, n0 = (u & 255) * 32;
    {
      const int tn = tid & 31, tc0 = tid >> 5;
      #pragma unroll
      for (int i = 0; i < 8; ++i) {
        const int c = tc0 * 8 + i;
        sh[c][tn] = points1[((size_t)b * 256 + c0 + c) * NN + n0 + tn];
      }
    }
    __syncthreads();
    {
      const int cg = tid & 7, n = tid >> 3;
      u16 tmp[8];
      #pragma unroll
      for (int j = 0; j < 8; ++j) tmp[j] = f2bf(sh[cg * 8 + j][n]);
      *(bf8*)&A0[((size_t)b * NN + n0 + n) * 512 + c0 + cg * 8] = *(bf8*)tmp;
    }
  } else {
    const int w = t - 6144;
    WcvP p = wa.e[w >> 5];
    const int xb = w & 31;
    const int total = p.rows * p.Kpad;
    for (int i = xb * 256 + tid; i < total; i += 32 * 256) {
      const int r = i / p.Kpad, k = i - r * p.Kpad;
      p.dst[i] = (k < p.K) ? f2bf(p.src[(size_t)r * p.K + k]) : (u16)0;
    }
  }
}

// ======================= fused 3-NN + interpolation (16 points per block)
__global__ __launch_bounds__(256) void knn_interp_k(const float* __restrict__ xyz1,
                                                    const float* __restrict__ xyz2,
                                                    const float* __restrict__ p2t,
                                                    const float* __restrict__ lastpred,
                                                    u16* __restrict__ A0,
                                                    float* __restrict__ preds) {
  __shared__ float4 P2[SS];
  __shared__ int   sidx[16][3];
  __shared__ float sw[16][3];
  const int b = blockIdx.y;
  const float* x2 = xyz2 + (size_t)b * SS * 3;
  for (int i = threadIdx.x; i < SS; i += 256) {
    float x = x2[i*3], y = x2[i*3+1], z = x2[i*3+2];
    P2[i] = make_float4(x, y, z, x*x + y*y + z*z);
  }
  __syncthreads();
  const int tid   = threadIdx.x;
  const int chunk = tid & 15;
  const int pt    = tid >> 4;
  const int n     = blockIdx.x * 16 + pt;
  const float* p  = xyz1 + ((size_t)b * NN + n) * 3;
  const float px = p[0], py = p[1], pz = p[2];
  const float ss1 = px*px + py*py + pz*pz;
  float d0 = 3.4e38f, d1 = 3.4e38f, d2 = 3.4e38f;
  int   i0 = 0, i1 = 0, i2 = 0;
  auto ins = [&](float d, int s) {
    const bool c0 = d < d0, c1 = d < d1, c2 = d < d2;
    const float nd0 = c0 ? d  : d0;
    const int   nj0 = c0 ? s  : i0;
    const float nd1 = c0 ? d0 : (c1 ? d : d1);
    const int   nj1 = c0 ? i0 : (c1 ? s : i1);
    const float nd2 = c1 ? d1 : (c2 ? d : d2);
    const int   nj2 = c1 ? i1 : (c2 ? s : i2);
    d0 = nd0; d1 = nd1; d2 = nd2;
    i0 = nj0; i1 = nj1; i2 = nj2;
  };
  #pragma unroll 8
  for (int i = 0; i < 128; ++i) {
    const int s = chunk + (i << 4);
    const float4 q = P2[s];
    float d = (ss1 + q.w) - 2.0f * (px*q.x + py*q.y + pz*q.z);
    ins(d, s);
  }
  #pragma unroll
  for (int off = 1; off <= 8; off <<= 1) {
    float e0 = __shfl_xor(d0, off), e1 = __shfl_xor(d1, off), e2 = __shfl_xor(d2, off);
    int   j0 = __shfl_xor(i0, off), j1 = __shfl_xor(i1, off), j2 = __shfl_xor(i2, off);
    ins(e0, j0); ins(e1, j1); ins(e2, j2);
  }
  if (chunk == 0) {
    d0 = fmaxf(d0, 1e-10f); d1 = fmaxf(d1, 1e-10f); d2 = fmaxf(d2, 1e-10f);
    float w0 = 1.f/d0, w1 = 1.f/d1, w2 = 1.f/d2;
    float ws = w0 + w1 + w2;
    sidx[pt][0] = i0; sidx[pt][1] = i1; sidx[pt][2] = i2;
    sw[pt][0] = w0/ws; sw[pt][1] = w1/ws; sw[pt][2] = w2/ws;
  }
  __syncthreads();

  const int n0 = blockIdx.x * 16;
  const float* pb = p2t + (size_t)b * SS * 256;
  const float* lp = lastpred + (size_t)b * SS * CLS;
  const int c = tid;
  #pragma unroll 4
  for (int q = 0; q < 16; ++q) {
    const size_t o = (size_t)b * NN + n0 + q;
    const int j0 = sidx[q][0], j1 = sidx[q][1], j2 = sidx[q][2];
    const float w0 = sw[q][0], w1 = sw[q][1], w2 = sw[q][2];
    const float v = w0 * pb[(size_t)j0*256 + c]
                  + w1 * pb[(size_t)j1*256 + c]
                  + w2 * pb[(size_t)j2*256 + c];
    A0[o*512 + 256 + c] = f2bf(v);
    if (c < CLS)
      preds[o*CLS + c] = w0 * lp[j0*CLS + c] + w1 * lp[j1*CLS + c] + w2 * lp[j2*CLS + c];
  }
}

// ======================= bf16 MFMA GEMM, 128x128 tile, T14 reg-prefetch staging
struct MgP {
  const u16* A; const u16* W;
  const float* bias; const float* bng; const float* bnb; const float* res;
  void* C; float* C2;
  int M, Nc, K, act, omode;
};

__global__ __launch_bounds__(256) void mgemm_k(MgP p) {
  __shared__ u16 As[128 * 64];
  __shared__ u16 Ws[128 * 64];
  const int tid = threadIdx.x;
  const int wave = tid >> 6, lane = tid & 63;
  const int l15 = lane & 15, l4 = lane >> 4;
  const int wr = wave >> 1, wc = wave & 1;
  const int bm = blockIdx.y * 128, bn = blockIdx.x * 128;
  const int srow = tid >> 3, sch = tid & 7;

  f4 acc[4][4];
  #pragma unroll
  for (int i = 0; i < 4; ++i)
    #pragma unroll
    for (int j = 0; j < 4; ++j) acc[i][j] = (f4){0.f, 0.f, 0.f, 0.f};

  bf8 vA[4], vB[4];
  auto loadT = [&](int k0) {
    #pragma unroll
    for (int it = 0; it < 4; ++it) {
      const int r = srow + it * 32;
      const int gm = bm + r;
      bf8 va = {0,0,0,0,0,0,0,0};
      if (gm < p.M) va = *(const bf8*)(p.A + (size_t)gm * p.K + k0 + sch * 8);
      vA[it] = va;
      const int gn = bn + r;
      bf8 vb = {0,0,0,0,0,0,0,0};
      if (gn < p.Nc) vb = *(const bf8*)(p.W + (size_t)gn * p.K + k0 + sch * 8);
      vB[it] = vb;
    }
  };
  auto writeT = [&]() {
    #pragma unroll
    for (int it = 0; it < 4; ++it) {
      const int r = srow + it * 32;
      *(bf8*)&As[r * 64 + ((sch ^ (r & 7)) << 3)] = vA[it];
      *(bf8*)&Ws[r * 64 + ((sch ^ (r & 7)) << 3)] = vB[it];
    }
  };

  loadT(0);
  for (int k0 = 0; k0 < p.K; k0 += 64) {
    __syncthreads();
    writeT();
    if (k0 + 64 < p.K) loadT(k0 + 64);
    __syncthreads();
    #pragma unroll
    for (int ks = 0; ks < 2; ++ks) {
      bf8 af[4], bf[4];
      #pragma unroll
      for (int mf = 0; mf < 4; ++mf) {
        int m = wr * 64 + mf * 16 + l15;
        af[mf] = *(const bf8*)&As[m * 64 + (((ks * 4 + l4) ^ (m & 7)) << 3)];
      }
      #pragma unroll
      for (int nf = 0; nf < 4; ++nf) {
        int n = wc * 64 + nf * 16 + l15;
        bf[nf] = *(const bf8*)&Ws[n * 64 + (((ks * 4 + l4) ^ (n & 7)) << 3)];
      }
      #pragma unroll
      for (int mf = 0; mf < 4; ++mf)
        #pragma unroll
        for (int nf = 0; nf < 4; ++nf)
          acc[mf][nf] = __builtin_amdgcn_mfma_f32_16x16x32_bf16(af[mf], bf[nf], acc[mf][nf], 0, 0, 0);
    }
  }

  const float bnden = sqrtf(1.0f + 1e-5f);
  #pragma unroll
  for (int mf = 0; mf < 4; ++mf) {
    #pragma unroll
    for (int i = 0; i < 4; ++i) {
      const int r = bm + wr * 64 + mf * 16 + l4 * 4 + i;
      if (r >= p.M) continue;
      #pragma unroll
      for (int nf = 0; nf < 4; ++nf) {
        const int c = bn + wc * 64 + nf * 16 + l15;
        float v = acc[mf][nf][i];
        if (p.bias) v += p.bias[c];
        if (p.bng)  v = v * (p.bng[c] / bnden) + p.bnb[c];
        if (p.res)  v += p.res[(size_t)r * p.Nc + c];
        if (p.act == 1)      v = fmaxf(v, 0.f);
        else if (p.act == 2) v = (v >= 0.f) ? v : 0.2f * v;
        if (p.omode == 0) {
          ((float*)p.C)[(size_t)r * p.Nc + c] = v;
        } else if (p.omode == 1) {
          ((u16*)p.C)[(size_t)r * p.Nc + c] = f2bf(v);
        } else {
          const int bb = r / HH, rr = r - bb * HH;
          ((u16*)p.C)[((size_t)(bb * p.Nc + c)) * 2048 + rr] = f2bf(v);
        }
        if (p.C2) p.C2[(size_t)r * p.Nc + c] = v;
      }
    }
  }
}

// ======================= two-stage fused bf16 GEMM (Nc=128 both stages)
// Stage-1 staging uses T14 register prefetch; A sources: plain / combA / gatherA.
// tailfuse: after stage-2 (n2==1), compute h5+logits+log_softmax in-block
// (replaces tail_k; npo buffer eliminated).
struct S2d { const u16* W; const float* bias; const float* bng; const float* bnb;
             int act; int omode; void* C; float* Ct; };
struct Mg2P {
  const u16* A; const u16* W;
  const float* bias; const float* bng; const float* bnb; const float* res;
  void* C1; float* C2f;
  const u16* ypA; const float2* mlA; int combA;
  const u16* gxtb; const float* gpreds; const int* gHidx; int gatherA;
  int M, K, act, writeC1, n2;
  S2d s2[2];
  // tail fusion (h5 + logits + log_softmax)
  const float *tw5, *tb5, *tg5, *tbe5, *tw6, *tb6;
  float* tout1;
  int tailfuse;
};

__global__ __launch_bounds__(256) void mgemm2_k(Mg2P p) {
  // SM layout: As[0:8192) | Ws[8192:16384) | T1s half0 [16384:24576) | half1 [24576:32768)
  // tail reuse: W5s f32 over As (16KB); Hs bf16 [128][128] over T1s (32KB)
  __shared__ u16 SM[4 * 128 * 64];
  __shared__ float cw[128][2];
  __shared__ float W6s[CLS * 32];
  u16* const As = SM;
  u16* const Ws = SM + 8192;
  const int tid = threadIdx.x;
  const int wave = tid >> 6, lane = tid & 63;
  const int l15 = lane & 15, l4 = lane >> 4;
  const int wr = wave >> 1, wc = wave & 1;
  const int bm = blockIdx.y * 128;
  const int srow = tid >> 3, sch = tid & 7;

  if (p.combA) {
    if (tid < 128) {
      const int gm = bm + tid;
      const float2 a0 = p.mlA[gm];
      const float2 a1 = p.mlA[(size_t)BB * NN + gm];
      const float mm = fmaxf(a0.x, a1.x);
      const float w0 = __expf(a0.x - mm);
      const float w1 = __expf(a1.x - mm);
      const float inv = 1.0f / (w0 * a0.y + w1 * a1.y);
      cw[tid][0] = w0 * inv;
      cw[tid][1] = w1 * inv;
    }
    __syncthreads();   // cw visible before prefetch reads it
  }

  f4 acc[4][4];
  #pragma unroll
  for (int i = 0; i < 4; ++i)
    #pragma unroll
    for (int j = 0; j < 4; ++j) acc[i][j] = (f4){0.f, 0.f, 0.f, 0.f};

  bf8 vA[4], vB[4];
  auto loadT = [&](int k0) {
    #pragma unroll
    for (int it = 0; it < 4; ++it) {
      const int r = srow + it * 32;
      const int gm = bm + r;
      bf8 va = {0,0,0,0,0,0,0,0};
      if (gm < p.M) {
        if (p.combA) {
          const float w0 = cw[r][0], w1 = cw[r][1];
          const bf8 y0 = *(const bf8*)(p.ypA + (size_t)gm * 128 + k0 + sch * 8);
          const bf8 y1 = *(const bf8*)(p.ypA + ((size_t)BB * NN + gm) * 128 + k0 + sch * 8);
          u16 tmp[8];
          #pragma unroll
          for (int j = 0; j < 8; ++j)
            tmp[j] = f2bf(w0 * bf2f(((const u16*)&y0)[j]) +
                          w1 * bf2f(((const u16*)&y1)[j]));
          va = *(bf8*)tmp;
        } else if (p.gatherA) {
          const int gb = gm / HH, gh = gm - gb * HH;
          const int src = p.gHidx[gb * HH + gh];
          const size_t sr = (size_t)gb * NN + src;
          const int colbase = k0 + sch * 8;
          if (colbase < CO) {
            va = *(const bf8*)(p.gxtb + sr * CO + colbase);
          } else {
            u16 tmp[8];
            #pragma unroll
            for (int j = 0; j < 8; ++j) {
              const int col = colbase + j;
              tmp[j] = (col < CO + CLS) ? f2bf(p.gpreds[sr * CLS + (col - CO)]) : (u16)0;
            }
            va = *(bf8*)tmp;
          }
        } else {
          va = *(const bf8*)(p.A + (size_t)gm * p.K + k0 + sch * 8);
        }
      }
      vA[it] = va;
      vB[it] = *(const bf8*)(p.W + (size_t)r * p.K + k0 + sch * 8);
    }
  };
  auto writeT = [&]() {
    #pragma unroll
    for (int it = 0; it < 4; ++it) {
      const int r = srow + it * 32;
      *(bf8*)&As[r * 64 + ((sch ^ (r & 7)) << 3)] = vA[it];
      *(bf8*)&Ws[r * 64 + ((sch ^ (r & 7)) << 3)] = vB[it];
    }
  };

  loadT(0);
  for (int k0 = 0; k0 < p.K; k0 += 64) {
    __syncthreads();
    writeT();
    if (k0 + 64 < p.K) loadT(k0 + 64);
    __syncthreads();
    #pragma unroll
    for (int ks = 0; ks < 2; ++ks) {
      bf8 af[4], bf[4];
      #pragma unroll
      for (int mf = 0; mf < 4; ++mf) {
        int m = wr * 64 + mf * 16 + l15;
        af[mf] = *(const bf8*)&As[m * 64 + (((ks * 4 + l4) ^ (m & 7)) << 3)];
      }
      #pragma unroll
      for (int nf = 0; nf < 4; ++nf) {
        int n = wc * 64 + nf * 16 + l15;
        bf[nf] = *(const bf8*)&Ws[n * 64 + (((ks * 4 + l4) ^ (n & 7)) << 3)];
      }
      #pragma unroll
      for (int mf = 0; mf < 4; ++mf)
        #pragma unroll
        for (int nf = 0; nf < 4; ++nf)
          acc[mf][nf] = __builtin_amdgcn_mfma_f32_16x16x32_bf16(af[mf], bf[nf], acc[mf][nf], 0, 0, 0);
    }
  }

  const float bnden = sqrtf(1.0f + 1e-5f);
  #pragma unroll
  for (int mf = 0; mf < 4; ++mf) {
    #pragma unroll
    for (int i = 0; i < 4; ++i) {
      const int rl = wr * 64 + mf * 16 + l4 * 4 + i;
      const int r  = bm + rl;
      #pragma unroll
      for (int nf = 0; nf < 4; ++nf) {
        const int c  = wc * 64 + nf * 16 + l15;
        float v = acc[mf][nf][i];
        if (p.bias) v += p.bias[c];
        if (p.bng)  v = v * (p.bng[c] / bnden) + p.bnb[c];
        if (p.res && r < p.M) v += p.res[(size_t)r * 128 + c];
        if (p.act == 1)      v = fmaxf(v, 0.f);
        else if (p.act == 2) v = (v >= 0.f) ? v : 0.2f * v;
        if (r < p.M) {
          if (p.writeC1) ((u16*)p.C1)[(size_t)r * 128 + c] = f2bf(v);
          if (p.C2f)     p.C2f[(size_t)r * 128 + c] = v;
        }
        const int cl = c & 63;
        SM[16384 + wc * 8192 + rl * 64 + (((cl >> 3) ^ (rl & 7)) << 3) + (cl & 7)] = f2bf(v);
      }
    }
  }

  for (int s = 0; s < p.n2; ++s) {
    const S2d q = p.s2[s];
    #pragma unroll
    for (int i = 0; i < 4; ++i)
      #pragma unroll
      for (int j = 0; j < 4; ++j) acc[i][j] = (f4){0.f, 0.f, 0.f, 0.f};
    for (int k0 = 0; k0 < 128; k0 += 64) {
      __syncthreads();
      #pragma unroll
      for (int it = 0; it < 4; ++it) {
        int id = it * 256 + tid;
        int r = id >> 3, ch = id & 7;
        bf8 vb = *(const bf8*)(q.W + (size_t)r * 128 + k0 + ch * 8);
        *(bf8*)&Ws[r * 64 + ((ch ^ (r & 7)) << 3)] = vb;
      }
      __syncthreads();
      #pragma unroll
      for (int ks = 0; ks < 2; ++ks) {
        bf8 af[4], bf[4];
        #pragma unroll
        for (int mf = 0; mf < 4; ++mf) {
          int m = wr * 64 + mf * 16 + l15;
          af[mf] = *(const bf8*)&SM[16384 + (k0 >> 6) * 8192 + m * 64 + (((ks * 4 + l4) ^ (m & 7)) << 3)];
        }
        #pragma unroll
        for (int nf = 0; nf < 4; ++nf) {
          int n = wc * 64 + nf * 16 + l15;
          bf[nf] = *(const bf8*)&Ws[n * 64 + (((ks * 4 + l4) ^ (n & 7)) << 3)];
        }
        #pragma unroll
        for (int mf = 0; mf < 4; ++mf)
          #pragma unroll
          for (int nf = 0; nf < 4; ++nf)
            acc[mf][nf] = __builtin_amdgcn_mfma_f32_16x16x32_bf16(af[mf], bf[nf], acc[mf][nf], 0, 0, 0);
      }
    }
    // tail prep: wait for all T1s reads, then stage w5/w6 into dead LDS
    if (p.tailfuse) {
      __syncthreads();
      float* W5L = (float*)SM;                  // 32x128 f32 over As region
      for (int i = tid; i < 32 * 128; i += 256) W5L[i] = p.tw5[i];
      for (int i = tid; i < CLS * 32; i += 256) W6s[i] = p.tw6[i];
    }
    #pragma unroll
    for (int mf = 0; mf < 4; ++mf) {
      #pragma unroll
      for (int i = 0; i < 4; ++i) {
        const int rl = wr * 64 + mf * 16 + l4 * 4 + i;
        const int r  = bm + rl;
        if (r >= p.M) continue;
        #pragma unroll
        for (int nf = 0; nf < 4; ++nf) {
          const int c = wc * 64 + nf * 16 + l15;
          float v = acc[mf][nf][i];
          if (q.bias) v += q.bias[c];
          if (q.bng)  v = v * (q.bng[c] / bnden) + q.bnb[c];
          if (q.act == 1)      v = fmaxf(v, 0.f);
          else if (q.act == 2) v = (v >= 0.f) ? v : 0.2f * v;
          if (q.omode == 0) {
            if (q.C) ((float*)q.C)[(size_t)r * 128 + c] = v;
          } else if (q.omode == 1) {
            ((u16*)q.C)[(size_t)r * 128 + c] = f2bf(v);
          } else {
            const int bb = r / HH, rr = r - bb * HH;
            ((u16*)q.C)[((size_t)(bb * 128 + c)) * 2048 + rr] = f2bf(v);
          }
          if (q.Ct) {
            const int bb = r >> 13, rr = r & (NN - 1);
            q.Ct[((size_t)(bb * 128 + c)) * NN + rr] = v;
          }
          if (p.tailfuse) {   // stash npo row (bf16, 4-bit swizzle) into Hs
            SM[16384 + rl * 128 + ((((c >> 3) ^ (rl & 15)) & 15) << 3) + (c & 7)] = f2bf(v);
          }
        }
      }
    }
  }

  // ===== fused tail: h5 + logits + log_softmax (2 threads per row) =====
  if (p.tailfuse) {
    __syncthreads();
    const u16* Hs = SM + 16384;          // [128][128] bf16 swizzled
    const float* W5L = (const float*)SM; // 32x128 f32
    const int tr = tid >> 1;
    const int jg = (tid & 1) * 16;
    float a[16];
    #pragma unroll
    for (int jj = 0; jj < 16; ++jj) a[jj] = 0.f;
    for (int c0 = 0; c0 < 128; c0 += 8) {
      const int sw = (((c0 >> 3) ^ (tr & 15)) & 15) << 3;
      const bf8 hx = *(const bf8*)&Hs[tr * 128 + sw];
      float xf[8];
      #pragma unroll
      for (int j = 0; j < 8; ++j) xf[j] = bf2f(((const u16*)&hx)[j]);
      #pragma unroll
      for (int jj = 0; jj < 16; ++jj) {
        const float4 w0 = *(const float4*)&W5L[(jg + jj) * 128 + c0];
        const float4 w1 = *(const float4*)&W5L[(jg + jj) * 128 + c0 + 4];
        a[jj] += xf[0]*w0.x + xf[1]*w0.y + xf[2]*w0.z + xf[3]*w0.w
               + xf[4]*w1.x + xf[5]*w1.y + xf[6]*w1.z + xf[7]*w1.w;
      }
    }
    float h[16];
    #pragma unroll
    for (int jj = 0; jj < 16; ++jj) {
      const int j = jg + jj;
      float v = a[jj] + p.tb5[j];
      v = v * (p.tg5[j] / bnden) + p.tbe5[j];
      h[jj] = fmaxf(v, 0.f);
    }
    float lg[CLS];
    float mx = -3.4e38f;
    #pragma unroll
    for (int o = 0; o < CLS; ++o) {
      float sp = (jg == 0) ? p.tb6[o] : 0.f;
      #pragma unroll
      for (int jj = 0; jj < 16; ++jj) sp += W6s[o * 32 + jg + jj] * h[jj];
      sp += __shfl_xor(sp, 1);
      lg[o] = sp;
      mx = fmaxf(mx, sp);
    }
    float se = 0.f;
    #pragma unroll
    for (int o = 0; o < CLS; ++o) se += __expf(lg[o] - mx);
    const float lse = mx + __logf(se);
    if ((tid & 1) == 0) {
      float* orow = p.tout1 + (size_t)(bm + tr) * CLS;
      #pragma unroll
      for (int o = 0; o < CLS; ++o) orow[o] = lg[o] - lse;
    }
  }
}

// ======================= bf16-MFMA flash attention, KV-split by blockIdx.z
// QBLK=64, z=2; lazy-max + deferred sum + setprio + T14 register prefetch.
// Writes UNNORMALIZED acc; normalization folded into combA weights.
// NOTE: P-pack uses manual-RNE f2bf — inline-asm v_cvt_pk_bf16_f32 corrupted
// out0 (R20: absmax 0.073; suspected operand-order/rounding mismatch).
__global__ __launch_bounds__(256) void attn_mfma_k(
    const u16* __restrict__ thetab,   // (B*N,128) bf16 rm
    const u16* __restrict__ phib,     // (B*H,128) bf16 rm
    const u16* __restrict__ gxT,      // (B,128,2048) bf16 (col 2047 junk)
    u16* __restrict__ yp,             // (2, B*N, 128) bf16 partials (unnormalized)
    float2* __restrict__ ml)          // (2, B*N) (m, l)
{
  __shared__ u16 Kt[64 * 128];
  __shared__ u16 Vt[128 * 64];
  __shared__ u16 Pt[64 * 64];
  const int b    = blockIdx.y;
  const int z    = blockIdx.z;
  const int row0 = blockIdx.x * 64;
  const int tid  = threadIdx.x;
  const int wave = tid >> 6;
  const int lane = tid & 63;
  const int l15  = lane & 15, l4 = lane >> 4;

  bf8 aq[4];
  {
    const u16* tq = thetab + ((size_t)(b * NN + row0 + wave * 16 + l15)) * 128;
    #pragma unroll
    for (int ks = 0; ks < 4; ++ks)
      aq[ks] = *(const bf8*)(tq + ks * 32 + l4 * 8);
  }

  f4 acc[8];
  #pragma unroll
  for (int i = 0; i < 8; ++i) acc[i] = (f4){0.f, 0.f, 0.f, 0.f};
  float mrow[4] = {-3e38f, -3e38f, -3e38f, -3e38f};
  float lrow[4] = {0.f, 0.f, 0.f, 0.f};   // per-lane partials

  const u16* phbase = phib + (size_t)b * HH * 128;
  const u16* gxbase = gxT  + (size_t)b * 128 * 2048;

  const int krow = tid >> 4, kch = tid & 15;
  const int vcol = tid >> 3, vch = tid & 7;

  bf8 kreg[4], vreg[4];
  auto loadregs = [&](int h0) {
    #pragma unroll
    for (int it = 0; it < 4; ++it) {
      const int r  = krow + it * 16;
      const int gp = h0 + r;
      bf8 vv = {0,0,0,0,0,0,0,0};
      if (gp < HH) vv = *(const bf8*)(phbase + (size_t)gp * 128 + kch * 8);
      kreg[it] = vv;
    }
    #pragma unroll
    for (int it = 0; it < 4; ++it) {
      const int c = vcol + it * 32;
      vreg[it] = *(const bf8*)(gxbase + (size_t)c * 2048 + h0 + vch * 8);
    }
  };
  auto writeLDS = [&]() {
    #pragma unroll
    for (int it = 0; it < 4; ++it) {
      const int r = krow + it * 16;
      *(bf8*)&Kt[r * 128 + ((kch ^ (r & 7)) << 3)] = kreg[it];
    }
    #pragma unroll
    for (int it = 0; it < 4; ++it) {
      const int c = vcol + it * 32;
      *(bf8*)&Vt[c * 64 + ((vch ^ (c & 7)) << 3)] = vreg[it];
    }
  };

  const int hbeg = z * 1024, hend = hbeg + 1024;
  loadregs(hbeg);
  for (int h0 = hbeg; h0 < hend; h0 += 64) {
    __syncthreads();
    writeLDS();
    if (h0 + 64 < hend) loadregs(h0 + 64);
    __syncthreads();

    f4 sacc[4];
    #pragma unroll
    for (int t = 0; t < 4; ++t) sacc[t] = (f4){0.f, 0.f, 0.f, 0.f};
    __builtin_amdgcn_s_setprio(1);
    #pragma unroll
    for (int ks = 0; ks < 4; ++ks) {
      #pragma unroll
      for (int t = 0; t < 4; ++t) {
        const int pr = t * 16 + l15;
        const int ch = (ks * 4 + l4) ^ (pr & 7);
        bf8 bk = *(const bf8*)&Kt[pr * 128 + ch * 8];
        sacc[t] = __builtin_amdgcn_mfma_f32_16x16x32_bf16(aq[ks], bk, sacc[t], 0, 0, 0);
      }
    }
    __builtin_amdgcn_s_setprio(0);
    if (h0 + 64 > HH) {
      #pragma unroll
      for (int t = 0; t < 4; ++t)
        if (h0 + t * 16 + l15 >= HH)
          sacc[t] = (f4){-3e38f, -3e38f, -3e38f, -3e38f};
    }

    // ---- lazy max
    float tl[4];
    #pragma unroll
    for (int r = 0; r < 4; ++r)
      tl[r] = fmaxf(fmaxf(sacc[0][r], sacc[1][r]), fmaxf(sacc[2][r], sacc[3][r]));
    const bool grow = (tl[0] > mrow[0]) | (tl[1] > mrow[1]) |
                      (tl[2] > mrow[2]) | (tl[3] > mrow[3]);
    if (__any(grow)) {
      #pragma unroll
      for (int r = 0; r < 4; ++r) {
        float tm = tl[r];
        tm = fmaxf(tm, __shfl_xor(tm, 1));
        tm = fmaxf(tm, __shfl_xor(tm, 2));
        tm = fmaxf(tm, __shfl_xor(tm, 4));
        tm = fmaxf(tm, __shfl_xor(tm, 8));
        const float mn = fmaxf(mrow[r], tm);
        const float sc = __expf(mrow[r] - mn);
        mrow[r] = mn;
        lrow[r] *= sc;
        #pragma unroll
        for (int ct = 0; ct < 8; ++ct) acc[ct][r] *= sc;
      }
    }
    // ---- exp + per-lane partial sum + P write (manual RNE pack)
    #pragma unroll
    for (int r = 0; r < 4; ++r) {
      float e[4];
      float ps = 0.f;
      #pragma unroll
      for (int t = 0; t < 4; ++t) {
        e[t] = __expf(sacc[t][r] - mrow[r]);
        ps += e[t];
      }
      lrow[r] += ps;
      const int prow = wave * 16 + l4 * 4 + r;
      #pragma unroll
      for (int t = 0; t < 4; ++t) {
        const int col = t * 16 + l15;
        const int scol = (((col >> 3) ^ (prow & 7)) << 3) | (col & 7);
        Pt[prow * 64 + scol] = f2bf(e[t]);
      }
    }

    __builtin_amdgcn_s_setprio(1);
    #pragma unroll
    for (int ks = 0; ks < 2; ++ks) {
      const int prow2 = wave * 16 + l15;
      bf8 pa = *(const bf8*)&Pt[prow2 * 64 + (((ks * 4 + l4) ^ (prow2 & 7)) << 3)];
      #pragma unroll
      for (int ct = 0; ct < 8; ++ct) {
        const int c  = ct * 16 + l15;
        const int ch = (ks * 4 + l4) ^ (c & 7);
        bf8 bv = *(const bf8*)&Vt[c * 64 + ch * 8];
        acc[ct] = __builtin_amdgcn_mfma_f32_16x16x32_bf16(pa, bv, acc[ct], 0, 0, 0);
      }
    }
    __builtin_amdgcn_s_setprio(0);
  }

  // final sum reduce (once) -- l needed for the combine denominator
  #pragma unroll
  for (int r = 0; r < 4; ++r) {
    float lr = lrow[r];
    lr += __shfl_xor(lr, 1); lr += __shfl_xor(lr, 2);
    lr += __shfl_xor(lr, 4); lr += __shfl_xor(lr, 8);
    lrow[r] = lr;
  }

  const size_t rbase = (size_t)z * BB * NN + (size_t)b * NN + row0 + wave * 16 + l4 * 4;
  u16* yo = yp + rbase * 128;
  #pragma unroll
  for (int r = 0; r < 4; ++r) {
    #pragma unroll
    for (int ct = 0; ct < 8; ++ct)
      yo[(size_t)r * 128 + ct * 16 + l15] = f2bf(acc[ct][r]);
    if (l15 == 0) ml[rbase + r] = make_float2(mrow[r], lrow[r]);
  }
}

// ======================= diff[b,n] = sum_k sum_c (flat[idx1]-xt)^2
// 8 points per 256-thread block; 32 lanes/point; uint2 (8B) loads.
__global__ __launch_bounds__(256) void diff_k(const u16* __restrict__ xtb,
                                              const int* __restrict__ idx1,
                                              float* __restrict__ diff) {
  const int tid = threadIdx.x;
  const int sub = tid >> 5, ln = tid & 31;
  const int bn  = blockIdx.x * 8 + sub;
  const uint2 xcp = *(const uint2*)(xtb + (size_t)bn * CO + ln * 4);
  const float x0 = bf2f((u16)(xcp.x & 0xFFFFu)), x1 = bf2f((u16)(xcp.x >> 16));
  const float x2 = bf2f((u16)(xcp.y & 0xFFFFu)), x3 = bf2f((u16)(xcp.y >> 16));
  const int* id = idx1 + (size_t)bn * KNB;
  float acc = 0.f;
  #pragma unroll 4
  for (int k = 0; k < KNB; ++k) {
    const int ix = id[k];
    const uint2 vp = *(const uint2*)(xtb + (size_t)ix * CO + ln * 4);
    const float d0 = bf2f((u16)(vp.x & 0xFFFFu)) - x0;
    const float d1 = bf2f((u16)(vp.x >> 16))     - x1;
    const float d2 = bf2f((u16)(vp.y & 0xFFFFu)) - x2;
    const float d3 = bf2f((u16)(vp.y >> 16))     - x3;
    acc += d0*d0 + d1*d1 + d2*d2 + d3*d3;
  }
  #pragma unroll
  for (int o = 1; o <= 16; o <<= 1) acc += __shfl_xor(acc, o);
  if (ln == 0) diff[bn] = acc;
}

// ======================= per-batch top-1638 SET via 4-round radix select
__global__ __launch_bounds__(1024) void topsel_k(const float* __restrict__ diff,
                                                 InnerArgs ia,
                                                 int* __restrict__ Hidx) {
  __shared__ uint32_t hist[256];
  __shared__ uint32_t sh_T, sh_need, sh_cnt, sh_eqc;
  __shared__ int      sh_eq[1024];
  const int b = blockIdx.x, tid = threadIdx.x;
  const float* db = diff + (size_t)b * NN;
  uint32_t v[8];
  #pragma unroll
  for (int i = 0; i < 8; ++i) v[i] = __float_as_uint(db[tid * 8 + i]);
  if (tid == 0) { sh_T = 0u; sh_need = OUTER; sh_cnt = 0u; sh_eqc = 0u; }
  #pragma unroll
  for (int round = 0; round < 4; ++round) {
    const int shift = 24 - 8 * round;
    for (int i = tid; i < 256; i += 1024) hist[i] = 0u;
    __syncthreads();
    const uint32_t Tpart  = sh_T;
    const uint32_t maskHi = (round == 0) ? 0u : (0xFFFFFFFFu << (shift + 8));
    #pragma unroll
    for (int i = 0; i < 8; ++i)
      if ((v[i] & maskHi) == (Tpart & maskHi))
        atomicAdd(&hist[(v[i] >> shift) & 255u], 1u);
    __syncthreads();
    if (tid == 0) {
      uint32_t need = sh_need, accn = 0u;
      int bsel = 0;
      for (int bin = 255; bin >= 0; --bin) {
        uint32_t h = hist[bin];
        if (accn + h >= need) { bsel = bin; break; }
        accn += h;
      }
      sh_T = Tpart | ((uint32_t)bsel << shift);
      sh_need = need - accn;
    }
    __syncthreads();
  }
  const uint32_t T   = sh_T;
  const uint32_t rem = sh_need;
  #pragma unroll
  for (int i = 0; i < 8; ++i) {
    const int idx = tid * 8 + i;
    if (v[i] > T) {
      uint32_t pos = atomicAdd(&sh_cnt, 1u);
      Hidx[b * HH + pos] = idx;
    } else if (v[i] == T) {
      uint32_t e = atomicAdd(&sh_eqc, 1u);
      if (e < 1024u) sh_eq[e] = idx;
    }
  }
  __syncthreads();
  if (tid == 0) {
    const uint32_t C = sh_cnt;
    uint32_t eqc = sh_eqc < 1024u ? sh_eqc : 1024u;
    for (uint32_t j = 0; j < rem && j < eqc; ++j) {
      int best = 0x7fffffff, bi = 0;
      for (uint32_t t = 0; t < eqc; ++t)
        if (sh_eq[t] < best) { best = sh_eq[t]; bi = (int)t; }
      Hidx[b * HH + C + j] = best;
      sh_eq[bi] = 0x7fffffff;
    }
  }
  if (tid < INNER) Hidx[b * HH + OUTER + tid] = ia.v[tid];
}

} // anonymous namespace

// ===========================================================================
extern "C" void kernel_launch(void* const* d_in, const int* in_sizes, int n_in,
                              void* d_out, int out_size, void* d_ws, size_t ws_size,
                              hipStream_t stream) {
  const float* xyz1    = (const float*)d_in[0];
  const float* xyz2    = (const float*)d_in[1];
  const float* points1 = (const float*)d_in[2];
  const float* points2 = (const float*)d_in[3];
  const float* lastpred= (const float*)d_in[5];
  const float* w_mlp0  = (const float*)d_in[6];
  const float* b_mlp0  = (const float*)d_in[7];
  const float* g_bn0   = (const float*)d_in[8];
  const float* be_bn0  = (const float*)d_in[9];
  const float* w_mlp1  = (const float*)d_in[10];
  const float* b_mlp1  = (const float*)d_in[11];
  const float* g_bn1   = (const float*)d_in[12];
  const float* be_bn1  = (const float*)d_in[13];
  const float* w_h     = (const float*)d_in[14];
  const float* g_hbn   = (const float*)d_in[15];
  const float* be_hbn  = (const float*)d_in[16];
  const float* w_outm  = (const float*)d_in[17];
  const float* g_obn   = (const float*)d_in[18];
  const float* be_obn  = (const float*)d_in[19];
  const float* w_g     = (const float*)d_in[20];
  const float* b_g     = (const float*)d_in[21];
  const float* w_theta = (const float*)d_in[22];
  const float* b_theta = (const float*)d_in[23];
  const float* w_phi   = (const float*)d_in[24];
  const float* b_phi   = (const float*)d_in[25];
  const float* w_W     = (const float*)d_in[26];
  const float* b_W     = (const float*)d_in[27];
  const float* g_Wbn   = (const float*)d_in[28];
  const float* be_Wbn  = (const float*)d_in[29];
  const float* w5      = (const float*)d_in[30];
  const float* b5      = (const float*)d_in[31];
  const float* g_bn5   = (const float*)d_in[32];
  const float* be_bn5  = (const float*)d_in[33];
  const float* w6      = (const float*)d_in[34];
  const float* b6      = (const float*)d_in[35];
  const int*   idx_1   = (const int*)d_in[36];

  float* out0 = (float*)d_out;
  float* out1 = out0 + (size_t)BB * CO * NN;

  char* base = (char*)d_ws;
  size_t off = 0;
  auto alloc = [&](size_t bytes) -> char* {
    char* p = base + off;
    off += (bytes + 255) & ~(size_t)255;
    return p;
  };
  float* diff   = (float*)alloc((size_t)BB * NN * 4);
  int*   Hidx   = (int*)  alloc((size_t)BB * HH * 4);
  float* preds  = (float*)alloc((size_t)BB * NN * CLS * 4);
  float* xt     = (float*)alloc((size_t)BB * NN * CO * 4);
  u16*   xtb    = (u16*)  alloc((size_t)BB * NN * CO * 2);
  u16*   phib   = (u16*)  alloc((size_t)BB * HH * CO * 2);
  u16*   gxT    = (u16*)  alloc((size_t)BB * CO * 2048 * 2);
  float2* mlbuf = (float2*)alloc((size_t)2 * BB * NN * 8);
  u16*   wbuf   = (u16*)  alloc((size_t)270336 * 2);
  char*  R1     =         alloc((size_t)BB * NN * 512 * 2);     // 33.5MB
  char*  R2     =         alloc((size_t)BB * NN * 256 * 2);     // 16MB
  if (off > ws_size) return;   // insufficient scratch (diagnostic)

  // weight bf16 buffers inside wbuf
  u16* w0b = wbuf;                 // 256x512
  u16* w1b = w0b + 256 * 512;      // 128x256
  u16* whb = w1b + 128 * 256;      // 128x192 (149 padded)
  u16* wgb = whb + 128 * 192;      // 128x128
  u16* wtb = wgb + 128 * 128;
  u16* wpb = wtb + 128 * 128;
  u16* wWb = wpb + 128 * 128;
  u16* wob = wWb + 128 * 128;

  // region aliases (lifetimes disjoint)
  u16*   A0     = (u16*)R1;                                     // prep..mlp0
  u16*   thetab = (u16*)R1;                                     // mlp1..attn (8MB)
  u16*   yp     = (u16*)(R1 + (size_t)8 * 1024 * 1024);         // attn..Wgemm (16MB)
  float* p2t    = (float*)R2;                                   // prep..knn_interp (8MB)
  u16*   x2b    = (u16*)R2;                                     // mlp0..mlp1 (16MB)

  // host RNG for inner indices (baked into topsel kernargs)
  InnerArgs ia;
  compute_inner_host(ia.v);

  // 1. merged prep: points2 transpose + points1 cvt + weight cvt
  {
    WcvAll wa;
    wa.e[0] = {w_mlp0, w0b, 256, 512, 512};
    wa.e[1] = {w_mlp1, w1b, 128, 256, 256};
    wa.e[2] = {w_h,    whb, 128, 149, 192};
    wa.e[3] = {w_g,    wgb, 128, 128, 128};
    wa.e[4] = {w_theta,wtb, 128, 128, 128};
    wa.e[5] = {w_phi,  wpb, 128, 128, 128};
    wa.e[6] = {w_W,    wWb, 128, 128, 128};
    wa.e[7] = {w_outm, wob, 128, 128, 128};
    prep1_k<<<6400, 256, 0, stream>>>(points2, p2t, points1, A0, wa);
  }

  // 2. fused 3-NN + interpolation -> A0 cols 256..511 (bf16) + preds f32
  knn_interp_k<<<dim3(NN/16, BB), 256, 0, stream>>>(xyz1, xyz2, p2t, lastpred, A0, preds);

  // 3. mlp0: relu(bn0(W0·A0 + b0)) -> x2b bf16
  {
    MgP p{};
    p.A = A0; p.W = w0b; p.bias = b_mlp0; p.bng = g_bn0; p.bnb = be_bn0;
    p.C = x2b; p.M = BB * NN; p.Nc = 256; p.K = 512; p.act = 1; p.omode = 1;
    mgemm_k<<<dim3(2, 256), 256, 0, stream>>>(p);
  }
  // 4. mlp1 (-> xtb bf16 + xt f32) fused with theta -> thetab
  {
    Mg2P p{};
    p.A = x2b; p.W = w1b; p.bias = b_mlp1; p.bng = g_bn1; p.bnb = be_bn1;
    p.C1 = xtb; p.writeC1 = 1; p.C2f = xt;
    p.M = BB * NN; p.K = 256; p.act = 1; p.n2 = 1;
    p.s2[0] = {wtb, b_theta, nullptr, nullptr, 0, 1, thetab, nullptr};
    mgemm2_k<<<dim3(1, 256), 256, 0, stream>>>(p);
  }

  // 5. KNN feature variance score (8 pts/block, 8B loads)
  diff_k<<<BB * NN / 8, 256, 0, stream>>>(xtb, idx_1, diff);

  // 6. per-batch top-1638 set via radix select (+ inner append from kernarg)
  topsel_k<<<BB, 1024, 0, stream>>>(diff, ia, Hidx);

  // 7. conv_h (A gathered via Hidx from xtb+preds) fused with g_x and phi
  {
    Mg2P p{};
    p.W = whb; p.bng = g_hbn; p.bnb = be_hbn;
    p.gxtb = xtb; p.gpreds = preds; p.gHidx = Hidx; p.gatherA = 1;
    p.writeC1 = 0; p.M = BB * HH; p.K = 192; p.act = 2; p.n2 = 2;
    p.s2[0] = {wgb, b_g,   nullptr, nullptr, 0, 2, gxT,  nullptr};
    p.s2[1] = {wpb, b_phi, nullptr, nullptr, 0, 1, phib, nullptr};
    mgemm2_k<<<dim3(1, 64), 256, 0, stream>>>(p);
  }

  // 8. MFMA flash attention, KV-split x2 -> unnormalized partials
  attn_mfma_k<<<dim3(NN/64, BB, 2), 256, 0, stream>>>(thetab, phib, gxT, yp, mlbuf);

  // 9. combine(yp) -> z = bn_W(W_W·y + b_W) + xt, fused with outm;
  // stage-2 writes out0 transposed + fused tail (h5+logits+log_softmax) -> out1.
  {
    Mg2P p{};
    p.W = wWb; p.bias = b_W; p.bng = g_Wbn; p.bnb = be_Wbn; p.res = xt;
    p.ypA = yp; p.mlA = mlbuf; p.combA = 1;
    p.writeC1 = 0; p.M = BB * NN; p.K = 128; p.act = 0; p.n2 = 1;
    p.s2[0] = {wob, nullptr, g_obn, be_obn, 2, 0, nullptr, out0};
    p.tw5 = w5; p.tb5 = b5; p.tg5 = g_bn5; p.tbe5 = be_bn5;
    p.tw6 = w6; p.tb6 = b6; p.tout1 = out1; p.tailfuse = 1;
    mgemm2_k<<<dim3(1, 256), 256, 0, stream>>>(p);
  }
}

// Round 23
// 474.970 us; speedup vs baseline: 1.0441x; 1.0441x over previous
//
#include <hip/hip_runtime.h>
#include <stdint.h>
#include <string.h>
#include <math.h>

// ---------------------------------------------------------------------------
// IAF_PointNetFeaturePropagation: bf16-MFMA fused GEMM chain + split flash attn.
// B=4, N=8192, S=2048, K=20, D1=D2=256, CO=128, CLS=21, H=1638+409=2047
// ---------------------------------------------------------------------------

namespace {

constexpr int BB   = 4;
constexpr int NN   = 8192;
constexpr int SS   = 2048;
constexpr int KNB  = 20;
constexpr int CO   = 128;
constexpr int CLS  = 21;
constexpr int HH   = 2047;
constexpr int OUTER= 1638;
constexpr int INNER= 409;

typedef unsigned short u16;
typedef short bf8 __attribute__((ext_vector_type(8)));   // 8 bf16 in 4 VGPRs
typedef float f4  __attribute__((ext_vector_type(4)));   // MFMA accumulator

__device__ inline u16 f2bf(float f) {                    // round-nearest-even
  uint32_t x = __float_as_uint(f);
  return (u16)((x + 0x7FFFu + ((x >> 16) & 1u)) >> 16);
}
__device__ inline float bf2f(u16 v) {
  return __uint_as_float((uint32_t)v << 16);
}

// ======================= numpy default_rng(0).choice(8192,409) on the HOST
struct InnerArgs { int v[INNER]; };

static void compute_inner_host(int* out) {
  uint32_t pool[4];
  uint32_t hc = 0x43b0d7e5u;
  auto hashmix = [&hc](uint32_t v) -> uint32_t {
    v ^= hc; hc *= 0x931e8875u; v *= hc; v ^= v >> 16; return v;
  };
  auto mixf = [](uint32_t x, uint32_t y) -> uint32_t {
    uint32_t r = x * 0xca01f9ddu; r ^= y * 0x4973f715u; r ^= r >> 16; return r;
  };
  pool[0] = hashmix(0u); pool[1] = hashmix(0u);
  pool[2] = hashmix(0u); pool[3] = hashmix(0u);
  for (int s = 0; s < 4; ++s)
    for (int d = 0; d < 4; ++d)
      if (s != d) pool[d] = mixf(pool[d], hashmix(pool[s]));

  uint32_t st32[8];
  uint32_t hb = 0x8b51f9ddu;
  for (int i = 0; i < 8; ++i) {
    uint32_t dv = pool[i & 3];
    dv ^= hb; hb *= 0x58f38dedu; dv *= hb; dv ^= dv >> 16;
    st32[i] = dv;
  }
  uint64_t s64[4];
  for (int i = 0; i < 4; ++i)
    s64[i] = (uint64_t)st32[2*i] | ((uint64_t)st32[2*i+1] << 32);

  typedef unsigned __int128 u128;
  const u128 MUL = ((u128)2549297995355413924ull << 64) | (u128)4865540595714422341ull;
  u128 inc   = (((((u128)s64[2]) << 64) | (u128)s64[3]) << 1) | 1;
  u128 state = inc;
  state += (((u128)s64[0]) << 64) | (u128)s64[1];
  state = state * MUL + inc;

  bool has32 = false; uint32_t buf32 = 0;
  auto next32 = [&]() -> uint32_t {
    if (has32) { has32 = false; return buf32; }
    state = state * MUL + inc;
    uint64_t hi = (uint64_t)(state >> 64), lo = (uint64_t)state;
    uint64_t x = hi ^ lo;
    unsigned rot = (unsigned)(state >> 122);
    uint64_t v = (x >> rot) | (x << ((64u - rot) & 63u));
    has32 = true; buf32 = (uint32_t)(v >> 32);
    return (uint32_t)v;
  };

  uint64_t hs[512];
  memset(hs, 0xFF, sizeof(hs));
  for (int j = NN - INNER; j < NN; ++j) {
    uint32_t rng = (uint32_t)j, rng_excl = rng + 1u;
    uint64_t m = (uint64_t)next32() * (uint64_t)rng_excl;
    uint32_t leftover = (uint32_t)m;
    if (leftover < rng_excl) {
      uint32_t threshold = (0xFFFFFFFFu - rng) % rng_excl;
      while (leftover < threshold) {
        m = (uint64_t)next32() * (uint64_t)rng_excl;
        leftover = (uint32_t)m;
      }
    }
    uint64_t val = m >> 32;
    uint32_t loc = (uint32_t)val & 511u;
    while (hs[loc] != ~0ull && hs[loc] != val) loc = (loc + 1u) & 511u;
    uint64_t chosen;
    if (hs[loc] == ~0ull) { hs[loc] = val; chosen = val; }
    else                  { hs[loc] = (uint64_t)j; chosen = (uint64_t)j; }
    out[j - (NN - INNER)] = (int)chosen;
  }
}

// ======================= weight f32 -> bf16 descriptor
struct WcvP { const float* src; u16* dst; int rows; int K; int Kpad; };
struct WcvAll { WcvP e[8]; };

// ======================= merged prep: transpose2 | tcvt | wcvt (one dispatch)
__global__ __launch_bounds__(256) void prep1_k(const float* __restrict__ points2,
                                               float* __restrict__ p2t,
                                               const float* __restrict__ points1,
                                               u16* __restrict__ A0,
                                               WcvAll wa) {
  const int t = blockIdx.x;
  const int tid = threadIdx.x;
  __shared__ float sh[64][33];
  if (t < 2048) {
    const int b = t >> 9, rest = t & 511;
    const int c0 = (rest & 63) * 32, r0 = (rest >> 6) * 32;
    const float* ib = points2 + (size_t)b * 256 * SS;
    float*       ob = p2t    + (size_t)b * SS * 256;
    const int tx = tid & 31, ty = tid >> 5;
    #pragma unroll
    for (int i = 0; i < 32; i += 8)
      sh[ty + i][tx] = ib[(size_t)(r0 + ty + i) * SS + c0 + tx];
    __syncthreads();
    #pragma unroll
    for (int i = 0; i < 32; i += 8)
      ob[(size_t)(c0 + ty + i) * 256 + r0 + tx] = sh[tx][ty + i];
  } else if (t < 6144) {
    const int u = t - 2048;
    const int b = u >> 10, c0 = ((u >> 8) & 3) * 64, n0 = (u & 255) * 32;
    {
      const int tn = tid & 31, tc0 = tid >> 5;
      #pragma unroll
      for (int i = 0; i < 8; ++i) {
        const int c = tc0 * 8 + i;
        sh[c][tn] = points1[((size_t)b * 256 + c0 + c) * NN + n0 + tn];
      }
    }
    __syncthreads();
    {
      const int cg = tid & 7, n = tid >> 3;
      u16 tmp[8];
      #pragma unroll
      for (int j = 0; j < 8; ++j) tmp[j] = f2bf(sh[cg * 8 + j][n]);
      *(bf8*)&A0[((size_t)b * NN + n0 + n) * 512 + c0 + cg * 8] = *(bf8*)tmp;
    }
  } else {
    const int w = t - 6144;
    WcvP p = wa.e[w >> 5];
    const int xb = w & 31;
    const int total = p.rows * p.Kpad;
    for (int i = xb * 256 + tid; i < total; i += 32 * 256) {
      const int r = i / p.Kpad, k = i - r * p.Kpad;
      p.dst[i] = (k < p.K) ? f2bf(p.src[(size_t)r * p.K + k]) : (u16)0;
    }
  }
}

// ======================= fused 3-NN + interpolation (16 points per block)
__global__ __launch_bounds__(256) void knn_interp_k(const float* __restrict__ xyz1,
                                                    const float* __restrict__ xyz2,
                                                    const float* __restrict__ p2t,
                                                    const float* __restrict__ lastpred,
                                                    u16* __restrict__ A0,
                                                    float* __restrict__ preds) {
  __shared__ float4 P2[SS];
  __shared__ int   sidx[16][3];
  __shared__ float sw[16][3];
  const int b = blockIdx.y;
  const float* x2 = xyz2 + (size_t)b * SS * 3;
  for (int i = threadIdx.x; i < SS; i += 256) {
    float x = x2[i*3], y = x2[i*3+1], z = x2[i*3+2];
    P2[i] = make_float4(x, y, z, x*x + y*y + z*z);
  }
  __syncthreads();
  const int tid   = threadIdx.x;
  const int chunk = tid & 15;
  const int pt    = tid >> 4;
  const int n     = blockIdx.x * 16 + pt;
  const float* p  = xyz1 + ((size_t)b * NN + n) * 3;
  const float px = p[0], py = p[1], pz = p[2];
  const float ss1 = px*px + py*py + pz*pz;
  float d0 = 3.4e38f, d1 = 3.4e38f, d2 = 3.4e38f;
  int   i0 = 0, i1 = 0, i2 = 0;
  auto ins = [&](float d, int s) {
    const bool c0 = d < d0, c1 = d < d1, c2 = d < d2;
    const float nd0 = c0 ? d  : d0;
    const int   nj0 = c0 ? s  : i0;
    const float nd1 = c0 ? d0 : (c1 ? d : d1);
    const int   nj1 = c0 ? i0 : (c1 ? s : i1);
    const float nd2 = c1 ? d1 : (c2 ? d : d2);
    const int   nj2 = c1 ? i1 : (c2 ? s : i2);
    d0 = nd0; d1 = nd1; d2 = nd2;
    i0 = nj0; i1 = nj1; i2 = nj2;
  };
  #pragma unroll 8
  for (int i = 0; i < 128; ++i) {
    const int s = chunk + (i << 4);
    const float4 q = P2[s];
    float d = (ss1 + q.w) - 2.0f * (px*q.x + py*q.y + pz*q.z);
    ins(d, s);
  }
  #pragma unroll
  for (int off = 1; off <= 8; off <<= 1) {
    float e0 = __shfl_xor(d0, off), e1 = __shfl_xor(d1, off), e2 = __shfl_xor(d2, off);
    int   j0 = __shfl_xor(i0, off), j1 = __shfl_xor(i1, off), j2 = __shfl_xor(i2, off);
    ins(e0, j0); ins(e1, j1); ins(e2, j2);
  }
  if (chunk == 0) {
    d0 = fmaxf(d0, 1e-10f); d1 = fmaxf(d1, 1e-10f); d2 = fmaxf(d2, 1e-10f);
    float w0 = 1.f/d0, w1 = 1.f/d1, w2 = 1.f/d2;
    float ws = w0 + w1 + w2;
    sidx[pt][0] = i0; sidx[pt][1] = i1; sidx[pt][2] = i2;
    sw[pt][0] = w0/ws; sw[pt][1] = w1/ws; sw[pt][2] = w2/ws;
  }
  __syncthreads();

  const int n0 = blockIdx.x * 16;
  const float* pb = p2t + (size_t)b * SS * 256;
  const float* lp = lastpred + (size_t)b * SS * CLS;
  const int c = tid;
  #pragma unroll 4
  for (int q = 0; q < 16; ++q) {
    const size_t o = (size_t)b * NN + n0 + q;
    const int j0 = sidx[q][0], j1 = sidx[q][1], j2 = sidx[q][2];
    const float w0 = sw[q][0], w1 = sw[q][1], w2 = sw[q][2];
    const float v = w0 * pb[(size_t)j0*256 + c]
                  + w1 * pb[(size_t)j1*256 + c]
                  + w2 * pb[(size_t)j2*256 + c];
    A0[o*512 + 256 + c] = f2bf(v);
    if (c < CLS)
      preds[o*CLS + c] = w0 * lp[j0*CLS + c] + w1 * lp[j1*CLS + c] + w2 * lp[j2*CLS + c];
  }
}

// ======================= bf16 MFMA GEMM, 128x128 tile, T14 reg-prefetch staging
struct MgP {
  const u16* A; const u16* W;
  const float* bias; const float* bng; const float* bnb; const float* res;
  void* C; float* C2;
  int M, Nc, K, act, omode;
};

__global__ __launch_bounds__(256) void mgemm_k(MgP p) {
  __shared__ u16 As[128 * 64];
  __shared__ u16 Ws[128 * 64];
  const int tid = threadIdx.x;
  const int wave = tid >> 6, lane = tid & 63;
  const int l15 = lane & 15, l4 = lane >> 4;
  const int wr = wave >> 1, wc = wave & 1;
  const int bm = blockIdx.y * 128, bn = blockIdx.x * 128;
  const int srow = tid >> 3, sch = tid & 7;

  f4 acc[4][4];
  #pragma unroll
  for (int i = 0; i < 4; ++i)
    #pragma unroll
    for (int j = 0; j < 4; ++j) acc[i][j] = (f4){0.f, 0.f, 0.f, 0.f};

  bf8 vA[4], vB[4];
  auto loadT = [&](int k0) {
    #pragma unroll
    for (int it = 0; it < 4; ++it) {
      const int r = srow + it * 32;
      const int gm = bm + r;
      bf8 va = {0,0,0,0,0,0,0,0};
      if (gm < p.M) va = *(const bf8*)(p.A + (size_t)gm * p.K + k0 + sch * 8);
      vA[it] = va;
      const int gn = bn + r;
      bf8 vb = {0,0,0,0,0,0,0,0};
      if (gn < p.Nc) vb = *(const bf8*)(p.W + (size_t)gn * p.K + k0 + sch * 8);
      vB[it] = vb;
    }
  };
  auto writeT = [&]() {
    #pragma unroll
    for (int it = 0; it < 4; ++it) {
      const int r = srow + it * 32;
      *(bf8*)&As[r * 64 + ((sch ^ (r & 7)) << 3)] = vA[it];
      *(bf8*)&Ws[r * 64 + ((sch ^ (r & 7)) << 3)] = vB[it];
    }
  };

  loadT(0);
  for (int k0 = 0; k0 < p.K; k0 += 64) {
    __syncthreads();
    writeT();
    if (k0 + 64 < p.K) loadT(k0 + 64);
    __syncthreads();
    #pragma unroll
    for (int ks = 0; ks < 2; ++ks) {
      bf8 af[4], bf[4];
      #pragma unroll
      for (int mf = 0; mf < 4; ++mf) {
        int m = wr * 64 + mf * 16 + l15;
        af[mf] = *(const bf8*)&As[m * 64 + (((ks * 4 + l4) ^ (m & 7)) << 3)];
      }
      #pragma unroll
      for (int nf = 0; nf < 4; ++nf) {
        int n = wc * 64 + nf * 16 + l15;
        bf[nf] = *(const bf8*)&Ws[n * 64 + (((ks * 4 + l4) ^ (n & 7)) << 3)];
      }
      #pragma unroll
      for (int mf = 0; mf < 4; ++mf)
        #pragma unroll
        for (int nf = 0; nf < 4; ++nf)
          acc[mf][nf] = __builtin_amdgcn_mfma_f32_16x16x32_bf16(af[mf], bf[nf], acc[mf][nf], 0, 0, 0);
    }
  }

  const float bnden = sqrtf(1.0f + 1e-5f);
  #pragma unroll
  for (int mf = 0; mf < 4; ++mf) {
    #pragma unroll
    for (int i = 0; i < 4; ++i) {
      const int r = bm + wr * 64 + mf * 16 + l4 * 4 + i;
      if (r >= p.M) continue;
      #pragma unroll
      for (int nf = 0; nf < 4; ++nf) {
        const int c = bn + wc * 64 + nf * 16 + l15;
        float v = acc[mf][nf][i];
        if (p.bias) v += p.bias[c];
        if (p.bng)  v = v * (p.bng[c] / bnden) + p.bnb[c];
        if (p.res)  v += p.res[(size_t)r * p.Nc + c];
        if (p.act == 1)      v = fmaxf(v, 0.f);
        else if (p.act == 2) v = (v >= 0.f) ? v : 0.2f * v;
        if (p.omode == 0) {
          ((float*)p.C)[(size_t)r * p.Nc + c] = v;
        } else if (p.omode == 1) {
          ((u16*)p.C)[(size_t)r * p.Nc + c] = f2bf(v);
        } else {
          const int bb = r / HH, rr = r - bb * HH;
          ((u16*)p.C)[((size_t)(bb * p.Nc + c)) * 2048 + rr] = f2bf(v);
        }
        if (p.C2) p.C2[(size_t)r * p.Nc + c] = v;
      }
    }
  }
}

// ======================= two-stage fused bf16 GEMM (Nc=128 both stages)
// TF=0: plain/gatherA variants (no tail) -- lean regalloc.
// TF=1: combA + tail fusion (h5+logits+log_softmax). Epilogue body = R21's
// verified scalar form (R22's restructure coincided with a replay-determinism
// failure; reverted).
struct S2d { const u16* W; const float* bias; const float* bng; const float* bnb;
             int act; int omode; void* C; float* Ct; };
struct Mg2P {
  const u16* A; const u16* W;
  const float* bias; const float* bng; const float* bnb; const float* res;
  void* C1; float* C2f;
  const u16* ypA; const float2* mlA; int combA;
  const u16* gxtb; const float* gpreds; const int* gHidx; int gatherA;
  int M, K, act, writeC1, n2;
  S2d s2[2];
  const float *tw5, *tb5, *tg5, *tbe5, *tw6, *tb6;
  float* tout1;
  int tailfuse;
};

template <int TF>
__global__ __launch_bounds__(256) void mgemm2_k(Mg2P p) {
  // SM: As[0:8192) | Ws[8192:16384) | T1s half0 [16384:24576) | half1 [24576:32768) (u16 idx)
  // TF=1 tail reuse: W5s f32 over As (16KB); Hs bf16 [128][128] over T1s (32KB)
  __shared__ u16 SM[4 * 128 * 64];
  __shared__ float XL[TF ? (256 + CLS * 32) : 1];   // cw[128][2] | W6s[CLS*32]
  float* const cw  = XL;
  float* const W6s = XL + 256;
  u16* const As = SM;
  u16* const Ws = SM + 8192;
  const int tid = threadIdx.x;
  const int wave = tid >> 6, lane = tid & 63;
  const int l15 = lane & 15, l4 = lane >> 4;
  const int wr = wave >> 1, wc = wave & 1;
  const int bm = blockIdx.y * 128;
  const int srow = tid >> 3, sch = tid & 7;

  if constexpr (TF) {
    if (p.combA) {
      if (tid < 128) {
        const int gm = bm + tid;
        const float2 a0 = p.mlA[gm];
        const float2 a1 = p.mlA[(size_t)BB * NN + gm];
        const float mm = fmaxf(a0.x, a1.x);
        const float w0 = __expf(a0.x - mm);
        const float w1 = __expf(a1.x - mm);
        const float inv = 1.0f / (w0 * a0.y + w1 * a1.y);
        cw[tid * 2 + 0] = w0 * inv;
        cw[tid * 2 + 1] = w1 * inv;
      }
      __syncthreads();   // cw visible before prefetch reads it
    }
  }

  f4 acc[4][4];
  #pragma unroll
  for (int i = 0; i < 4; ++i)
    #pragma unroll
    for (int j = 0; j < 4; ++j) acc[i][j] = (f4){0.f, 0.f, 0.f, 0.f};

  bf8 vA[4], vB[4];
  auto loadT = [&](int k0) {
    #pragma unroll
    for (int it = 0; it < 4; ++it) {
      const int r = srow + it * 32;
      const int gm = bm + r;
      bf8 va = {0,0,0,0,0,0,0,0};
      if (gm < p.M) {
        if constexpr (TF) {
          const float w0 = cw[r * 2 + 0], w1 = cw[r * 2 + 1];
          const bf8 y0 = *(const bf8*)(p.ypA + (size_t)gm * 128 + k0 + sch * 8);
          const bf8 y1 = *(const bf8*)(p.ypA + ((size_t)BB * NN + gm) * 128 + k0 + sch * 8);
          u16 tmp[8];
          #pragma unroll
          for (int j = 0; j < 8; ++j)
            tmp[j] = f2bf(w0 * bf2f(((const u16*)&y0)[j]) +
                          w1 * bf2f(((const u16*)&y1)[j]));
          va = *(bf8*)tmp;
        } else {
          if (p.gatherA) {
            const int gb = gm / HH, gh = gm - gb * HH;
            const int src = p.gHidx[gb * HH + gh];
            const size_t sr = (size_t)gb * NN + src;
            const int colbase = k0 + sch * 8;
            if (colbase < CO) {
              va = *(const bf8*)(p.gxtb + sr * CO + colbase);
            } else {
              u16 tmp[8];
              #pragma unroll
              for (int j = 0; j < 8; ++j) {
                const int col = colbase + j;
                tmp[j] = (col < CO + CLS) ? f2bf(p.gpreds[sr * CLS + (col - CO)]) : (u16)0;
              }
              va = *(bf8*)tmp;
            }
          } else {
            va = *(const bf8*)(p.A + (size_t)gm * p.K + k0 + sch * 8);
          }
        }
      }
      vA[it] = va;
      vB[it] = *(const bf8*)(p.W + (size_t)r * p.K + k0 + sch * 8);
    }
  };
  auto writeT = [&]() {
    #pragma unroll
    for (int it = 0; it < 4; ++it) {
      const int r = srow + it * 32;
      *(bf8*)&As[r * 64 + ((sch ^ (r & 7)) << 3)] = vA[it];
      *(bf8*)&Ws[r * 64 + ((sch ^ (r & 7)) << 3)] = vB[it];
    }
  };

  loadT(0);
  for (int k0 = 0; k0 < p.K; k0 += 64) {
    __syncthreads();
    writeT();
    if (k0 + 64 < p.K) loadT(k0 + 64);
    __syncthreads();
    #pragma unroll
    for (int ks = 0; ks < 2; ++ks) {
      bf8 af[4], bf[4];
      #pragma unroll
      for (int mf = 0; mf < 4; ++mf) {
        int m = wr * 64 + mf * 16 + l15;
        af[mf] = *(const bf8*)&As[m * 64 + (((ks * 4 + l4) ^ (m & 7)) << 3)];
      }
      #pragma unroll
      for (int nf = 0; nf < 4; ++nf) {
        int n = wc * 64 + nf * 16 + l15;
        bf[nf] = *(const bf8*)&Ws[n * 64 + (((ks * 4 + l4) ^ (n & 7)) << 3)];
      }
      #pragma unroll
      for (int mf = 0; mf < 4; ++mf)
        #pragma unroll
        for (int nf = 0; nf < 4; ++nf)
          acc[mf][nf] = __builtin_amdgcn_mfma_f32_16x16x32_bf16(af[mf], bf[nf], acc[mf][nf], 0, 0, 0);
    }
  }

  const float bnden = sqrtf(1.0f + 1e-5f);
  #pragma unroll
  for (int mf = 0; mf < 4; ++mf) {
    #pragma unroll
    for (int i = 0; i < 4; ++i) {
      const int rl = wr * 64 + mf * 16 + l4 * 4 + i;
      const int r  = bm + rl;
      #pragma unroll
      for (int nf = 0; nf < 4; ++nf) {
        const int c  = wc * 64 + nf * 16 + l15;
        float v = acc[mf][nf][i];
        if (p.bias) v += p.bias[c];
        if (p.bng)  v = v * (p.bng[c] / bnden) + p.bnb[c];
        if (p.res && r < p.M) v += p.res[(size_t)r * 128 + c];
        if (p.act == 1)      v = fmaxf(v, 0.f);
        else if (p.act == 2) v = (v >= 0.f) ? v : 0.2f * v;
        if (r < p.M) {
          if (p.writeC1) ((u16*)p.C1)[(size_t)r * 128 + c] = f2bf(v);
          if (p.C2f)     p.C2f[(size_t)r * 128 + c] = v;
        }
        const int cl = c & 63;
        SM[16384 + wc * 8192 + rl * 64 + (((cl >> 3) ^ (rl & 7)) << 3) + (cl & 7)] = f2bf(v);
      }
    }
  }

  for (int s = 0; s < p.n2; ++s) {
    const S2d q = p.s2[s];
    #pragma unroll
    for (int i = 0; i < 4; ++i)
      #pragma unroll
      for (int j = 0; j < 4; ++j) acc[i][j] = (f4){0.f, 0.f, 0.f, 0.f};
    for (int k0 = 0; k0 < 128; k0 += 64) {
      __syncthreads();
      #pragma unroll
      for (int it = 0; it < 4; ++it) {
        int id = it * 256 + tid;
        int r = id >> 3, ch = id & 7;
        bf8 vb = *(const bf8*)(q.W + (size_t)r * 128 + k0 + ch * 8);
        *(bf8*)&Ws[r * 64 + ((ch ^ (r & 7)) << 3)] = vb;
      }
      __syncthreads();
      #pragma unroll
      for (int ks = 0; ks < 2; ++ks) {
        bf8 af[4], bf[4];
        #pragma unroll
        for (int mf = 0; mf < 4; ++mf) {
          int m = wr * 64 + mf * 16 + l15;
          af[mf] = *(const bf8*)&SM[16384 + (k0 >> 6) * 8192 + m * 64 + (((ks * 4 + l4) ^ (m & 7)) << 3)];
        }
        #pragma unroll
        for (int nf = 0; nf < 4; ++nf) {
          int n = wc * 64 + nf * 16 + l15;
          bf[nf] = *(const bf8*)&Ws[n * 64 + (((ks * 4 + l4) ^ (n & 7)) << 3)];
        }
        #pragma unroll
        for (int mf = 0; mf < 4; ++mf)
          #pragma unroll
          for (int nf = 0; nf < 4; ++nf)
            acc[mf][nf] = __builtin_amdgcn_mfma_f32_16x16x32_bf16(af[mf], bf[nf], acc[mf][nf], 0, 0, 0);
      }
    }
    // tail prep (TF=1): wait for all T1s reads, then stage w5/w6 into dead LDS
    if constexpr (TF) {
      __syncthreads();
      float* W5L = (float*)SM;                  // 32x128 f32 over As region
      for (int i = tid; i < 32 * 128; i += 256) W5L[i] = p.tw5[i];
      for (int i = tid; i < CLS * 32; i += 256) W6s[i] = p.tw6[i];
    }
    #pragma unroll
    for (int mf = 0; mf < 4; ++mf) {
      #pragma unroll
      for (int i = 0; i < 4; ++i) {
        const int rl = wr * 64 + mf * 16 + l4 * 4 + i;
        const int r  = bm + rl;
        if (r >= p.M) continue;
        #pragma unroll
        for (int nf = 0; nf < 4; ++nf) {
          const int c = wc * 64 + nf * 16 + l15;
          float v = acc[mf][nf][i];
          if (q.bias) v += q.bias[c];
          if (q.bng)  v = v * (q.bng[c] / bnden) + q.bnb[c];
          if (q.act == 1)      v = fmaxf(v, 0.f);
          else if (q.act == 2) v = (v >= 0.f) ? v : 0.2f * v;
          if (q.omode == 0) {
            if (q.C) ((float*)q.C)[(size_t)r * 128 + c] = v;
          } else if (q.omode == 1) {
            ((u16*)q.C)[(size_t)r * 128 + c] = f2bf(v);
          } else {
            const int bb = r / HH, rr = r - bb * HH;
            ((u16*)q.C)[((size_t)(bb * 128 + c)) * 2048 + rr] = f2bf(v);
            // deterministically zero the padding column 2047 (read by attn,
            // masked by P=0; must not hold re-poisoned workspace junk)
            if (rr == HH - 1)
              ((u16*)q.C)[((size_t)(bb * 128 + c)) * 2048 + HH] = (u16)0;
          }
          if (q.Ct) {
            const int bb = r >> 13, rr = r & (NN - 1);
            q.Ct[((size_t)(bb * 128 + c)) * NN + rr] = v;
          }
          if constexpr (TF) {   // stash npo row (bf16, 4-bit swizzle) into Hs
            SM[16384 + rl * 128 + ((((c >> 3) ^ (rl & 15)) & 15) << 3) + (c & 7)] = f2bf(v);
          }
        }
      }
    }
  }

  // ===== fused tail: h5 + logits + log_softmax (2 threads per row) =====
  if constexpr (TF) {
    __syncthreads();
    const u16* Hs = SM + 16384;          // [128][128] bf16 swizzled
    const float* W5L = (const float*)SM; // 32x128 f32
    const int tr = tid >> 1;
    const int jg = (tid & 1) * 16;
    float a[16];
    #pragma unroll
    for (int jj = 0; jj < 16; ++jj) a[jj] = 0.f;
    for (int c0 = 0; c0 < 128; c0 += 8) {
      const int sw = (((c0 >> 3) ^ (tr & 15)) & 15) << 3;
      const bf8 hx = *(const bf8*)&Hs[tr * 128 + sw];
      float xf[8];
      #pragma unroll
      for (int j = 0; j < 8; ++j) xf[j] = bf2f(((const u16*)&hx)[j]);
      #pragma unroll
      for (int jj = 0; jj < 16; ++jj) {
        const float4 w0 = *(const float4*)&W5L[(jg + jj) * 128 + c0];
        const float4 w1 = *(const float4*)&W5L[(jg + jj) * 128 + c0 + 4];
        a[jj] += xf[0]*w0.x + xf[1]*w0.y + xf[2]*w0.z + xf[3]*w0.w
               + xf[4]*w1.x + xf[5]*w1.y + xf[6]*w1.z + xf[7]*w1.w;
      }
    }
    float h[16];
    #pragma unroll
    for (int jj = 0; jj < 16; ++jj) {
      const int j = jg + jj;
      float v = a[jj] + p.tb5[j];
      v = v * (p.tg5[j] / bnden) + p.tbe5[j];
      h[jj] = fmaxf(v, 0.f);
    }
    float lg[CLS];
    float mx = -3.4e38f;
    #pragma unroll
    for (int o = 0; o < CLS; ++o) {
      float sp = (jg == 0) ? p.tb6[o] : 0.f;
      #pragma unroll
      for (int jj = 0; jj < 16; ++jj) sp += W6s[o * 32 + jg + jj] * h[jj];
      sp += __shfl_xor(sp, 1);
      lg[o] = sp;
      mx = fmaxf(mx, sp);
    }
    float se = 0.f;
    #pragma unroll
    for (int o = 0; o < CLS; ++o) se += __expf(lg[o] - mx);
    const float lse = mx + __logf(se);
    if ((tid & 1) == 0) {
      float* orow = p.tout1 + (size_t)(bm + tr) * CLS;
      #pragma unroll
      for (int o = 0; o < CLS; ++o) orow[o] = lg[o] - lse;
    }
  }
}

// ======================= bf16-MFMA flash attention, KV-split by blockIdx.z
// QBLK=64, z=2; lazy-max + deferred sum + setprio + T14 register prefetch.
// Writes UNNORMALIZED acc; normalization folded into combA weights.
// NOTE: P-pack uses manual-RNE f2bf (inline-asm cvt_pk corrupted out0, R20).
__global__ __launch_bounds__(256) void attn_mfma_k(
    const u16* __restrict__ thetab,   // (B*N,128) bf16 rm
    const u16* __restrict__ phib,     // (B*H,128) bf16 rm
    const u16* __restrict__ gxT,      // (B,128,2048) bf16 (col 2047 zeroed)
    u16* __restrict__ yp,             // (2, B*N, 128) bf16 partials (unnormalized)
    float2* __restrict__ ml)          // (2, B*N) (m, l)
{
  __shared__ u16 Kt[64 * 128];
  __shared__ u16 Vt[128 * 64];
  __shared__ u16 Pt[64 * 64];
  const int b    = blockIdx.y;
  const int z    = blockIdx.z;
  const int row0 = blockIdx.x * 64;
  const int tid  = threadIdx.x;
  const int wave = tid >> 6;
  const int lane = tid & 63;
  const int l15  = lane & 15, l4 = lane >> 4;

  bf8 aq[4];
  {
    const u16* tq = thetab + ((size_t)(b * NN + row0 + wave * 16 + l15)) * 128;
    #pragma unroll
    for (int ks = 0; ks < 4; ++ks)
      aq[ks] = *(const bf8*)(tq + ks * 32 + l4 * 8);
  }

  f4 acc[8];
  #pragma unroll
  for (int i = 0; i < 8; ++i) acc[i] = (f4){0.f, 0.f, 0.f, 0.f};
  float mrow[4] = {-3e38f, -3e38f, -3e38f, -3e38f};
  float lrow[4] = {0.f, 0.f, 0.f, 0.f};   // per-lane partials

  const u16* phbase = phib + (size_t)b * HH * 128;
  const u16* gxbase = gxT  + (size_t)b * 128 * 2048;

  const int krow = tid >> 4, kch = tid & 15;
  const int vcol = tid >> 3, vch = tid & 7;

  bf8 kreg[4], vreg[4];
  auto loadregs = [&](int h0) {
    #pragma unroll
    for (int it = 0; it < 4; ++it) {
      const int r  = krow + it * 16;
      const int gp = h0 + r;
      bf8 vv = {0,0,0,0,0,0,0,0};
      if (gp < HH) vv = *(const bf8*)(phbase + (size_t)gp * 128 + kch * 8);
      kreg[it] = vv;
    }
    #pragma unroll
    for (int it = 0; it < 4; ++it) {
      const int c = vcol + it * 32;
      vreg[it] = *(const bf8*)(gxbase + (size_t)c * 2048 + h0 + vch * 8);
    }
  };
  auto writeLDS = [&]() {
    #pragma unroll
    for (int it = 0; it < 4; ++it) {
      const int r = krow + it * 16;
      *(bf8*)&Kt[r * 128 + ((kch ^ (r & 7)) << 3)] = kreg[it];
    }
    #pragma unroll
    for (int it = 0; it < 4; ++it) {
      const int c = vcol + it * 32;
      *(bf8*)&Vt[c * 64 + ((vch ^ (c & 7)) << 3)] = vreg[it];
    }
  };

  const int hbeg = z * 1024, hend = hbeg + 1024;
  loadregs(hbeg);
  for (int h0 = hbeg; h0 < hend; h0 += 64) {
    __syncthreads();
    writeLDS();
    if (h0 + 64 < hend) loadregs(h0 + 64);
    __syncthreads();

    f4 sacc[4];
    #pragma unroll
    for (int t = 0; t < 4; ++t) sacc[t] = (f4){0.f, 0.f, 0.f, 0.f};
    __builtin_amdgcn_s_setprio(1);
    #pragma unroll
    for (int ks = 0; ks < 4; ++ks) {
      #pragma unroll
      for (int t = 0; t < 4; ++t) {
        const int pr = t * 16 + l15;
        const int ch = (ks * 4 + l4) ^ (pr & 7);
        bf8 bk = *(const bf8*)&Kt[pr * 128 + ch * 8];
        sacc[t] = __builtin_amdgcn_mfma_f32_16x16x32_bf16(aq[ks], bk, sacc[t], 0, 0, 0);
      }
    }
    __builtin_amdgcn_s_setprio(0);
    if (h0 + 64 > HH) {
      #pragma unroll
      for (int t = 0; t < 4; ++t)
        if (h0 + t * 16 + l15 >= HH)
          sacc[t] = (f4){-3e38f, -3e38f, -3e38f, -3e38f};
    }

    // ---- lazy max
    float tl[4];
    #pragma unroll
    for (int r = 0; r < 4; ++r)
      tl[r] = fmaxf(fmaxf(sacc[0][r], sacc[1][r]), fmaxf(sacc[2][r], sacc[3][r]));
    const bool grow = (tl[0] > mrow[0]) | (tl[1] > mrow[1]) |
                      (tl[2] > mrow[2]) | (tl[3] > mrow[3]);
    if (__any(grow)) {
      #pragma unroll
      for (int r = 0; r < 4; ++r) {
        float tm = tl[r];
        tm = fmaxf(tm, __shfl_xor(tm, 1));
        tm = fmaxf(tm, __shfl_xor(tm, 2));
        tm = fmaxf(tm, __shfl_xor(tm, 4));
        tm = fmaxf(tm, __shfl_xor(tm, 8));
        const float mn = fmaxf(mrow[r], tm);
        const float sc = __expf(mrow[r] - mn);
        mrow[r] = mn;
        lrow[r] *= sc;
        #pragma unroll
        for (int ct = 0; ct < 8; ++ct) acc[ct][r] *= sc;
      }
    }
    // ---- exp + per-lane partial sum + P write (manual RNE pack)
    #pragma unroll
    for (int r = 0; r < 4; ++r) {
      float e[4];
      float ps = 0.f;
      #pragma unroll
      for (int t = 0; t < 4; ++t) {
        e[t] = __expf(sacc[t][r] - mrow[r]);
        ps += e[t];
      }
      lrow[r] += ps;
      const int prow = wave * 16 + l4 * 4 + r;
      #pragma unroll
      for (int t = 0; t < 4; ++t) {
        const int col = t * 16 + l15;
        const int scol = (((col >> 3) ^ (prow & 7)) << 3) | (col & 7);
        Pt[prow * 64 + scol] = f2bf(e[t]);
      }
    }

    __builtin_amdgcn_s_setprio(1);
    #pragma unroll
    for (int ks = 0; ks < 2; ++ks) {
      const int prow2 = wave * 16 + l15;
      bf8 pa = *(const bf8*)&Pt[prow2 * 64 + (((ks * 4 + l4) ^ (prow2 & 7)) << 3)];
      #pragma unroll
      for (int ct = 0; ct < 8; ++ct) {
        const int c  = ct * 16 + l15;
        const int ch = (ks * 4 + l4) ^ (c & 7);
        bf8 bv = *(const bf8*)&Vt[c * 64 + ch * 8];
        acc[ct] = __builtin_amdgcn_mfma_f32_16x16x32_bf16(pa, bv, acc[ct], 0, 0, 0);
      }
    }
    __builtin_amdgcn_s_setprio(0);
  }

  // final sum reduce (once) -- l needed for the combine denominator
  #pragma unroll
  for (int r = 0; r < 4; ++r) {
    float lr = lrow[r];
    lr += __shfl_xor(lr, 1); lr += __shfl_xor(lr, 2);
    lr += __shfl_xor(lr, 4); lr += __shfl_xor(lr, 8);
    lrow[r] = lr;
  }

  const size_t rbase = (size_t)z * BB * NN + (size_t)b * NN + row0 + wave * 16 + l4 * 4;
  u16* yo = yp + rbase * 128;
  #pragma unroll
  for (int r = 0; r < 4; ++r) {
    #pragma unroll
    for (int ct = 0; ct < 8; ++ct)
      yo[(size_t)r * 128 + ct * 16 + l15] = f2bf(acc[ct][r]);
    if (l15 == 0) ml[rbase + r] = make_float2(mrow[r], lrow[r]);
  }
}

// ======================= diff[b,n] = sum_k sum_c (flat[idx1]-xt)^2
// 8 points per 256-thread block; 32 lanes/point; uint2 (8B) loads.
__global__ __launch_bounds__(256) void diff_k(const u16* __restrict__ xtb,
                                              const int* __restrict__ idx1,
                                              float* __restrict__ diff) {
  const int tid = threadIdx.x;
  const int sub = tid >> 5, ln = tid & 31;
  const int bn  = blockIdx.x * 8 + sub;
  const uint2 xcp = *(const uint2*)(xtb + (size_t)bn * CO + ln * 4);
  const float x0 = bf2f((u16)(xcp.x & 0xFFFFu)), x1 = bf2f((u16)(xcp.x >> 16));
  const float x2 = bf2f((u16)(xcp.y & 0xFFFFu)), x3 = bf2f((u16)(xcp.y >> 16));
  const int* id = idx1 + (size_t)bn * KNB;
  float acc = 0.f;
  #pragma unroll 4
  for (int k = 0; k < KNB; ++k) {
    const int ix = id[k];
    const uint2 vp = *(const uint2*)(xtb + (size_t)ix * CO + ln * 4);
    const float d0 = bf2f((u16)(vp.x & 0xFFFFu)) - x0;
    const float d1 = bf2f((u16)(vp.x >> 16))     - x1;
    const float d2 = bf2f((u16)(vp.y & 0xFFFFu)) - x2;
    const float d3 = bf2f((u16)(vp.y >> 16))     - x3;
    acc += d0*d0 + d1*d1 + d2*d2 + d3*d3;
  }
  #pragma unroll
  for (int o = 1; o <= 16; o <<= 1) acc += __shfl_xor(acc, o);
  if (ln == 0) diff[bn] = acc;
}

// ======================= per-batch top-1638 SET via 4-round radix select
// DETERMINISTIC placement: prefix-scan positions (replay-invariant Hidx order).
__global__ __launch_bounds__(1024) void topsel_k(const float* __restrict__ diff,
                                                 InnerArgs ia,
                                                 int* __restrict__ Hidx) {
  __shared__ uint32_t hist[256];
  __shared__ uint32_t sh_T, sh_need, sh_eqc;
  __shared__ int      sh_eq[1024];
  __shared__ uint32_t scn[1024];
  const int b = blockIdx.x, tid = threadIdx.x;
  const float* db = diff + (size_t)b * NN;
  uint32_t v[8];
  #pragma unroll
  for (int i = 0; i < 8; ++i) v[i] = __float_as_uint(db[tid * 8 + i]);
  if (tid == 0) { sh_T = 0u; sh_need = OUTER; sh_eqc = 0u; }
  #pragma unroll
  for (int round = 0; round < 4; ++round) {
    const int shift = 24 - 8 * round;
    for (int i = tid; i < 256; i += 1024) hist[i] = 0u;
    __syncthreads();
    const uint32_t Tpart  = sh_T;
    const uint32_t maskHi = (round == 0) ? 0u : (0xFFFFFFFFu << (shift + 8));
    #pragma unroll
    for (int i = 0; i < 8; ++i)
      if ((v[i] & maskHi) == (Tpart & maskHi))
        atomicAdd(&hist[(v[i] >> shift) & 255u], 1u);
    __syncthreads();
    if (tid == 0) {
      uint32_t need = sh_need, accn = 0u;
      int bsel = 0;
      for (int bin = 255; bin >= 0; --bin) {
        uint32_t h = hist[bin];
        if (accn + h >= need) { bsel = bin; break; }
        accn += h;
      }
      sh_T = Tpart | ((uint32_t)bsel << shift);
      sh_need = need - accn;
    }
    __syncthreads();
  }
  const uint32_t T   = sh_T;
  const uint32_t rem = sh_need;

  // deterministic exclusive scan of per-thread ">" counts
  uint32_t cnt = 0;
  #pragma unroll
  for (int i = 0; i < 8; ++i) cnt += (v[i] > T) ? 1u : 0u;
  scn[tid] = cnt;
  __syncthreads();
  for (int off = 1; off < 1024; off <<= 1) {
    uint32_t t = (tid >= off) ? scn[tid - off] : 0u;
    __syncthreads();
    scn[tid] += t;
    __syncthreads();
  }
  uint32_t pos = scn[tid] - cnt;   // exclusive prefix (index-ordered placement)
  #pragma unroll
  for (int i = 0; i < 8; ++i) {
    const int idx = tid * 8 + i;
    if (v[i] > T) {
      Hidx[b * HH + (int)(pos++)] = idx;
    } else if (v[i] == T) {
      uint32_t e = atomicAdd(&sh_eqc, 1u);
      if (e < 1024u) sh_eq[e] = idx;
    }
  }
  __syncthreads();
  if (tid == 0) {
    const uint32_t C = OUTER - rem;          // #(v > T) is exactly OUTER - rem
    uint32_t eqc = sh_eqc < 1024u ? sh_eqc : 1024u;
    for (uint32_t j = 0; j < rem && j < eqc; ++j) {
      int best = 0x7fffffff, bi = 0;
      for (uint32_t t = 0; t < eqc; ++t)
        if (sh_eq[t] < best) { best = sh_eq[t]; bi = (int)t; }
      Hidx[b * HH + C + j] = best;
      sh_eq[bi] = 0x7fffffff;
    }
  }
  if (tid < INNER) Hidx[b * HH + OUTER + tid] = ia.v[tid];
}

} // anonymous namespace

// ===========================================================================
extern "C" void kernel_launch(void* const* d_in, const int* in_sizes, int n_in,
                              void* d_out, int out_size, void* d_ws, size_t ws_size,
                              hipStream_t stream) {
  const float* xyz1    = (const float*)d_in[0];
  const float* xyz2    = (const float*)d_in[1];
  const float* points1 = (const float*)d_in[2];
  const float* points2 = (const float*)d_in[3];
  const float* lastpred= (const float*)d_in[5];
  const float* w_mlp0  = (const float*)d_in[6];
  const float* b_mlp0  = (const float*)d_in[7];
  const float* g_bn0   = (const float*)d_in[8];
  const float* be_bn0  = (const float*)d_in[9];
  const float* w_mlp1  = (const float*)d_in[10];
  const float* b_mlp1  = (const float*)d_in[11];
  const float* g_bn1   = (const float*)d_in[12];
  const float* be_bn1  = (const float*)d_in[13];
  const float* w_h     = (const float*)d_in[14];
  const float* g_hbn   = (const float*)d_in[15];
  const float* be_hbn  = (const float*)d_in[16];
  const float* w_outm  = (const float*)d_in[17];
  const float* g_obn   = (const float*)d_in[18];
  const float* be_obn  = (const float*)d_in[19];
  const float* w_g     = (const float*)d_in[20];
  const float* b_g     = (const float*)d_in[21];
  const float* w_theta = (const float*)d_in[22];
  const float* b_theta = (const float*)d_in[23];
  const float* w_phi   = (const float*)d_in[24];
  const float* b_phi   = (const float*)d_in[25];
  const float* w_W     = (const float*)d_in[26];
  const float* b_W     = (const float*)d_in[27];
  const float* g_Wbn   = (const float*)d_in[28];
  const float* be_Wbn  = (const float*)d_in[29];
  const float* w5      = (const float*)d_in[30];
  const float* b5      = (const float*)d_in[31];
  const float* g_bn5   = (const float*)d_in[32];
  const float* be_bn5  = (const float*)d_in[33];
  const float* w6      = (const float*)d_in[34];
  const float* b6      = (const float*)d_in[35];
  const int*   idx_1   = (const int*)d_in[36];

  float* out0 = (float*)d_out;
  float* out1 = out0 + (size_t)BB * CO * NN;

  char* base = (char*)d_ws;
  size_t off = 0;
  auto alloc = [&](size_t bytes) -> char* {
    char* p = base + off;
    off += (bytes + 255) & ~(size_t)255;
    return p;
  };
  float* diff   = (float*)alloc((size_t)BB * NN * 4);
  int*   Hidx   = (int*)  alloc((size_t)BB * HH * 4);
  float* preds  = (float*)alloc((size_t)BB * NN * CLS * 4);
  float* xt     = (float*)alloc((size_t)BB * NN * CO * 4);
  u16*   xtb    = (u16*)  alloc((size_t)BB * NN * CO * 2);
  u16*   phib   = (u16*)  alloc((size_t)BB * HH * CO * 2);
  u16*   gxT    = (u16*)  alloc((size_t)BB * CO * 2048 * 2);
  float2* mlbuf = (float2*)alloc((size_t)2 * BB * NN * 8);
  u16*   wbuf   = (u16*)  alloc((size_t)270336 * 2);
  char*  R1     =         alloc((size_t)BB * NN * 512 * 2);     // 33.5MB
  char*  R2     =         alloc((size_t)BB * NN * 256 * 2);     // 16MB
  if (off > ws_size) return;   // insufficient scratch (diagnostic)

  // weight bf16 buffers inside wbuf
  u16* w0b = wbuf;                 // 256x512
  u16* w1b = w0b + 256 * 512;      // 128x256
  u16* whb = w1b + 128 * 256;      // 128x192 (149 padded)
  u16* wgb = whb + 128 * 192;      // 128x128
  u16* wtb = wgb + 128 * 128;
  u16* wpb = wtb + 128 * 128;
  u16* wWb = wpb + 128 * 128;
  u16* wob = wWb + 128 * 128;

  // region aliases (lifetimes disjoint)
  u16*   A0     = (u16*)R1;                                     // prep..mlp0
  u16*   thetab = (u16*)R1;                                     // mlp1..attn (8MB)
  u16*   yp     = (u16*)(R1 + (size_t)8 * 1024 * 1024);         // attn..Wgemm (16MB)
  float* p2t    = (float*)R2;                                   // prep..knn_interp (8MB)
  u16*   x2b    = (u16*)R2;                                     // mlp0..mlp1 (16MB)

  // host RNG for inner indices (baked into topsel kernargs)
  InnerArgs ia;
  compute_inner_host(ia.v);

  // 1. merged prep: points2 transpose + points1 cvt + weight cvt
  {
    WcvAll wa;
    wa.e[0] = {w_mlp0, w0b, 256, 512, 512};
    wa.e[1] = {w_mlp1, w1b, 128, 256, 256};
    wa.e[2] = {w_h,    whb, 128, 149, 192};
    wa.e[3] = {w_g,    wgb, 128, 128, 128};
    wa.e[4] = {w_theta,wtb, 128, 128, 128};
    wa.e[5] = {w_phi,  wpb, 128, 128, 128};
    wa.e[6] = {w_W,    wWb, 128, 128, 128};
    wa.e[7] = {w_outm, wob, 128, 128, 128};
    prep1_k<<<6400, 256, 0, stream>>>(points2, p2t, points1, A0, wa);
  }

  // 2. fused 3-NN + interpolation -> A0 cols 256..511 (bf16) + preds f32
  knn_interp_k<<<dim3(NN/16, BB), 256, 0, stream>>>(xyz1, xyz2, p2t, lastpred, A0, preds);

  // 3. mlp0: relu(bn0(W0·A0 + b0)) -> x2b bf16
  {
    MgP p{};
    p.A = A0; p.W = w0b; p.bias = b_mlp0; p.bng = g_bn0; p.bnb = be_bn0;
    p.C = x2b; p.M = BB * NN; p.Nc = 256; p.K = 512; p.act = 1; p.omode = 1;
    mgemm_k<<<dim3(2, 256), 256, 0, stream>>>(p);
  }
  // 4. mlp1 (-> xtb bf16 + xt f32) fused with theta -> thetab   [TF=0]
  {
    Mg2P p{};
    p.A = x2b; p.W = w1b; p.bias = b_mlp1; p.bng = g_bn1; p.bnb = be_bn1;
    p.C1 = xtb; p.writeC1 = 1; p.C2f = xt;
    p.M = BB * NN; p.K = 256; p.act = 1; p.n2 = 1;
    p.s2[0] = {wtb, b_theta, nullptr, nullptr, 0, 1, thetab, nullptr};
    mgemm2_k<0><<<dim3(1, 256), 256, 0, stream>>>(p);
  }

  // 5. KNN feature variance score (8 pts/block, 8B loads)
  diff_k<<<BB * NN / 8, 256, 0, stream>>>(xtb, idx_1, diff);

  // 6. per-batch top-1638 set via deterministic radix select
  topsel_k<<<BB, 1024, 0, stream>>>(diff, ia, Hidx);

  // 7. conv_h (A gathered via Hidx from xtb+preds) fused with g_x and phi [TF=0]
  {
    Mg2P p{};
    p.W = whb; p.bng = g_hbn; p.bnb = be_hbn;
    p.gxtb = xtb; p.gpreds = preds; p.gHidx = Hidx; p.gatherA = 1;
    p.writeC1 = 0; p.M = BB * HH; p.K = 192; p.act = 2; p.n2 = 2;
    p.s2[0] = {wgb, b_g,   nullptr, nullptr, 0, 2, gxT,  nullptr};
    p.s2[1] = {wpb, b_phi, nullptr, nullptr, 0, 1, phib, nullptr};
    mgemm2_k<0><<<dim3(1, 64), 256, 0, stream>>>(p);
  }

  // 8. MFMA flash attention, KV-split x2 -> unnormalized partials
  attn_mfma_k<<<dim3(NN/64, BB, 2), 256, 0, stream>>>(thetab, phib, gxT, yp, mlbuf);

  // 9. combine(yp) -> z = bn_W(W_W·y + b_W) + xt, fused with outm;
  // stage-2 writes out0 transposed + fused tail -> out1. [TF=1]
  {
    Mg2P p{};
    p.W = wWb; p.bias = b_W; p.bng = g_Wbn; p.bnb = be_Wbn; p.res = xt;
    p.ypA = yp; p.mlA = mlbuf; p.combA = 1;
    p.writeC1 = 0; p.M = BB * NN; p.K = 128; p.act = 0; p.n2 = 1;
    p.s2[0] = {wob, nullptr, g_obn, be_obn, 2, 0, nullptr, out0};
    p.tw5 = w5; p.tb5 = b5; p.tg5 = g_bn5; p.tbe5 = be_bn5;
    p.tw6 = w6; p.tb6 = b6; p.tout1 = out1; p.tailfuse = 1;
    mgemm2_k<1><<<dim3(1, 256), 256, 0, stream>>>(p);
  }
}

// Round 24
// 421.684 us; speedup vs baseline: 1.1760x; 1.1264x over previous
//
#include <hip/hip_runtime.h>
#include <stdint.h>
#include <string.h>
#include <math.h>

// ---------------------------------------------------------------------------
// IAF_PointNetFeaturePropagation: bf16-MFMA fused GEMM chain + split flash attn.
// B=4, N=8192, S=2048, K=20, D1=D2=256, CO=128, CLS=21, H=1638+409=2047
// ---------------------------------------------------------------------------

namespace {

constexpr int BB   = 4;
constexpr int NN   = 8192;
constexpr int SS   = 2048;
constexpr int KNB  = 20;
constexpr int CO   = 128;
constexpr int CLS  = 21;
constexpr int HH   = 2047;
constexpr int OUTER= 1638;
constexpr int INNER= 409;

typedef unsigned short u16;
typedef short bf8 __attribute__((ext_vector_type(8)));   // 8 bf16 in 4 VGPRs
typedef float f4  __attribute__((ext_vector_type(4)));   // MFMA accumulator

__device__ inline u16 f2bf(float f) {                    // round-nearest-even
  uint32_t x = __float_as_uint(f);
  return (u16)((x + 0x7FFFu + ((x >> 16) & 1u)) >> 16);
}
__device__ inline float bf2f(u16 v) {
  return __uint_as_float((uint32_t)v << 16);
}

// ======================= numpy default_rng(0).choice(8192,409) on the HOST
struct InnerArgs { int v[INNER]; };

static void compute_inner_host(int* out) {
  uint32_t pool[4];
  uint32_t hc = 0x43b0d7e5u;
  auto hashmix = [&hc](uint32_t v) -> uint32_t {
    v ^= hc; hc *= 0x931e8875u; v *= hc; v ^= v >> 16; return v;
  };
  auto mixf = [](uint32_t x, uint32_t y) -> uint32_t {
    uint32_t r = x * 0xca01f9ddu; r ^= y * 0x4973f715u; r ^= r >> 16; return r;
  };
  pool[0] = hashmix(0u); pool[1] = hashmix(0u);
  pool[2] = hashmix(0u); pool[3] = hashmix(0u);
  for (int s = 0; s < 4; ++s)
    for (int d = 0; d < 4; ++d)
      if (s != d) pool[d] = mixf(pool[d], hashmix(pool[s]));

  uint32_t st32[8];
  uint32_t hb = 0x8b51f9ddu;
  for (int i = 0; i < 8; ++i) {
    uint32_t dv = pool[i & 3];
    dv ^= hb; hb *= 0x58f38dedu; dv *= hb; dv ^= dv >> 16;
    st32[i] = dv;
  }
  uint64_t s64[4];
  for (int i = 0; i < 4; ++i)
    s64[i] = (uint64_t)st32[2*i] | ((uint64_t)st32[2*i+1] << 32);

  typedef unsigned __int128 u128;
  const u128 MUL = ((u128)2549297995355413924ull << 64) | (u128)4865540595714422341ull;
  u128 inc   = (((((u128)s64[2]) << 64) | (u128)s64[3]) << 1) | 1;
  u128 state = inc;
  state += (((u128)s64[0]) << 64) | (u128)s64[1];
  state = state * MUL + inc;

  bool has32 = false; uint32_t buf32 = 0;
  auto next32 = [&]() -> uint32_t {
    if (has32) { has32 = false; return buf32; }
    state = state * MUL + inc;
    uint64_t hi = (uint64_t)(state >> 64), lo = (uint64_t)state;
    uint64_t x = hi ^ lo;
    unsigned rot = (unsigned)(state >> 122);
    uint64_t v = (x >> rot) | (x << ((64u - rot) & 63u));
    has32 = true; buf32 = (uint32_t)(v >> 32);
    return (uint32_t)v;
  };

  uint64_t hs[512];
  memset(hs, 0xFF, sizeof(hs));
  for (int j = NN - INNER; j < NN; ++j) {
    uint32_t rng = (uint32_t)j, rng_excl = rng + 1u;
    uint64_t m = (uint64_t)next32() * (uint64_t)rng_excl;
    uint32_t leftover = (uint32_t)m;
    if (leftover < rng_excl) {
      uint32_t threshold = (0xFFFFFFFFu - rng) % rng_excl;
      while (leftover < threshold) {
        m = (uint64_t)next32() * (uint64_t)rng_excl;
        leftover = (uint32_t)m;
      }
    }
    uint64_t val = m >> 32;
    uint32_t loc = (uint32_t)val & 511u;
    while (hs[loc] != ~0ull && hs[loc] != val) loc = (loc + 1u) & 511u;
    uint64_t chosen;
    if (hs[loc] == ~0ull) { hs[loc] = val; chosen = val; }
    else                  { hs[loc] = (uint64_t)j; chosen = (uint64_t)j; }
    out[j - (NN - INNER)] = (int)chosen;
  }
}

// ======================= weight f32 -> bf16 descriptor
struct WcvP { const float* src; u16* dst; int rows; int K; int Kpad; };
struct WcvAll { WcvP e[8]; };

// ======================= merged prep: transpose2 | tcvt | wcvt (one dispatch)
__global__ __launch_bounds__(256) void prep1_k(const float* __restrict__ points2,
                                               float* __restrict__ p2t,
                                               const float* __restrict__ points1,
                                               u16* __restrict__ A0,
                                               WcvAll wa) {
  const int t = blockIdx.x;
  const int tid = threadIdx.x;
  __shared__ float sh[64][33];
  if (t < 2048) {
    const int b = t >> 9, rest = t & 511;
    const int c0 = (rest & 63) * 32, r0 = (rest >> 6) * 32;
    const float* ib = points2 + (size_t)b * 256 * SS;
    float*       ob = p2t    + (size_t)b * SS * 256;
    const int tx = tid & 31, ty = tid >> 5;
    #pragma unroll
    for (int i = 0; i < 32; i += 8)
      sh[ty + i][tx] = ib[(size_t)(r0 + ty + i) * SS + c0 + tx];
    __syncthreads();
    #pragma unroll
    for (int i = 0; i < 32; i += 8)
      ob[(size_t)(c0 + ty + i) * 256 + r0 + tx] = sh[tx][ty + i];
  } else if (t < 6144) {
    const int u = t - 2048;
    const int b = u >> 10, c0 = ((u >> 8) & 3) * 64, n0 = (u & 255) * 32;
    {
      const int tn = tid & 31, tc0 = tid >> 5;
      #pragma unroll
      for (int i = 0; i < 8; ++i) {
        const int c = tc0 * 8 + i;
        sh[c][tn] = points1[((size_t)b * 256 + c0 + c) * NN + n0 + tn];
      }
    }
    __syncthreads();
    {
      const int cg = tid & 7, n = tid >> 3;
      u16 tmp[8];
      #pragma unroll
      for (int j = 0; j < 8; ++j) tmp[j] = f2bf(sh[cg * 8 + j][n]);
      *(bf8*)&A0[((size_t)b * NN + n0 + n) * 512 + c0 + cg * 8] = *(bf8*)tmp;
    }
  } else {
    const int w = t - 6144;
    WcvP p = wa.e[w >> 5];
    const int xb = w & 31;
    const int total = p.rows * p.Kpad;
    for (int i = xb * 256 + tid; i < total; i += 32 * 256) {
      const int r = i / p.Kpad, k = i - r * p.Kpad;
      p.dst[i] = (k < p.K) ? f2bf(p.src[(size_t)r * p.K + k]) : (u16)0;
    }
  }
}

// ======================= fused 3-NN + interpolation (16 points per block)
__global__ __launch_bounds__(256) void knn_interp_k(const float* __restrict__ xyz1,
                                                    const float* __restrict__ xyz2,
                                                    const float* __restrict__ p2t,
                                                    const float* __restrict__ lastpred,
                                                    u16* __restrict__ A0,
                                                    float* __restrict__ preds) {
  __shared__ float4 P2[SS];
  __shared__ int   sidx[16][3];
  __shared__ float sw[16][3];
  const int b = blockIdx.y;
  const float* x2 = xyz2 + (size_t)b * SS * 3;
  for (int i = threadIdx.x; i < SS; i += 256) {
    float x = x2[i*3], y = x2[i*3+1], z = x2[i*3+2];
    P2[i] = make_float4(x, y, z, x*x + y*y + z*z);
  }
  __syncthreads();
  const int tid   = threadIdx.x;
  const int chunk = tid & 15;
  const int pt    = tid >> 4;
  const int n     = blockIdx.x * 16 + pt;
  const float* p  = xyz1 + ((size_t)b * NN + n) * 3;
  const float px = p[0], py = p[1], pz = p[2];
  const float ss1 = px*px + py*py + pz*pz;
  float d0 = 3.4e38f, d1 = 3.4e38f, d2 = 3.4e38f;
  int   i0 = 0, i1 = 0, i2 = 0;
  auto ins = [&](float d, int s) {
    const bool c0 = d < d0, c1 = d < d1, c2 = d < d2;
    const float nd0 = c0 ? d  : d0;
    const int   nj0 = c0 ? s  : i0;
    const float nd1 = c0 ? d0 : (c1 ? d : d1);
    const int   nj1 = c0 ? i0 : (c1 ? s : i1);
    const float nd2 = c1 ? d1 : (c2 ? d : d2);
    const int   nj2 = c1 ? i1 : (c2 ? s : i2);
    d0 = nd0; d1 = nd1; d2 = nd2;
    i0 = nj0; i1 = nj1; i2 = nj2;
  };
  #pragma unroll 8
  for (int i = 0; i < 128; ++i) {
    const int s = chunk + (i << 4);
    const float4 q = P2[s];
    float d = (ss1 + q.w) - 2.0f * (px*q.x + py*q.y + pz*q.z);
    ins(d, s);
  }
  #pragma unroll
  for (int off = 1; off <= 8; off <<= 1) {
    float e0 = __shfl_xor(d0, off), e1 = __shfl_xor(d1, off), e2 = __shfl_xor(d2, off);
    int   j0 = __shfl_xor(i0, off), j1 = __shfl_xor(i1, off), j2 = __shfl_xor(i2, off);
    ins(e0, j0); ins(e1, j1); ins(e2, j2);
  }
  if (chunk == 0) {
    d0 = fmaxf(d0, 1e-10f); d1 = fmaxf(d1, 1e-10f); d2 = fmaxf(d2, 1e-10f);
    float w0 = 1.f/d0, w1 = 1.f/d1, w2 = 1.f/d2;
    float ws = w0 + w1 + w2;
    sidx[pt][0] = i0; sidx[pt][1] = i1; sidx[pt][2] = i2;
    sw[pt][0] = w0/ws; sw[pt][1] = w1/ws; sw[pt][2] = w2/ws;
  }
  __syncthreads();

  const int n0 = blockIdx.x * 16;
  const float* pb = p2t + (size_t)b * SS * 256;
  const float* lp = lastpred + (size_t)b * SS * CLS;
  const int c = tid;
  #pragma unroll 4
  for (int q = 0; q < 16; ++q) {
    const size_t o = (size_t)b * NN + n0 + q;
    const int j0 = sidx[q][0], j1 = sidx[q][1], j2 = sidx[q][2];
    const float w0 = sw[q][0], w1 = sw[q][1], w2 = sw[q][2];
    const float v = w0 * pb[(size_t)j0*256 + c]
                  + w1 * pb[(size_t)j1*256 + c]
                  + w2 * pb[(size_t)j2*256 + c];
    A0[o*512 + 256 + c] = f2bf(v);
    if (c < CLS)
      preds[o*CLS + c] = w0 * lp[j0*CLS + c] + w1 * lp[j1*CLS + c] + w2 * lp[j2*CLS + c];
  }
}

// ======================= bf16 MFMA GEMM, 128x128 tile, T14 reg-prefetch staging
struct MgP {
  const u16* A; const u16* W;
  const float* bias; const float* bng; const float* bnb; const float* res;
  void* C; float* C2;
  int M, Nc, K, act, omode;
};

__global__ __launch_bounds__(256) void mgemm_k(MgP p) {
  __shared__ u16 As[128 * 64];
  __shared__ u16 Ws[128 * 64];
  const int tid = threadIdx.x;
  const int wave = tid >> 6, lane = tid & 63;
  const int l15 = lane & 15, l4 = lane >> 4;
  const int wr = wave >> 1, wc = wave & 1;
  const int bm = blockIdx.y * 128, bn = blockIdx.x * 128;
  const int srow = tid >> 3, sch = tid & 7;

  f4 acc[4][4];
  #pragma unroll
  for (int i = 0; i < 4; ++i)
    #pragma unroll
    for (int j = 0; j < 4; ++j) acc[i][j] = (f4){0.f, 0.f, 0.f, 0.f};

  bf8 vA[4], vB[4];
  auto loadT = [&](int k0) {
    #pragma unroll
    for (int it = 0; it < 4; ++it) {
      const int r = srow + it * 32;
      const int gm = bm + r;
      bf8 va = {0,0,0,0,0,0,0,0};
      if (gm < p.M) va = *(const bf8*)(p.A + (size_t)gm * p.K + k0 + sch * 8);
      vA[it] = va;
      const int gn = bn + r;
      bf8 vb = {0,0,0,0,0,0,0,0};
      if (gn < p.Nc) vb = *(const bf8*)(p.W + (size_t)gn * p.K + k0 + sch * 8);
      vB[it] = vb;
    }
  };
  auto writeT = [&]() {
    #pragma unroll
    for (int it = 0; it < 4; ++it) {
      const int r = srow + it * 32;
      *(bf8*)&As[r * 64 + ((sch ^ (r & 7)) << 3)] = vA[it];
      *(bf8*)&Ws[r * 64 + ((sch ^ (r & 7)) << 3)] = vB[it];
    }
  };

  loadT(0);
  for (int k0 = 0; k0 < p.K; k0 += 64) {
    __syncthreads();
    writeT();
    if (k0 + 64 < p.K) loadT(k0 + 64);
    __syncthreads();
    #pragma unroll
    for (int ks = 0; ks < 2; ++ks) {
      bf8 af[4], bf[4];
      #pragma unroll
      for (int mf = 0; mf < 4; ++mf) {
        int m = wr * 64 + mf * 16 + l15;
        af[mf] = *(const bf8*)&As[m * 64 + (((ks * 4 + l4) ^ (m & 7)) << 3)];
      }
      #pragma unroll
      for (int nf = 0; nf < 4; ++nf) {
        int n = wc * 64 + nf * 16 + l15;
        bf[nf] = *(const bf8*)&Ws[n * 64 + (((ks * 4 + l4) ^ (n & 7)) << 3)];
      }
      #pragma unroll
      for (int mf = 0; mf < 4; ++mf)
        #pragma unroll
        for (int nf = 0; nf < 4; ++nf)
          acc[mf][nf] = __builtin_amdgcn_mfma_f32_16x16x32_bf16(af[mf], bf[nf], acc[mf][nf], 0, 0, 0);
    }
  }

  const float bnden = sqrtf(1.0f + 1e-5f);
  #pragma unroll
  for (int mf = 0; mf < 4; ++mf) {
    #pragma unroll
    for (int i = 0; i < 4; ++i) {
      const int r = bm + wr * 64 + mf * 16 + l4 * 4 + i;
      if (r >= p.M) continue;
      #pragma unroll
      for (int nf = 0; nf < 4; ++nf) {
        const int c = bn + wc * 64 + nf * 16 + l15;
        float v = acc[mf][nf][i];
        if (p.bias) v += p.bias[c];
        if (p.bng)  v = v * (p.bng[c] / bnden) + p.bnb[c];
        if (p.res)  v += p.res[(size_t)r * p.Nc + c];
        if (p.act == 1)      v = fmaxf(v, 0.f);
        else if (p.act == 2) v = (v >= 0.f) ? v : 0.2f * v;
        if (p.omode == 0) {
          ((float*)p.C)[(size_t)r * p.Nc + c] = v;
        } else if (p.omode == 1) {
          ((u16*)p.C)[(size_t)r * p.Nc + c] = f2bf(v);
        } else {
          const int bb = r / HH, rr = r - bb * HH;
          ((u16*)p.C)[((size_t)(bb * p.Nc + c)) * 2048 + rr] = f2bf(v);
        }
        if (p.C2) p.C2[(size_t)r * p.Nc + c] = v;
      }
    }
  }
}

// ======================= two-stage fused bf16 GEMM, 64-row M-tiles (2+ blk/CU)
// TF=0: plain/gatherA variants (no tail). TF=1: combA + tail fusion.
// SM(u16): As[0,4096) | Ws[4096,12288) | T1[12288 + half*4096), half in {0,1}
// TF=1 tail reuse: W5L f32 16KB over SM[0,8192); Hs bf16 [64][128] over T1 region.
struct S2d { const u16* W; const float* bias; const float* bng; const float* bnb;
             int act; int omode; void* C; float* Ct; };
struct Mg2P {
  const u16* A; const u16* W;
  const float* bias; const float* bng; const float* bnb; const float* res;
  void* C1; float* C2f;
  const u16* ypA; const float2* mlA; int combA;
  const u16* gxtb; const float* gpreds; const int* gHidx; int gatherA;
  int M, K, act, writeC1, n2;
  S2d s2[2];
  const float *tw5, *tb5, *tg5, *tbe5, *tw6, *tb6;
  float* tout1;
  int tailfuse;
};

template <int TF>
__global__ __launch_bounds__(256) void mgemm2_k(Mg2P p) {
  __shared__ u16 SM[20480];                        // 40KB
  __shared__ float XL[TF ? (128 + CLS * 32) : 1];  // cw[64][2] | W6s[CLS*32]
  float* const cw  = XL;
  float* const W6s = XL + 128;
  u16* const As  = SM;          // 64 x 64
  u16* const Wsp = SM + 4096;   // 128 x 64
  u16* const T1  = SM + 12288;  // 2 halves x 64 x 64
  const int tid = threadIdx.x;
  const int wave = tid >> 6, lane = tid & 63;
  const int l15 = lane & 15, l4 = lane >> 4;
  const int wr = wave >> 1, wc = wave & 1;   // 2x2 waves: 32 rows x 64 cols each
  const int bm = blockIdx.y * 64;
  const int srow = tid >> 3, sch = tid & 7;  // srow in [0,32)

  if constexpr (TF) {
    if (p.combA) {
      if (tid < 64) {
        const int gm = bm + tid;
        const float2 a0 = p.mlA[gm];
        const float2 a1 = p.mlA[(size_t)BB * NN + gm];
        const float mm = fmaxf(a0.x, a1.x);
        const float w0 = __expf(a0.x - mm);
        const float w1 = __expf(a1.x - mm);
        const float inv = 1.0f / (w0 * a0.y + w1 * a1.y);
        cw[tid * 2 + 0] = w0 * inv;
        cw[tid * 2 + 1] = w1 * inv;
      }
      __syncthreads();   // cw visible before prefetch reads it
    }
  }

  f4 acc[2][4];
  #pragma unroll
  for (int i = 0; i < 2; ++i)
    #pragma unroll
    for (int j = 0; j < 4; ++j) acc[i][j] = (f4){0.f, 0.f, 0.f, 0.f};

  bf8 vA[2], vB[4];
  auto loadT = [&](int k0) {
    #pragma unroll
    for (int it = 0; it < 2; ++it) {           // A: 64 rows
      const int r = srow + it * 32;
      const int gm = bm + r;
      bf8 va = {0,0,0,0,0,0,0,0};
      if (gm < p.M) {
        if constexpr (TF) {
          const float w0 = cw[r * 2 + 0], w1 = cw[r * 2 + 1];
          const bf8 y0 = *(const bf8*)(p.ypA + (size_t)gm * 128 + k0 + sch * 8);
          const bf8 y1 = *(const bf8*)(p.ypA + ((size_t)BB * NN + gm) * 128 + k0 + sch * 8);
          u16 tmp[8];
          #pragma unroll
          for (int j = 0; j < 8; ++j)
            tmp[j] = f2bf(w0 * bf2f(((const u16*)&y0)[j]) +
                          w1 * bf2f(((const u16*)&y1)[j]));
          va = *(bf8*)tmp;
        } else {
          if (p.gatherA) {
            const int gb = gm / HH, gh = gm - gb * HH;
            const int src = p.gHidx[gb * HH + gh];
            const size_t sr = (size_t)gb * NN + src;
            const int colbase = k0 + sch * 8;
            if (colbase < CO) {
              va = *(const bf8*)(p.gxtb + sr * CO + colbase);
            } else {
              u16 tmp[8];
              #pragma unroll
              for (int j = 0; j < 8; ++j) {
                const int col = colbase + j;
                tmp[j] = (col < CO + CLS) ? f2bf(p.gpreds[sr * CLS + (col - CO)]) : (u16)0;
              }
              va = *(bf8*)tmp;
            }
          } else {
            va = *(const bf8*)(p.A + (size_t)gm * p.K + k0 + sch * 8);
          }
        }
      }
      vA[it] = va;
    }
    #pragma unroll
    for (int it = 0; it < 4; ++it) {           // B (weights): 128 rows
      const int r = srow + it * 32;
      vB[it] = *(const bf8*)(p.W + (size_t)r * p.K + k0 + sch * 8);
    }
  };
  auto writeT = [&]() {
    #pragma unroll
    for (int it = 0; it < 2; ++it) {
      const int r = srow + it * 32;
      *(bf8*)&As[r * 64 + ((sch ^ (r & 7)) << 3)] = vA[it];
    }
    #pragma unroll
    for (int it = 0; it < 4; ++it) {
      const int r = srow + it * 32;
      *(bf8*)&Wsp[r * 64 + ((sch ^ (r & 7)) << 3)] = vB[it];
    }
  };

  loadT(0);
  for (int k0 = 0; k0 < p.K; k0 += 64) {
    __syncthreads();
    writeT();
    if (k0 + 64 < p.K) loadT(k0 + 64);
    __syncthreads();
    #pragma unroll
    for (int ks = 0; ks < 2; ++ks) {
      bf8 af[2], bf[4];
      #pragma unroll
      for (int mf = 0; mf < 2; ++mf) {
        int m = wr * 32 + mf * 16 + l15;
        af[mf] = *(const bf8*)&As[m * 64 + (((ks * 4 + l4) ^ (m & 7)) << 3)];
      }
      #pragma unroll
      for (int nf = 0; nf < 4; ++nf) {
        int n = wc * 64 + nf * 16 + l15;
        bf[nf] = *(const bf8*)&Wsp[n * 64 + (((ks * 4 + l4) ^ (n & 7)) << 3)];
      }
      #pragma unroll
      for (int mf = 0; mf < 2; ++mf)
        #pragma unroll
        for (int nf = 0; nf < 4; ++nf)
          acc[mf][nf] = __builtin_amdgcn_mfma_f32_16x16x32_bf16(af[mf], bf[nf], acc[mf][nf], 0, 0, 0);
    }
  }

  const float bnden = sqrtf(1.0f + 1e-5f);
  #pragma unroll
  for (int mf = 0; mf < 2; ++mf) {
    #pragma unroll
    for (int i = 0; i < 4; ++i) {
      const int rl = wr * 32 + mf * 16 + l4 * 4 + i;
      const int r  = bm + rl;
      #pragma unroll
      for (int nf = 0; nf < 4; ++nf) {
        const int c  = wc * 64 + nf * 16 + l15;
        float v = acc[mf][nf][i];
        if (p.bias) v += p.bias[c];
        if (p.bng)  v = v * (p.bng[c] / bnden) + p.bnb[c];
        if (p.res && r < p.M) v += p.res[(size_t)r * 128 + c];
        if (p.act == 1)      v = fmaxf(v, 0.f);
        else if (p.act == 2) v = (v >= 0.f) ? v : 0.2f * v;
        if (r < p.M) {
          if (p.writeC1) ((u16*)p.C1)[(size_t)r * 128 + c] = f2bf(v);
          if (p.C2f)     p.C2f[(size_t)r * 128 + c] = v;
        }
        const int cl = c & 63;
        T1[wc * 4096 + rl * 64 + (((cl >> 3) ^ (rl & 7)) << 3) + (cl & 7)] = f2bf(v);
      }
    }
  }

  for (int s = 0; s < p.n2; ++s) {
    const S2d q = p.s2[s];
    #pragma unroll
    for (int i = 0; i < 2; ++i)
      #pragma unroll
      for (int j = 0; j < 4; ++j) acc[i][j] = (f4){0.f, 0.f, 0.f, 0.f};
    for (int k0 = 0; k0 < 128; k0 += 64) {
      __syncthreads();
      #pragma unroll
      for (int it = 0; it < 4; ++it) {
        int id = it * 256 + tid;
        int r = id >> 3, ch = id & 7;
        bf8 vb = *(const bf8*)(q.W + (size_t)r * 128 + k0 + ch * 8);
        *(bf8*)&Wsp[r * 64 + ((ch ^ (r & 7)) << 3)] = vb;
      }
      __syncthreads();
      #pragma unroll
      for (int ks = 0; ks < 2; ++ks) {
        bf8 af[2], bf[4];
        #pragma unroll
        for (int mf = 0; mf < 2; ++mf) {
          int m = wr * 32 + mf * 16 + l15;
          af[mf] = *(const bf8*)&T1[(k0 >> 6) * 4096 + m * 64 + (((ks * 4 + l4) ^ (m & 7)) << 3)];
        }
        #pragma unroll
        for (int nf = 0; nf < 4; ++nf) {
          int n = wc * 64 + nf * 16 + l15;
          bf[nf] = *(const bf8*)&Wsp[n * 64 + (((ks * 4 + l4) ^ (n & 7)) << 3)];
        }
        #pragma unroll
        for (int mf = 0; mf < 2; ++mf)
          #pragma unroll
          for (int nf = 0; nf < 4; ++nf)
            acc[mf][nf] = __builtin_amdgcn_mfma_f32_16x16x32_bf16(af[mf], bf[nf], acc[mf][nf], 0, 0, 0);
      }
    }
    // tail prep (TF=1): wait for all T1/Wsp reads, then stage w5/w6 into dead LDS
    if constexpr (TF) {
      __syncthreads();
      float* W5L = (float*)SM;                  // 32x128 f32 over As+Ws region
      for (int i = tid; i < 32 * 128; i += 256) W5L[i] = p.tw5[i];
      for (int i = tid; i < CLS * 32; i += 256) W6s[i] = p.tw6[i];
    }
    #pragma unroll
    for (int mf = 0; mf < 2; ++mf) {
      #pragma unroll
      for (int i = 0; i < 4; ++i) {
        const int rl = wr * 32 + mf * 16 + l4 * 4 + i;
        const int r  = bm + rl;
        if (r >= p.M) continue;
        #pragma unroll
        for (int nf = 0; nf < 4; ++nf) {
          const int c = wc * 64 + nf * 16 + l15;
          float v = acc[mf][nf][i];
          if (q.bias) v += q.bias[c];
          if (q.bng)  v = v * (q.bng[c] / bnden) + q.bnb[c];
          if (q.act == 1)      v = fmaxf(v, 0.f);
          else if (q.act == 2) v = (v >= 0.f) ? v : 0.2f * v;
          if (q.omode == 0) {
            if (q.C) ((float*)q.C)[(size_t)r * 128 + c] = v;
          } else if (q.omode == 1) {
            ((u16*)q.C)[(size_t)r * 128 + c] = f2bf(v);
          } else {
            const int bb = r / HH, rr = r - bb * HH;
            ((u16*)q.C)[((size_t)(bb * 128 + c)) * 2048 + rr] = f2bf(v);
            // deterministically zero padding column 2047 (read by attn, P=0-masked)
            if (rr == HH - 1)
              ((u16*)q.C)[((size_t)(bb * 128 + c)) * 2048 + HH] = (u16)0;
          }
          if (q.Ct) {
            const int bb = r >> 13, rr = r & (NN - 1);
            q.Ct[((size_t)(bb * 128 + c)) * NN + rr] = v;
          }
          if constexpr (TF) {   // stash npo row (bf16, 4-bit swizzle) into Hs
            T1[rl * 128 + ((((c >> 3) ^ (rl & 15)) & 15) << 3) + (c & 7)] = f2bf(v);
          }
        }
      }
    }
  }

  // ===== fused tail: h5 + logits + log_softmax (4 threads per row) =====
  if constexpr (TF) {
    __syncthreads();
    const u16* Hs = T1;                  // [64][128] bf16 swizzled
    const float* W5L = (const float*)SM; // 32x128 f32
    const int tr = tid >> 2;             // row 0..63
    const int jq = (tid & 3) * 8;        // 8 h5-channels per thread
    float a[8];
    #pragma unroll
    for (int jj = 0; jj < 8; ++jj) a[jj] = 0.f;
    for (int c0 = 0; c0 < 128; c0 += 8) {
      const int sw = (((c0 >> 3) ^ (tr & 15)) & 15) << 3;
      const bf8 hx = *(const bf8*)&Hs[tr * 128 + sw];
      float xf[8];
      #pragma unroll
      for (int j = 0; j < 8; ++j) xf[j] = bf2f(((const u16*)&hx)[j]);
      #pragma unroll
      for (int jj = 0; jj < 8; ++jj) {
        const float4 w0 = *(const float4*)&W5L[(jq + jj) * 128 + c0];
        const float4 w1 = *(const float4*)&W5L[(jq + jj) * 128 + c0 + 4];
        a[jj] += xf[0]*w0.x + xf[1]*w0.y + xf[2]*w0.z + xf[3]*w0.w
               + xf[4]*w1.x + xf[5]*w1.y + xf[6]*w1.z + xf[7]*w1.w;
      }
    }
    float h[8];
    #pragma unroll
    for (int jj = 0; jj < 8; ++jj) {
      const int j = jq + jj;
      float v = a[jj] + p.tb5[j];
      v = v * (p.tg5[j] / bnden) + p.tbe5[j];
      h[jj] = fmaxf(v, 0.f);
    }
    float lg[CLS];
    float mx = -3.4e38f;
    #pragma unroll
    for (int o = 0; o < CLS; ++o) {
      float sp = (jq == 0) ? p.tb6[o] : 0.f;
      #pragma unroll
      for (int jj = 0; jj < 8; ++jj) sp += W6s[o * 32 + jq + jj] * h[jj];
      sp += __shfl_xor(sp, 1);
      sp += __shfl_xor(sp, 2);
      lg[o] = sp;
      mx = fmaxf(mx, sp);
    }
    float se = 0.f;
    #pragma unroll
    for (int o = 0; o < CLS; ++o) se += __expf(lg[o] - mx);
    const float lse = mx + __logf(se);
    if ((tid & 3) == 0) {
      float* orow = p.tout1 + (size_t)(bm + tr) * CLS;
      #pragma unroll
      for (int o = 0; o < CLS; ++o) orow[o] = lg[o] - lse;
    }
  }
}

// ======================= bf16-MFMA flash attention, KV-split by blockIdx.z
// QBLK=64, z=2; lazy-max + deferred sum + setprio + T14 register prefetch.
// Writes UNNORMALIZED acc; normalization folded into combA weights.
// NOTE: P-pack uses manual-RNE f2bf (inline-asm cvt_pk corrupted out0, R20).
__global__ __launch_bounds__(256) void attn_mfma_k(
    const u16* __restrict__ thetab,   // (B*N,128) bf16 rm
    const u16* __restrict__ phib,     // (B*H,128) bf16 rm
    const u16* __restrict__ gxT,      // (B,128,2048) bf16 (col 2047 zeroed)
    u16* __restrict__ yp,             // (2, B*N, 128) bf16 partials (unnormalized)
    float2* __restrict__ ml)          // (2, B*N) (m, l)
{
  __shared__ u16 Kt[64 * 128];
  __shared__ u16 Vt[128 * 64];
  __shared__ u16 Pt[64 * 64];
  const int b    = blockIdx.y;
  const int z    = blockIdx.z;
  const int row0 = blockIdx.x * 64;
  const int tid  = threadIdx.x;
  const int wave = tid >> 6;
  const int lane = tid & 63;
  const int l15  = lane & 15, l4 = lane >> 4;

  bf8 aq[4];
  {
    const u16* tq = thetab + ((size_t)(b * NN + row0 + wave * 16 + l15)) * 128;
    #pragma unroll
    for (int ks = 0; ks < 4; ++ks)
      aq[ks] = *(const bf8*)(tq + ks * 32 + l4 * 8);
  }

  f4 acc[8];
  #pragma unroll
  for (int i = 0; i < 8; ++i) acc[i] = (f4){0.f, 0.f, 0.f, 0.f};
  float mrow[4] = {-3e38f, -3e38f, -3e38f, -3e38f};
  float lrow[4] = {0.f, 0.f, 0.f, 0.f};   // per-lane partials

  const u16* phbase = phib + (size_t)b * HH * 128;
  const u16* gxbase = gxT  + (size_t)b * 128 * 2048;

  const int krow = tid >> 4, kch = tid & 15;
  const int vcol = tid >> 3, vch = tid & 7;

  bf8 kreg[4], vreg[4];
  auto loadregs = [&](int h0) {
    #pragma unroll
    for (int it = 0; it < 4; ++it) {
      const int r  = krow + it * 16;
      const int gp = h0 + r;
      bf8 vv = {0,0,0,0,0,0,0,0};
      if (gp < HH) vv = *(const bf8*)(phbase + (size_t)gp * 128 + kch * 8);
      kreg[it] = vv;
    }
    #pragma unroll
    for (int it = 0; it < 4; ++it) {
      const int c = vcol + it * 32;
      vreg[it] = *(const bf8*)(gxbase + (size_t)c * 2048 + h0 + vch * 8);
    }
  };
  auto writeLDS = [&]() {
    #pragma unroll
    for (int it = 0; it < 4; ++it) {
      const int r = krow + it * 16;
      *(bf8*)&Kt[r * 128 + ((kch ^ (r & 7)) << 3)] = kreg[it];
    }
    #pragma unroll
    for (int it = 0; it < 4; ++it) {
      const int c = vcol + it * 32;
      *(bf8*)&Vt[c * 64 + ((vch ^ (c & 7)) << 3)] = vreg[it];
    }
  };

  const int hbeg = z * 1024, hend = hbeg + 1024;
  loadregs(hbeg);
  for (int h0 = hbeg; h0 < hend; h0 += 64) {
    __syncthreads();
    writeLDS();
    if (h0 + 64 < hend) loadregs(h0 + 64);
    __syncthreads();

    f4 sacc[4];
    #pragma unroll
    for (int t = 0; t < 4; ++t) sacc[t] = (f4){0.f, 0.f, 0.f, 0.f};
    __builtin_amdgcn_s_setprio(1);
    #pragma unroll
    for (int ks = 0; ks < 4; ++ks) {
      #pragma unroll
      for (int t = 0; t < 4; ++t) {
        const int pr = t * 16 + l15;
        const int ch = (ks * 4 + l4) ^ (pr & 7);
        bf8 bk = *(const bf8*)&Kt[pr * 128 + ch * 8];
        sacc[t] = __builtin_amdgcn_mfma_f32_16x16x32_bf16(aq[ks], bk, sacc[t], 0, 0, 0);
      }
    }
    __builtin_amdgcn_s_setprio(0);
    if (h0 + 64 > HH) {
      #pragma unroll
      for (int t = 0; t < 4; ++t)
        if (h0 + t * 16 + l15 >= HH)
          sacc[t] = (f4){-3e38f, -3e38f, -3e38f, -3e38f};
    }

    // ---- lazy max
    float tl[4];
    #pragma unroll
    for (int r = 0; r < 4; ++r)
      tl[r] = fmaxf(fmaxf(sacc[0][r], sacc[1][r]), fmaxf(sacc[2][r], sacc[3][r]));
    const bool grow = (tl[0] > mrow[0]) | (tl[1] > mrow[1]) |
                      (tl[2] > mrow[2]) | (tl[3] > mrow[3]);
    if (__any(grow)) {
      #pragma unroll
      for (int r = 0; r < 4; ++r) {
        float tm = tl[r];
        tm = fmaxf(tm, __shfl_xor(tm, 1));
        tm = fmaxf(tm, __shfl_xor(tm, 2));
        tm = fmaxf(tm, __shfl_xor(tm, 4));
        tm = fmaxf(tm, __shfl_xor(tm, 8));
        const float mn = fmaxf(mrow[r], tm);
        const float sc = __expf(mrow[r] - mn);
        mrow[r] = mn;
        lrow[r] *= sc;
        #pragma unroll
        for (int ct = 0; ct < 8; ++ct) acc[ct][r] *= sc;
      }
    }
    // ---- exp + per-lane partial sum + P write (manual RNE pack)
    #pragma unroll
    for (int r = 0; r < 4; ++r) {
      float e[4];
      float ps = 0.f;
      #pragma unroll
      for (int t = 0; t < 4; ++t) {
        e[t] = __expf(sacc[t][r] - mrow[r]);
        ps += e[t];
      }
      lrow[r] += ps;
      const int prow = wave * 16 + l4 * 4 + r;
      #pragma unroll
      for (int t = 0; t < 4; ++t) {
        const int col = t * 16 + l15;
        const int scol = (((col >> 3) ^ (prow & 7)) << 3) | (col & 7);
        Pt[prow * 64 + scol] = f2bf(e[t]);
      }
    }

    __builtin_amdgcn_s_setprio(1);
    #pragma unroll
    for (int ks = 0; ks < 2; ++ks) {
      const int prow2 = wave * 16 + l15;
      bf8 pa = *(const bf8*)&Pt[prow2 * 64 + (((ks * 4 + l4) ^ (prow2 & 7)) << 3)];
      #pragma unroll
      for (int ct = 0; ct < 8; ++ct) {
        const int c  = ct * 16 + l15;
        const int ch = (ks * 4 + l4) ^ (c & 7);
        bf8 bv = *(const bf8*)&Vt[c * 64 + ch * 8];
        acc[ct] = __builtin_amdgcn_mfma_f32_16x16x32_bf16(pa, bv, acc[ct], 0, 0, 0);
      }
    }
    __builtin_amdgcn_s_setprio(0);
  }

  // final sum reduce (once) -- l needed for the combine denominator
  #pragma unroll
  for (int r = 0; r < 4; ++r) {
    float lr = lrow[r];
    lr += __shfl_xor(lr, 1); lr += __shfl_xor(lr, 2);
    lr += __shfl_xor(lr, 4); lr += __shfl_xor(lr, 8);
    lrow[r] = lr;
  }

  const size_t rbase = (size_t)z * BB * NN + (size_t)b * NN + row0 + wave * 16 + l4 * 4;
  u16* yo = yp + rbase * 128;
  #pragma unroll
  for (int r = 0; r < 4; ++r) {
    #pragma unroll
    for (int ct = 0; ct < 8; ++ct)
      yo[(size_t)r * 128 + ct * 16 + l15] = f2bf(acc[ct][r]);
    if (l15 == 0) ml[rbase + r] = make_float2(mrow[r], lrow[r]);
  }
}

// ======================= diff[b,n] = sum_k sum_c (flat[idx1]-xt)^2
// 8 points per 256-thread block; 32 lanes/point; uint2 (8B) loads.
__global__ __launch_bounds__(256) void diff_k(const u16* __restrict__ xtb,
                                              const int* __restrict__ idx1,
                                              float* __restrict__ diff) {
  const int tid = threadIdx.x;
  const int sub = tid >> 5, ln = tid & 31;
  const int bn  = blockIdx.x * 8 + sub;
  const uint2 xcp = *(const uint2*)(xtb + (size_t)bn * CO + ln * 4);
  const float x0 = bf2f((u16)(xcp.x & 0xFFFFu)), x1 = bf2f((u16)(xcp.x >> 16));
  const float x2 = bf2f((u16)(xcp.y & 0xFFFFu)), x3 = bf2f((u16)(xcp.y >> 16));
  const int* id = idx1 + (size_t)bn * KNB;
  float acc = 0.f;
  #pragma unroll 4
  for (int k = 0; k < KNB; ++k) {
    const int ix = id[k];
    const uint2 vp = *(const uint2*)(xtb + (size_t)ix * CO + ln * 4);
    const float d0 = bf2f((u16)(vp.x & 0xFFFFu)) - x0;
    const float d1 = bf2f((u16)(vp.x >> 16))     - x1;
    const float d2 = bf2f((u16)(vp.y & 0xFFFFu)) - x2;
    const float d3 = bf2f((u16)(vp.y >> 16))     - x3;
    acc += d0*d0 + d1*d1 + d2*d2 + d3*d3;
  }
  #pragma unroll
  for (int o = 1; o <= 16; o <<= 1) acc += __shfl_xor(acc, o);
  if (ln == 0) diff[bn] = acc;
}

// ======================= per-batch top-1638 SET via 4-round radix select
// DETERMINISTIC placement: prefix-scan positions (replay-invariant Hidx order).
__global__ __launch_bounds__(1024) void topsel_k(const float* __restrict__ diff,
                                                 InnerArgs ia,
                                                 int* __restrict__ Hidx) {
  __shared__ uint32_t hist[256];
  __shared__ uint32_t sh_T, sh_need, sh_eqc;
  __shared__ int      sh_eq[1024];
  __shared__ uint32_t scn[1024];
  const int b = blockIdx.x, tid = threadIdx.x;
  const float* db = diff + (size_t)b * NN;
  uint32_t v[8];
  #pragma unroll
  for (int i = 0; i < 8; ++i) v[i] = __float_as_uint(db[tid * 8 + i]);
  if (tid == 0) { sh_T = 0u; sh_need = OUTER; sh_eqc = 0u; }
  #pragma unroll
  for (int round = 0; round < 4; ++round) {
    const int shift = 24 - 8 * round;
    for (int i = tid; i < 256; i += 1024) hist[i] = 0u;
    __syncthreads();
    const uint32_t Tpart  = sh_T;
    const uint32_t maskHi = (round == 0) ? 0u : (0xFFFFFFFFu << (shift + 8));
    #pragma unroll
    for (int i = 0; i < 8; ++i)
      if ((v[i] & maskHi) == (Tpart & maskHi))
        atomicAdd(&hist[(v[i] >> shift) & 255u], 1u);
    __syncthreads();
    if (tid == 0) {
      uint32_t need = sh_need, accn = 0u;
      int bsel = 0;
      for (int bin = 255; bin >= 0; --bin) {
        uint32_t h = hist[bin];
        if (accn + h >= need) { bsel = bin; break; }
        accn += h;
      }
      sh_T = Tpart | ((uint32_t)bsel << shift);
      sh_need = need - accn;
    }
    __syncthreads();
  }
  const uint32_t T   = sh_T;
  const uint32_t rem = sh_need;

  // deterministic exclusive scan of per-thread ">" counts
  uint32_t cnt = 0;
  #pragma unroll
  for (int i = 0; i < 8; ++i) cnt += (v[i] > T) ? 1u : 0u;
  scn[tid] = cnt;
  __syncthreads();
  for (int off = 1; off < 1024; off <<= 1) {
    uint32_t t = (tid >= off) ? scn[tid - off] : 0u;
    __syncthreads();
    scn[tid] += t;
    __syncthreads();
  }
  uint32_t pos = scn[tid] - cnt;   // exclusive prefix (index-ordered placement)
  #pragma unroll
  for (int i = 0; i < 8; ++i) {
    const int idx = tid * 8 + i;
    if (v[i] > T) {
      Hidx[b * HH + (int)(pos++)] = idx;
    } else if (v[i] == T) {
      uint32_t e = atomicAdd(&sh_eqc, 1u);
      if (e < 1024u) sh_eq[e] = idx;
    }
  }
  __syncthreads();
  if (tid == 0) {
    const uint32_t C = OUTER - rem;          // #(v > T) is exactly OUTER - rem
    uint32_t eqc = sh_eqc < 1024u ? sh_eqc : 1024u;
    for (uint32_t j = 0; j < rem && j < eqc; ++j) {
      int best = 0x7fffffff, bi = 0;
      for (uint32_t t = 0; t < eqc; ++t)
        if (sh_eq[t] < best) { best = sh_eq[t]; bi = (int)t; }
      Hidx[b * HH + C + j] = best;
      sh_eq[bi] = 0x7fffffff;
    }
  }
  if (tid < INNER) Hidx[b * HH + OUTER + tid] = ia.v[tid];
}

} // anonymous namespace

// ===========================================================================
extern "C" void kernel_launch(void* const* d_in, const int* in_sizes, int n_in,
                              void* d_out, int out_size, void* d_ws, size_t ws_size,
                              hipStream_t stream) {
  const float* xyz1    = (const float*)d_in[0];
  const float* xyz2    = (const float*)d_in[1];
  const float* points1 = (const float*)d_in[2];
  const float* points2 = (const float*)d_in[3];
  const float* lastpred= (const float*)d_in[5];
  const float* w_mlp0  = (const float*)d_in[6];
  const float* b_mlp0  = (const float*)d_in[7];
  const float* g_bn0   = (const float*)d_in[8];
  const float* be_bn0  = (const float*)d_in[9];
  const float* w_mlp1  = (const float*)d_in[10];
  const float* b_mlp1  = (const float*)d_in[11];
  const float* g_bn1   = (const float*)d_in[12];
  const float* be_bn1  = (const float*)d_in[13];
  const float* w_h     = (const float*)d_in[14];
  const float* g_hbn   = (const float*)d_in[15];
  const float* be_hbn  = (const float*)d_in[16];
  const float* w_outm  = (const float*)d_in[17];
  const float* g_obn   = (const float*)d_in[18];
  const float* be_obn  = (const float*)d_in[19];
  const float* w_g     = (const float*)d_in[20];
  const float* b_g     = (const float*)d_in[21];
  const float* w_theta = (const float*)d_in[22];
  const float* b_theta = (const float*)d_in[23];
  const float* w_phi   = (const float*)d_in[24];
  const float* b_phi   = (const float*)d_in[25];
  const float* w_W     = (const float*)d_in[26];
  const float* b_W     = (const float*)d_in[27];
  const float* g_Wbn   = (const float*)d_in[28];
  const float* be_Wbn  = (const float*)d_in[29];
  const float* w5      = (const float*)d_in[30];
  const float* b5      = (const float*)d_in[31];
  const float* g_bn5   = (const float*)d_in[32];
  const float* be_bn5  = (const float*)d_in[33];
  const float* w6      = (const float*)d_in[34];
  const float* b6      = (const float*)d_in[35];
  const int*   idx_1   = (const int*)d_in[36];

  float* out0 = (float*)d_out;
  float* out1 = out0 + (size_t)BB * CO * NN;

  char* base = (char*)d_ws;
  size_t off = 0;
  auto alloc = [&](size_t bytes) -> char* {
    char* p = base + off;
    off += (bytes + 255) & ~(size_t)255;
    return p;
  };
  float* diff   = (float*)alloc((size_t)BB * NN * 4);
  int*   Hidx   = (int*)  alloc((size_t)BB * HH * 4);
  float* preds  = (float*)alloc((size_t)BB * NN * CLS * 4);
  float* xt     = (float*)alloc((size_t)BB * NN * CO * 4);
  u16*   xtb    = (u16*)  alloc((size_t)BB * NN * CO * 2);
  u16*   phib   = (u16*)  alloc((size_t)BB * HH * CO * 2);
  u16*   gxT    = (u16*)  alloc((size_t)BB * CO * 2048 * 2);
  float2* mlbuf = (float2*)alloc((size_t)2 * BB * NN * 8);
  u16*   wbuf   = (u16*)  alloc((size_t)270336 * 2);
  char*  R1     =         alloc((size_t)BB * NN * 512 * 2);     // 33.5MB
  char*  R2     =         alloc((size_t)BB * NN * 256 * 2);     // 16MB
  if (off > ws_size) return;   // insufficient scratch (diagnostic)

  // weight bf16 buffers inside wbuf
  u16* w0b = wbuf;                 // 256x512
  u16* w1b = w0b + 256 * 512;      // 128x256
  u16* whb = w1b + 128 * 256;      // 128x192 (149 padded)
  u16* wgb = whb + 128 * 192;      // 128x128
  u16* wtb = wgb + 128 * 128;
  u16* wpb = wtb + 128 * 128;
  u16* wWb = wpb + 128 * 128;
  u16* wob = wWb + 128 * 128;

  // region aliases (lifetimes disjoint)
  u16*   A0     = (u16*)R1;                                     // prep..mlp0
  u16*   thetab = (u16*)R1;                                     // mlp1..attn (8MB)
  u16*   yp     = (u16*)(R1 + (size_t)8 * 1024 * 1024);         // attn..Wgemm (16MB)
  float* p2t    = (float*)R2;                                   // prep..knn_interp (8MB)
  u16*   x2b    = (u16*)R2;                                     // mlp0..mlp1 (16MB)

  // host RNG for inner indices (baked into topsel kernargs)
  InnerArgs ia;
  compute_inner_host(ia.v);

  // 1. merged prep: points2 transpose + points1 cvt + weight cvt
  {
    WcvAll wa;
    wa.e[0] = {w_mlp0, w0b, 256, 512, 512};
    wa.e[1] = {w_mlp1, w1b, 128, 256, 256};
    wa.e[2] = {w_h,    whb, 128, 149, 192};
    wa.e[3] = {w_g,    wgb, 128, 128, 128};
    wa.e[4] = {w_theta,wtb, 128, 128, 128};
    wa.e[5] = {w_phi,  wpb, 128, 128, 128};
    wa.e[6] = {w_W,    wWb, 128, 128, 128};
    wa.e[7] = {w_outm, wob, 128, 128, 128};
    prep1_k<<<6400, 256, 0, stream>>>(points2, p2t, points1, A0, wa);
  }

  // 2. fused 3-NN + interpolation -> A0 cols 256..511 (bf16) + preds f32
  knn_interp_k<<<dim3(NN/16, BB), 256, 0, stream>>>(xyz1, xyz2, p2t, lastpred, A0, preds);

  // 3. mlp0: relu(bn0(W0·A0 + b0)) -> x2b bf16
  {
    MgP p{};
    p.A = A0; p.W = w0b; p.bias = b_mlp0; p.bng = g_bn0; p.bnb = be_bn0;
    p.C = x2b; p.M = BB * NN; p.Nc = 256; p.K = 512; p.act = 1; p.omode = 1;
    mgemm_k<<<dim3(2, 256), 256, 0, stream>>>(p);
  }
  // 4. mlp1 (-> xtb bf16 + xt f32) fused with theta -> thetab   [TF=0, 64-row tiles]
  {
    Mg2P p{};
    p.A = x2b; p.W = w1b; p.bias = b_mlp1; p.bng = g_bn1; p.bnb = be_bn1;
    p.C1 = xtb; p.writeC1 = 1; p.C2f = xt;
    p.M = BB * NN; p.K = 256; p.act = 1; p.n2 = 1;
    p.s2[0] = {wtb, b_theta, nullptr, nullptr, 0, 1, thetab, nullptr};
    mgemm2_k<0><<<dim3(1, 512), 256, 0, stream>>>(p);
  }

  // 5. KNN feature variance score (8 pts/block, 8B loads)
  diff_k<<<BB * NN / 8, 256, 0, stream>>>(xtb, idx_1, diff);

  // 6. per-batch top-1638 set via deterministic radix select
  topsel_k<<<BB, 1024, 0, stream>>>(diff, ia, Hidx);

  // 7. conv_h (A gathered via Hidx) fused with g_x and phi [TF=0, 64-row tiles]
  {
    Mg2P p{};
    p.W = whb; p.bng = g_hbn; p.bnb = be_hbn;
    p.gxtb = xtb; p.gpreds = preds; p.gHidx = Hidx; p.gatherA = 1;
    p.writeC1 = 0; p.M = BB * HH; p.K = 192; p.act = 2; p.n2 = 2;
    p.s2[0] = {wgb, b_g,   nullptr, nullptr, 0, 2, gxT,  nullptr};
    p.s2[1] = {wpb, b_phi, nullptr, nullptr, 0, 1, phib, nullptr};
    mgemm2_k<0><<<dim3(1, 128), 256, 0, stream>>>(p);
  }

  // 8. MFMA flash attention, KV-split x2 -> unnormalized partials
  attn_mfma_k<<<dim3(NN/64, BB, 2), 256, 0, stream>>>(thetab, phib, gxT, yp, mlbuf);

  // 9. combine(yp) -> z = bn_W(W_W·y + b_W) + xt, fused with outm;
  // stage-2 writes out0 transposed + fused tail -> out1. [TF=1, 64-row tiles]
  {
    Mg2P p{};
    p.W = wWb; p.bias = b_W; p.bng = g_Wbn; p.bnb = be_Wbn; p.res = xt;
    p.ypA = yp; p.mlA = mlbuf; p.combA = 1;
    p.writeC1 = 0; p.M = BB * NN; p.K = 128; p.act = 0; p.n2 = 1;
    p.s2[0] = {wob, nullptr, g_obn, be_obn, 2, 0, nullptr, out0};
    p.tw5 = w5; p.tb5 = b5; p.tg5 = g_bn5; p.tbe5 = be_bn5;
    p.tw6 = w6; p.tb6 = b6; p.tout1 = out1; p.tailfuse = 1;
    mgemm2_k<1><<<dim3(1, 512), 256, 0, stream>>>(p);
  }
}

// Round 25
// 396.522 us; speedup vs baseline: 1.2507x; 1.0635x over previous
//
#include <hip/hip_runtime.h>
#include <stdint.h>
#include <string.h>
#include <math.h>

// ---------------------------------------------------------------------------
// IAF_PointNetFeaturePropagation: bf16-MFMA fused GEMM chain + split flash attn.
// B=4, N=8192, S=2048, K=20, D1=D2=256, CO=128, CLS=21, H=1638+409=2047
// ---------------------------------------------------------------------------

namespace {

constexpr int BB   = 4;
constexpr int NN   = 8192;
constexpr int SS   = 2048;
constexpr int KNB  = 20;
constexpr int CO   = 128;
constexpr int CLS  = 21;
constexpr int HH   = 2047;
constexpr int OUTER= 1638;
constexpr int INNER= 409;

typedef unsigned short u16;
typedef short bf8 __attribute__((ext_vector_type(8)));   // 8 bf16 in 4 VGPRs
typedef float f4  __attribute__((ext_vector_type(4)));   // MFMA accumulator

__device__ inline u16 f2bf(float f) {                    // round-nearest-even
  uint32_t x = __float_as_uint(f);
  return (u16)((x + 0x7FFFu + ((x >> 16) & 1u)) >> 16);
}
__device__ inline float bf2f(u16 v) {
  return __uint_as_float((uint32_t)v << 16);
}

// ======================= numpy default_rng(0).choice(8192,409) on the HOST
struct InnerArgs { int v[INNER]; };

static void compute_inner_host(int* out) {
  uint32_t pool[4];
  uint32_t hc = 0x43b0d7e5u;
  auto hashmix = [&hc](uint32_t v) -> uint32_t {
    v ^= hc; hc *= 0x931e8875u; v *= hc; v ^= v >> 16; return v;
  };
  auto mixf = [](uint32_t x, uint32_t y) -> uint32_t {
    uint32_t r = x * 0xca01f9ddu; r ^= y * 0x4973f715u; r ^= r >> 16; return r;
  };
  pool[0] = hashmix(0u); pool[1] = hashmix(0u);
  pool[2] = hashmix(0u); pool[3] = hashmix(0u);
  for (int s = 0; s < 4; ++s)
    for (int d = 0; d < 4; ++d)
      if (s != d) pool[d] = mixf(pool[d], hashmix(pool[s]));

  uint32_t st32[8];
  uint32_t hb = 0x8b51f9ddu;
  for (int i = 0; i < 8; ++i) {
    uint32_t dv = pool[i & 3];
    dv ^= hb; hb *= 0x58f38dedu; dv *= hb; dv ^= dv >> 16;
    st32[i] = dv;
  }
  uint64_t s64[4];
  for (int i = 0; i < 4; ++i)
    s64[i] = (uint64_t)st32[2*i] | ((uint64_t)st32[2*i+1] << 32);

  typedef unsigned __int128 u128;
  const u128 MUL = ((u128)2549297995355413924ull << 64) | (u128)4865540595714422341ull;
  u128 inc   = (((((u128)s64[2]) << 64) | (u128)s64[3]) << 1) | 1;
  u128 state = inc;
  state += (((u128)s64[0]) << 64) | (u128)s64[1];
  state = state * MUL + inc;

  bool has32 = false; uint32_t buf32 = 0;
  auto next32 = [&]() -> uint32_t {
    if (has32) { has32 = false; return buf32; }
    state = state * MUL + inc;
    uint64_t hi = (uint64_t)(state >> 64), lo = (uint64_t)state;
    uint64_t x = hi ^ lo;
    unsigned rot = (unsigned)(state >> 122);
    uint64_t v = (x >> rot) | (x << ((64u - rot) & 63u));
    has32 = true; buf32 = (uint32_t)(v >> 32);
    return (uint32_t)v;
  };

  uint64_t hs[512];
  memset(hs, 0xFF, sizeof(hs));
  for (int j = NN - INNER; j < NN; ++j) {
    uint32_t rng = (uint32_t)j, rng_excl = rng + 1u;
    uint64_t m = (uint64_t)next32() * (uint64_t)rng_excl;
    uint32_t leftover = (uint32_t)m;
    if (leftover < rng_excl) {
      uint32_t threshold = (0xFFFFFFFFu - rng) % rng_excl;
      while (leftover < threshold) {
        m = (uint64_t)next32() * (uint64_t)rng_excl;
        leftover = (uint32_t)m;
      }
    }
    uint64_t val = m >> 32;
    uint32_t loc = (uint32_t)val & 511u;
    while (hs[loc] != ~0ull && hs[loc] != val) loc = (loc + 1u) & 511u;
    uint64_t chosen;
    if (hs[loc] == ~0ull) { hs[loc] = val; chosen = val; }
    else                  { hs[loc] = (uint64_t)j; chosen = (uint64_t)j; }
    out[j - (NN - INNER)] = (int)chosen;
  }
}

// ======================= weight f32 -> bf16 descriptor
struct WcvP { const float* src; u16* dst; int rows; int K; int Kpad; };
struct WcvAll { WcvP e[8]; };

// ======================= merged prep: transpose2 | tcvt | wcvt (one dispatch)
__global__ __launch_bounds__(256) void prep1_k(const float* __restrict__ points2,
                                               float* __restrict__ p2t,
                                               const float* __restrict__ points1,
                                               u16* __restrict__ A0,
                                               WcvAll wa) {
  const int t = blockIdx.x;
  const int tid = threadIdx.x;
  __shared__ float sh[64][33];
  if (t < 2048) {
    const int b = t >> 9, rest = t & 511;
    const int c0 = (rest & 63) * 32, r0 = (rest >> 6) * 32;
    const float* ib = points2 + (size_t)b * 256 * SS;
    float*       ob = p2t    + (size_t)b * SS * 256;
    const int tx = tid & 31, ty = tid >> 5;
    #pragma unroll
    for (int i = 0; i < 32; i += 8)
      sh[ty + i][tx] = ib[(size_t)(r0 + ty + i) * SS + c0 + tx];
    __syncthreads();
    #pragma unroll
    for (int i = 0; i < 32; i += 8)
      ob[(size_t)(c0 + ty + i) * 256 + r0 + tx] = sh[tx][ty + i];
  } else if (t < 6144) {
    const int u = t - 2048;
    const int b = u >> 10, c0 = ((u >> 8) & 3) * 64, n0 = (u & 255) * 32;
    {
      const int tn = tid & 31, tc0 = tid >> 5;
      #pragma unroll
      for (int i = 0; i < 8; ++i) {
        const int c = tc0 * 8 + i;
        sh[c][tn] = points1[((size_t)b * 256 + c0 + c) * NN + n0 + tn];
      }
    }
    __syncthreads();
    {
      const int cg = tid & 7, n = tid >> 3;
      u16 tmp[8];
      #pragma unroll
      for (int j = 0; j < 8; ++j) tmp[j] = f2bf(sh[cg * 8 + j][n]);
      *(bf8*)&A0[((size_t)b * NN + n0 + n) * 512 + c0 + cg * 8] = *(bf8*)tmp;
    }
  } else {
    const int w = t - 6144;
    WcvP p = wa.e[w >> 5];
    const int xb = w & 31;
    const int total = p.rows * p.Kpad;
    for (int i = xb * 256 + tid; i < total; i += 32 * 256) {
      const int r = i / p.Kpad, k = i - r * p.Kpad;
      p.dst[i] = (k < p.K) ? f2bf(p.src[(size_t)r * p.K + k]) : (u16)0;
    }
  }
}

// ======================= fused 3-NN + interpolation (16 points per block)
__global__ __launch_bounds__(256) void knn_interp_k(const float* __restrict__ xyz1,
                                                    const float* __restrict__ xyz2,
                                                    const float* __restrict__ p2t,
                                                    const float* __restrict__ lastpred,
                                                    u16* __restrict__ A0,
                                                    float* __restrict__ preds) {
  __shared__ float4 P2[SS];
  __shared__ int   sidx[16][3];
  __shared__ float sw[16][3];
  const int b = blockIdx.y;
  const float* x2 = xyz2 + (size_t)b * SS * 3;
  for (int i = threadIdx.x; i < SS; i += 256) {
    float x = x2[i*3], y = x2[i*3+1], z = x2[i*3+2];
    P2[i] = make_float4(x, y, z, x*x + y*y + z*z);
  }
  __syncthreads();
  const int tid   = threadIdx.x;
  const int chunk = tid & 15;
  const int pt    = tid >> 4;
  const int n     = blockIdx.x * 16 + pt;
  const float* p  = xyz1 + ((size_t)b * NN + n) * 3;
  const float px = p[0], py = p[1], pz = p[2];
  const float ss1 = px*px + py*py + pz*pz;
  float d0 = 3.4e38f, d1 = 3.4e38f, d2 = 3.4e38f;
  int   i0 = 0, i1 = 0, i2 = 0;
  auto ins = [&](float d, int s) {
    const bool c0 = d < d0, c1 = d < d1, c2 = d < d2;
    const float nd0 = c0 ? d  : d0;
    const int   nj0 = c0 ? s  : i0;
    const float nd1 = c0 ? d0 : (c1 ? d : d1);
    const int   nj1 = c0 ? i0 : (c1 ? s : i1);
    const float nd2 = c1 ? d1 : (c2 ? d : d2);
    const int   nj2 = c1 ? i1 : (c2 ? s : i2);
    d0 = nd0; d1 = nd1; d2 = nd2;
    i0 = nj0; i1 = nj1; i2 = nj2;
  };
  #pragma unroll 8
  for (int i = 0; i < 128; ++i) {
    const int s = chunk + (i << 4);
    const float4 q = P2[s];
    float d = (ss1 + q.w) - 2.0f * (px*q.x + py*q.y + pz*q.z);
    ins(d, s);
  }
  #pragma unroll
  for (int off = 1; off <= 8; off <<= 1) {
    float e0 = __shfl_xor(d0, off), e1 = __shfl_xor(d1, off), e2 = __shfl_xor(d2, off);
    int   j0 = __shfl_xor(i0, off), j1 = __shfl_xor(i1, off), j2 = __shfl_xor(i2, off);
    ins(e0, j0); ins(e1, j1); ins(e2, j2);
  }
  if (chunk == 0) {
    d0 = fmaxf(d0, 1e-10f); d1 = fmaxf(d1, 1e-10f); d2 = fmaxf(d2, 1e-10f);
    float w0 = 1.f/d0, w1 = 1.f/d1, w2 = 1.f/d2;
    float ws = w0 + w1 + w2;
    sidx[pt][0] = i0; sidx[pt][1] = i1; sidx[pt][2] = i2;
    sw[pt][0] = w0/ws; sw[pt][1] = w1/ws; sw[pt][2] = w2/ws;
  }
  __syncthreads();

  const int n0 = blockIdx.x * 16;
  const float* pb = p2t + (size_t)b * SS * 256;
  const float* lp = lastpred + (size_t)b * SS * CLS;
  const int c = tid;
  #pragma unroll 4
  for (int q = 0; q < 16; ++q) {
    const size_t o = (size_t)b * NN + n0 + q;
    const int j0 = sidx[q][0], j1 = sidx[q][1], j2 = sidx[q][2];
    const float w0 = sw[q][0], w1 = sw[q][1], w2 = sw[q][2];
    const float v = w0 * pb[(size_t)j0*256 + c]
                  + w1 * pb[(size_t)j1*256 + c]
                  + w2 * pb[(size_t)j2*256 + c];
    A0[o*512 + 256 + c] = f2bf(v);
    if (c < CLS)
      preds[o*CLS + c] = w0 * lp[j0*CLS + c] + w1 * lp[j1*CLS + c] + w2 * lp[j2*CLS + c];
  }
}

// ======================= bf16 MFMA GEMM, 128x128 tile, T14 reg-prefetch staging
struct MgP {
  const u16* A; const u16* W;
  const float* bias; const float* bng; const float* bnb; const float* res;
  void* C; float* C2;
  int M, Nc, K, act, omode;
};

__global__ __launch_bounds__(256) void mgemm_k(MgP p) {
  __shared__ u16 As[128 * 64];
  __shared__ u16 Ws[128 * 64];
  const int tid = threadIdx.x;
  const int wave = tid >> 6, lane = tid & 63;
  const int l15 = lane & 15, l4 = lane >> 4;
  const int wr = wave >> 1, wc = wave & 1;
  const int bm = blockIdx.y * 128, bn = blockIdx.x * 128;
  const int srow = tid >> 3, sch = tid & 7;

  f4 acc[4][4];
  #pragma unroll
  for (int i = 0; i < 4; ++i)
    #pragma unroll
    for (int j = 0; j < 4; ++j) acc[i][j] = (f4){0.f, 0.f, 0.f, 0.f};

  bf8 vA[4], vB[4];
  auto loadT = [&](int k0) {
    #pragma unroll
    for (int it = 0; it < 4; ++it) {
      const int r = srow + it * 32;
      const int gm = bm + r;
      bf8 va = {0,0,0,0,0,0,0,0};
      if (gm < p.M) va = *(const bf8*)(p.A + (size_t)gm * p.K + k0 + sch * 8);
      vA[it] = va;
      const int gn = bn + r;
      bf8 vb = {0,0,0,0,0,0,0,0};
      if (gn < p.Nc) vb = *(const bf8*)(p.W + (size_t)gn * p.K + k0 + sch * 8);
      vB[it] = vb;
    }
  };
  auto writeT = [&]() {
    #pragma unroll
    for (int it = 0; it < 4; ++it) {
      const int r = srow + it * 32;
      *(bf8*)&As[r * 64 + ((sch ^ (r & 7)) << 3)] = vA[it];
      *(bf8*)&Ws[r * 64 + ((sch ^ (r & 7)) << 3)] = vB[it];
    }
  };

  loadT(0);
  for (int k0 = 0; k0 < p.K; k0 += 64) {
    __syncthreads();
    writeT();
    if (k0 + 64 < p.K) loadT(k0 + 64);
    __syncthreads();
    #pragma unroll
    for (int ks = 0; ks < 2; ++ks) {
      bf8 af[4], bf[4];
      #pragma unroll
      for (int mf = 0; mf < 4; ++mf) {
        int m = wr * 64 + mf * 16 + l15;
        af[mf] = *(const bf8*)&As[m * 64 + (((ks * 4 + l4) ^ (m & 7)) << 3)];
      }
      #pragma unroll
      for (int nf = 0; nf < 4; ++nf) {
        int n = wc * 64 + nf * 16 + l15;
        bf[nf] = *(const bf8*)&Ws[n * 64 + (((ks * 4 + l4) ^ (n & 7)) << 3)];
      }
      #pragma unroll
      for (int mf = 0; mf < 4; ++mf)
        #pragma unroll
        for (int nf = 0; nf < 4; ++nf)
          acc[mf][nf] = __builtin_amdgcn_mfma_f32_16x16x32_bf16(af[mf], bf[nf], acc[mf][nf], 0, 0, 0);
    }
  }

  const float bnden = sqrtf(1.0f + 1e-5f);
  #pragma unroll
  for (int mf = 0; mf < 4; ++mf) {
    #pragma unroll
    for (int i = 0; i < 4; ++i) {
      const int r = bm + wr * 64 + mf * 16 + l4 * 4 + i;
      if (r >= p.M) continue;
      #pragma unroll
      for (int nf = 0; nf < 4; ++nf) {
        const int c = bn + wc * 64 + nf * 16 + l15;
        float v = acc[mf][nf][i];
        if (p.bias) v += p.bias[c];
        if (p.bng)  v = v * (p.bng[c] / bnden) + p.bnb[c];
        if (p.res)  v += p.res[(size_t)r * p.Nc + c];
        if (p.act == 1)      v = fmaxf(v, 0.f);
        else if (p.act == 2) v = (v >= 0.f) ? v : 0.2f * v;
        if (p.omode == 0) {
          ((float*)p.C)[(size_t)r * p.Nc + c] = v;
        } else if (p.omode == 1) {
          ((u16*)p.C)[(size_t)r * p.Nc + c] = f2bf(v);
        } else {
          const int bb = r / HH, rr = r - bb * HH;
          ((u16*)p.C)[((size_t)(bb * p.Nc + c)) * 2048 + rr] = f2bf(v);
        }
        if (p.C2) p.C2[(size_t)r * p.Nc + c] = v;
      }
    }
  }
}

// ======================= two-stage fused bf16 GEMM, 64-row M-tiles (2+ blk/CU)
// TF=0: plain/gatherA variants. TF=1: combA (KV-split partial merge). No tail.
// SM(u16): As[0,4096) | Ws[4096,12288) | T1[12288 + half*4096), half in {0,1}
struct S2d { const u16* W; const float* bias; const float* bng; const float* bnb;
             int act; int omode; void* C; float* Ct; };
struct Mg2P {
  const u16* A; const u16* W;
  const float* bias; const float* bng; const float* bnb; const float* res;
  void* C1; float* C2f;
  const u16* ypA; const float2* mlA; int combA;
  const u16* gxtb; const float* gpreds; const int* gHidx; int gatherA;
  int M, K, act, writeC1, n2;
  S2d s2[2];
};

template <int TF>
__global__ __launch_bounds__(256) void mgemm2_k(Mg2P p) {
  __shared__ u16 SM[20480];                        // 40KB
  __shared__ float XL[TF ? 128 : 1];               // cw[64][2]
  float* const cw  = XL;
  u16* const As  = SM;          // 64 x 64
  u16* const Wsp = SM + 4096;   // 128 x 64
  u16* const T1  = SM + 12288;  // 2 halves x 64 x 64
  const int tid = threadIdx.x;
  const int wave = tid >> 6, lane = tid & 63;
  const int l15 = lane & 15, l4 = lane >> 4;
  const int wr = wave >> 1, wc = wave & 1;   // 2x2 waves: 32 rows x 64 cols each
  const int bm = blockIdx.y * 64;
  const int srow = tid >> 3, sch = tid & 7;  // srow in [0,32)

  if constexpr (TF) {
    if (p.combA) {
      if (tid < 64) {
        const int gm = bm + tid;
        const float2 a0 = p.mlA[gm];
        const float2 a1 = p.mlA[(size_t)BB * NN + gm];
        const float mm = fmaxf(a0.x, a1.x);
        const float w0 = __expf(a0.x - mm);
        const float w1 = __expf(a1.x - mm);
        const float inv = 1.0f / (w0 * a0.y + w1 * a1.y);
        cw[tid * 2 + 0] = w0 * inv;
        cw[tid * 2 + 1] = w1 * inv;
      }
      __syncthreads();   // cw visible before prefetch reads it
    }
  }

  f4 acc[2][4];
  #pragma unroll
  for (int i = 0; i < 2; ++i)
    #pragma unroll
    for (int j = 0; j < 4; ++j) acc[i][j] = (f4){0.f, 0.f, 0.f, 0.f};

  bf8 vA[2], vB[4];
  auto loadT = [&](int k0) {
    #pragma unroll
    for (int it = 0; it < 2; ++it) {           // A: 64 rows
      const int r = srow + it * 32;
      const int gm = bm + r;
      bf8 va = {0,0,0,0,0,0,0,0};
      if (gm < p.M) {
        if constexpr (TF) {
          const float w0 = cw[r * 2 + 0], w1 = cw[r * 2 + 1];
          const bf8 y0 = *(const bf8*)(p.ypA + (size_t)gm * 128 + k0 + sch * 8);
          const bf8 y1 = *(const bf8*)(p.ypA + ((size_t)BB * NN + gm) * 128 + k0 + sch * 8);
          u16 tmp[8];
          #pragma unroll
          for (int j = 0; j < 8; ++j)
            tmp[j] = f2bf(w0 * bf2f(((const u16*)&y0)[j]) +
                          w1 * bf2f(((const u16*)&y1)[j]));
          va = *(bf8*)tmp;
        } else {
          if (p.gatherA) {
            const int gb = gm / HH, gh = gm - gb * HH;
            const int src = p.gHidx[gb * HH + gh];
            const size_t sr = (size_t)gb * NN + src;
            const int colbase = k0 + sch * 8;
            if (colbase < CO) {
              va = *(const bf8*)(p.gxtb + sr * CO + colbase);
            } else {
              u16 tmp[8];
              #pragma unroll
              for (int j = 0; j < 8; ++j) {
                const int col = colbase + j;
                tmp[j] = (col < CO + CLS) ? f2bf(p.gpreds[sr * CLS + (col - CO)]) : (u16)0;
              }
              va = *(bf8*)tmp;
            }
          } else {
            va = *(const bf8*)(p.A + (size_t)gm * p.K + k0 + sch * 8);
          }
        }
      }
      vA[it] = va;
    }
    #pragma unroll
    for (int it = 0; it < 4; ++it) {           // B (weights): 128 rows
      const int r = srow + it * 32;
      vB[it] = *(const bf8*)(p.W + (size_t)r * p.K + k0 + sch * 8);
    }
  };
  auto writeT = [&]() {
    #pragma unroll
    for (int it = 0; it < 2; ++it) {
      const int r = srow + it * 32;
      *(bf8*)&As[r * 64 + ((sch ^ (r & 7)) << 3)] = vA[it];
    }
    #pragma unroll
    for (int it = 0; it < 4; ++it) {
      const int r = srow + it * 32;
      *(bf8*)&Wsp[r * 64 + ((sch ^ (r & 7)) << 3)] = vB[it];
    }
  };

  loadT(0);
  for (int k0 = 0; k0 < p.K; k0 += 64) {
    __syncthreads();
    writeT();
    if (k0 + 64 < p.K) loadT(k0 + 64);
    __syncthreads();
    #pragma unroll
    for (int ks = 0; ks < 2; ++ks) {
      bf8 af[2], bf[4];
      #pragma unroll
      for (int mf = 0; mf < 2; ++mf) {
        int m = wr * 32 + mf * 16 + l15;
        af[mf] = *(const bf8*)&As[m * 64 + (((ks * 4 + l4) ^ (m & 7)) << 3)];
      }
      #pragma unroll
      for (int nf = 0; nf < 4; ++nf) {
        int n = wc * 64 + nf * 16 + l15;
        bf[nf] = *(const bf8*)&Wsp[n * 64 + (((ks * 4 + l4) ^ (n & 7)) << 3)];
      }
      #pragma unroll
      for (int mf = 0; mf < 2; ++mf)
        #pragma unroll
        for (int nf = 0; nf < 4; ++nf)
          acc[mf][nf] = __builtin_amdgcn_mfma_f32_16x16x32_bf16(af[mf], bf[nf], acc[mf][nf], 0, 0, 0);
    }
  }

  const float bnden = sqrtf(1.0f + 1e-5f);
  #pragma unroll
  for (int mf = 0; mf < 2; ++mf) {
    #pragma unroll
    for (int i = 0; i < 4; ++i) {
      const int rl = wr * 32 + mf * 16 + l4 * 4 + i;
      const int r  = bm + rl;
      #pragma unroll
      for (int nf = 0; nf < 4; ++nf) {
        const int c  = wc * 64 + nf * 16 + l15;
        float v = acc[mf][nf][i];
        if (p.bias) v += p.bias[c];
        if (p.bng)  v = v * (p.bng[c] / bnden) + p.bnb[c];
        if (p.res && r < p.M) v += p.res[(size_t)r * 128 + c];
        if (p.act == 1)      v = fmaxf(v, 0.f);
        else if (p.act == 2) v = (v >= 0.f) ? v : 0.2f * v;
        if (r < p.M) {
          if (p.writeC1) ((u16*)p.C1)[(size_t)r * 128 + c] = f2bf(v);
          if (p.C2f)     p.C2f[(size_t)r * 128 + c] = v;
        }
        const int cl = c & 63;
        T1[wc * 4096 + rl * 64 + (((cl >> 3) ^ (rl & 7)) << 3) + (cl & 7)] = f2bf(v);
      }
    }
  }

  for (int s = 0; s < p.n2; ++s) {
    const S2d q = p.s2[s];
    #pragma unroll
    for (int i = 0; i < 2; ++i)
      #pragma unroll
      for (int j = 0; j < 4; ++j) acc[i][j] = (f4){0.f, 0.f, 0.f, 0.f};
    for (int k0 = 0; k0 < 128; k0 += 64) {
      __syncthreads();
      #pragma unroll
      for (int it = 0; it < 4; ++it) {
        int id = it * 256 + tid;
        int r = id >> 3, ch = id & 7;
        bf8 vb = *(const bf8*)(q.W + (size_t)r * 128 + k0 + ch * 8);
        *(bf8*)&Wsp[r * 64 + ((ch ^ (r & 7)) << 3)] = vb;
      }
      __syncthreads();
      #pragma unroll
      for (int ks = 0; ks < 2; ++ks) {
        bf8 af[2], bf[4];
        #pragma unroll
        for (int mf = 0; mf < 2; ++mf) {
          int m = wr * 32 + mf * 16 + l15;
          af[mf] = *(const bf8*)&T1[(k0 >> 6) * 4096 + m * 64 + (((ks * 4 + l4) ^ (m & 7)) << 3)];
        }
        #pragma unroll
        for (int nf = 0; nf < 4; ++nf) {
          int n = wc * 64 + nf * 16 + l15;
          bf[nf] = *(const bf8*)&Wsp[n * 64 + (((ks * 4 + l4) ^ (n & 7)) << 3)];
        }
        #pragma unroll
        for (int mf = 0; mf < 2; ++mf)
          #pragma unroll
          for (int nf = 0; nf < 4; ++nf)
            acc[mf][nf] = __builtin_amdgcn_mfma_f32_16x16x32_bf16(af[mf], bf[nf], acc[mf][nf], 0, 0, 0);
      }
    }
    #pragma unroll
    for (int mf = 0; mf < 2; ++mf) {
      #pragma unroll
      for (int i = 0; i < 4; ++i) {
        const int rl = wr * 32 + mf * 16 + l4 * 4 + i;
        const int r  = bm + rl;
        if (r >= p.M) continue;
        #pragma unroll
        for (int nf = 0; nf < 4; ++nf) {
          const int c = wc * 64 + nf * 16 + l15;
          float v = acc[mf][nf][i];
          if (q.bias) v += q.bias[c];
          if (q.bng)  v = v * (q.bng[c] / bnden) + q.bnb[c];
          if (q.act == 1)      v = fmaxf(v, 0.f);
          else if (q.act == 2) v = (v >= 0.f) ? v : 0.2f * v;
          if (q.omode == 0) {
            if (q.C) ((float*)q.C)[(size_t)r * 128 + c] = v;
          } else if (q.omode == 1) {
            ((u16*)q.C)[(size_t)r * 128 + c] = f2bf(v);
          } else {
            const int bb = r / HH, rr = r - bb * HH;
            ((u16*)q.C)[((size_t)(bb * 128 + c)) * 2048 + rr] = f2bf(v);
            // deterministically zero padding column 2047 (read by attn, P=0-masked)
            if (rr == HH - 1)
              ((u16*)q.C)[((size_t)(bb * 128 + c)) * 2048 + HH] = (u16)0;
          }
          if (q.Ct) {
            const int bb = r >> 13, rr = r & (NN - 1);
            q.Ct[((size_t)(bb * 128 + c)) * NN + rr] = v;
          }
        }
      }
    }
  }
}

// ======================= bf16-MFMA flash attention, KV-split by blockIdx.z
// QBLK=64, z=2; lazy-max + deferred sum + setprio + T14 register prefetch.
// Writes UNNORMALIZED acc; normalization folded into combA weights.
// NOTE: P-pack uses manual-RNE f2bf (inline-asm cvt_pk corrupted out0, R20).
__global__ __launch_bounds__(256) void attn_mfma_k(
    const u16* __restrict__ thetab,   // (B*N,128) bf16 rm
    const u16* __restrict__ phib,     // (B*H,128) bf16 rm
    const u16* __restrict__ gxT,      // (B,128,2048) bf16 (col 2047 zeroed)
    u16* __restrict__ yp,             // (2, B*N, 128) bf16 partials (unnormalized)
    float2* __restrict__ ml)          // (2, B*N) (m, l)
{
  __shared__ u16 Kt[64 * 128];
  __shared__ u16 Vt[128 * 64];
  __shared__ u16 Pt[64 * 64];
  const int b    = blockIdx.y;
  const int z    = blockIdx.z;
  const int row0 = blockIdx.x * 64;
  const int tid  = threadIdx.x;
  const int wave = tid >> 6;
  const int lane = tid & 63;
  const int l15  = lane & 15, l4 = lane >> 4;

  bf8 aq[4];
  {
    const u16* tq = thetab + ((size_t)(b * NN + row0 + wave * 16 + l15)) * 128;
    #pragma unroll
    for (int ks = 0; ks < 4; ++ks)
      aq[ks] = *(const bf8*)(tq + ks * 32 + l4 * 8);
  }

  f4 acc[8];
  #pragma unroll
  for (int i = 0; i < 8; ++i) acc[i] = (f4){0.f, 0.f, 0.f, 0.f};
  float mrow[4] = {-3e38f, -3e38f, -3e38f, -3e38f};
  float lrow[4] = {0.f, 0.f, 0.f, 0.f};   // per-lane partials

  const u16* phbase = phib + (size_t)b * HH * 128;
  const u16* gxbase = gxT  + (size_t)b * 128 * 2048;

  const int krow = tid >> 4, kch = tid & 15;
  const int vcol = tid >> 3, vch = tid & 7;

  bf8 kreg[4], vreg[4];
  auto loadregs = [&](int h0) {
    #pragma unroll
    for (int it = 0; it < 4; ++it) {
      const int r  = krow + it * 16;
      const int gp = h0 + r;
      bf8 vv = {0,0,0,0,0,0,0,0};
      if (gp < HH) vv = *(const bf8*)(phbase + (size_t)gp * 128 + kch * 8);
      kreg[it] = vv;
    }
    #pragma unroll
    for (int it = 0; it < 4; ++it) {
      const int c = vcol + it * 32;
      vreg[it] = *(const bf8*)(gxbase + (size_t)c * 2048 + h0 + vch * 8);
    }
  };
  auto writeLDS = [&]() {
    #pragma unroll
    for (int it = 0; it < 4; ++it) {
      const int r = krow + it * 16;
      *(bf8*)&Kt[r * 128 + ((kch ^ (r & 7)) << 3)] = kreg[it];
    }
    #pragma unroll
    for (int it = 0; it < 4; ++it) {
      const int c = vcol + it * 32;
      *(bf8*)&Vt[c * 64 + ((vch ^ (c & 7)) << 3)] = vreg[it];
    }
  };

  const int hbeg = z * 1024, hend = hbeg + 1024;
  loadregs(hbeg);
  for (int h0 = hbeg; h0 < hend; h0 += 64) {
    __syncthreads();
    writeLDS();
    if (h0 + 64 < hend) loadregs(h0 + 64);
    __syncthreads();

    f4 sacc[4];
    #pragma unroll
    for (int t = 0; t < 4; ++t) sacc[t] = (f4){0.f, 0.f, 0.f, 0.f};
    __builtin_amdgcn_s_setprio(1);
    #pragma unroll
    for (int ks = 0; ks < 4; ++ks) {
      #pragma unroll
      for (int t = 0; t < 4; ++t) {
        const int pr = t * 16 + l15;
        const int ch = (ks * 4 + l4) ^ (pr & 7);
        bf8 bk = *(const bf8*)&Kt[pr * 128 + ch * 8];
        sacc[t] = __builtin_amdgcn_mfma_f32_16x16x32_bf16(aq[ks], bk, sacc[t], 0, 0, 0);
      }
    }
    __builtin_amdgcn_s_setprio(0);
    if (h0 + 64 > HH) {
      #pragma unroll
      for (int t = 0; t < 4; ++t)
        if (h0 + t * 16 + l15 >= HH)
          sacc[t] = (f4){-3e38f, -3e38f, -3e38f, -3e38f};
    }

    // ---- lazy max
    float tl[4];
    #pragma unroll
    for (int r = 0; r < 4; ++r)
      tl[r] = fmaxf(fmaxf(sacc[0][r], sacc[1][r]), fmaxf(sacc[2][r], sacc[3][r]));
    const bool grow = (tl[0] > mrow[0]) | (tl[1] > mrow[1]) |
                      (tl[2] > mrow[2]) | (tl[3] > mrow[3]);
    if (__any(grow)) {
      #pragma unroll
      for (int r = 0; r < 4; ++r) {
        float tm = tl[r];
        tm = fmaxf(tm, __shfl_xor(tm, 1));
        tm = fmaxf(tm, __shfl_xor(tm, 2));
        tm = fmaxf(tm, __shfl_xor(tm, 4));
        tm = fmaxf(tm, __shfl_xor(tm, 8));
        const float mn = fmaxf(mrow[r], tm);
        const float sc = __expf(mrow[r] - mn);
        mrow[r] = mn;
        lrow[r] *= sc;
        #pragma unroll
        for (int ct = 0; ct < 8; ++ct) acc[ct][r] *= sc;
      }
    }
    // ---- exp + per-lane partial sum + P write (manual RNE pack)
    #pragma unroll
    for (int r = 0; r < 4; ++r) {
      float e[4];
      float ps = 0.f;
      #pragma unroll
      for (int t = 0; t < 4; ++t) {
        e[t] = __expf(sacc[t][r] - mrow[r]);
        ps += e[t];
      }
      lrow[r] += ps;
      const int prow = wave * 16 + l4 * 4 + r;
      #pragma unroll
      for (int t = 0; t < 4; ++t) {
        const int col = t * 16 + l15;
        const int scol = (((col >> 3) ^ (prow & 7)) << 3) | (col & 7);
        Pt[prow * 64 + scol] = f2bf(e[t]);
      }
    }

    __builtin_amdgcn_s_setprio(1);
    #pragma unroll
    for (int ks = 0; ks < 2; ++ks) {
      const int prow2 = wave * 16 + l15;
      bf8 pa = *(const bf8*)&Pt[prow2 * 64 + (((ks * 4 + l4) ^ (prow2 & 7)) << 3)];
      #pragma unroll
      for (int ct = 0; ct < 8; ++ct) {
        const int c  = ct * 16 + l15;
        const int ch = (ks * 4 + l4) ^ (c & 7);
        bf8 bv = *(const bf8*)&Vt[c * 64 + ch * 8];
        acc[ct] = __builtin_amdgcn_mfma_f32_16x16x32_bf16(pa, bv, acc[ct], 0, 0, 0);
      }
    }
    __builtin_amdgcn_s_setprio(0);
  }

  // final sum reduce (once) -- l needed for the combine denominator
  #pragma unroll
  for (int r = 0; r < 4; ++r) {
    float lr = lrow[r];
    lr += __shfl_xor(lr, 1); lr += __shfl_xor(lr, 2);
    lr += __shfl_xor(lr, 4); lr += __shfl_xor(lr, 8);
    lrow[r] = lr;
  }

  const size_t rbase = (size_t)z * BB * NN + (size_t)b * NN + row0 + wave * 16 + l4 * 4;
  u16* yo = yp + rbase * 128;
  #pragma unroll
  for (int r = 0; r < 4; ++r) {
    #pragma unroll
    for (int ct = 0; ct < 8; ++ct)
      yo[(size_t)r * 128 + ct * 16 + l15] = f2bf(acc[ct][r]);
    if (l15 == 0) ml[rbase + r] = make_float2(mrow[r], lrow[r]);
  }
}

// ======================= diff[b,n] = sum_k sum_c (flat[idx1]-xt)^2
// 8 points per 256-thread block; 32 lanes/point; uint2 (8B) loads.
__global__ __launch_bounds__(256) void diff_k(const u16* __restrict__ xtb,
                                              const int* __restrict__ idx1,
                                              float* __restrict__ diff) {
  const int tid = threadIdx.x;
  const int sub = tid >> 5, ln = tid & 31;
  const int bn  = blockIdx.x * 8 + sub;
  const uint2 xcp = *(const uint2*)(xtb + (size_t)bn * CO + ln * 4);
  const float x0 = bf2f((u16)(xcp.x & 0xFFFFu)), x1 = bf2f((u16)(xcp.x >> 16));
  const float x2 = bf2f((u16)(xcp.y & 0xFFFFu)), x3 = bf2f((u16)(xcp.y >> 16));
  const int* id = idx1 + (size_t)bn * KNB;
  float acc = 0.f;
  #pragma unroll 4
  for (int k = 0; k < KNB; ++k) {
    const int ix = id[k];
    const uint2 vp = *(const uint2*)(xtb + (size_t)ix * CO + ln * 4);
    const float d0 = bf2f((u16)(vp.x & 0xFFFFu)) - x0;
    const float d1 = bf2f((u16)(vp.x >> 16))     - x1;
    const float d2 = bf2f((u16)(vp.y & 0xFFFFu)) - x2;
    const float d3 = bf2f((u16)(vp.y >> 16))     - x3;
    acc += d0*d0 + d1*d1 + d2*d2 + d3*d3;
  }
  #pragma unroll
  for (int o = 1; o <= 16; o <<= 1) acc += __shfl_xor(acc, o);
  if (ln == 0) diff[bn] = acc;
}

// ======================= per-batch top-1638 SET via 4-round radix select
// DETERMINISTIC placement: prefix-scan positions (replay-invariant Hidx order).
__global__ __launch_bounds__(1024) void topsel_k(const float* __restrict__ diff,
                                                 InnerArgs ia,
                                                 int* __restrict__ Hidx) {
  __shared__ uint32_t hist[256];
  __shared__ uint32_t sh_T, sh_need, sh_eqc;
  __shared__ int      sh_eq[1024];
  __shared__ uint32_t scn[1024];
  const int b = blockIdx.x, tid = threadIdx.x;
  const float* db = diff + (size_t)b * NN;
  uint32_t v[8];
  #pragma unroll
  for (int i = 0; i < 8; ++i) v[i] = __float_as_uint(db[tid * 8 + i]);
  if (tid == 0) { sh_T = 0u; sh_need = OUTER; sh_eqc = 0u; }
  #pragma unroll
  for (int round = 0; round < 4; ++round) {
    const int shift = 24 - 8 * round;
    for (int i = tid; i < 256; i += 1024) hist[i] = 0u;
    __syncthreads();
    const uint32_t Tpart  = sh_T;
    const uint32_t maskHi = (round == 0) ? 0u : (0xFFFFFFFFu << (shift + 8));
    #pragma unroll
    for (int i = 0; i < 8; ++i)
      if ((v[i] & maskHi) == (Tpart & maskHi))
        atomicAdd(&hist[(v[i] >> shift) & 255u], 1u);
    __syncthreads();
    if (tid == 0) {
      uint32_t need = sh_need, accn = 0u;
      int bsel = 0;
      for (int bin = 255; bin >= 0; --bin) {
        uint32_t h = hist[bin];
        if (accn + h >= need) { bsel = bin; break; }
        accn += h;
      }
      sh_T = Tpart | ((uint32_t)bsel << shift);
      sh_need = need - accn;
    }
    __syncthreads();
  }
  const uint32_t T   = sh_T;
  const uint32_t rem = sh_need;

  // deterministic exclusive scan of per-thread ">" counts
  uint32_t cnt = 0;
  #pragma unroll
  for (int i = 0; i < 8; ++i) cnt += (v[i] > T) ? 1u : 0u;
  scn[tid] = cnt;
  __syncthreads();
  for (int off = 1; off < 1024; off <<= 1) {
    uint32_t t = (tid >= off) ? scn[tid - off] : 0u;
    __syncthreads();
    scn[tid] += t;
    __syncthreads();
  }
  uint32_t pos = scn[tid] - cnt;   // exclusive prefix (index-ordered placement)
  #pragma unroll
  for (int i = 0; i < 8; ++i) {
    const int idx = tid * 8 + i;
    if (v[i] > T) {
      Hidx[b * HH + (int)(pos++)] = idx;
    } else if (v[i] == T) {
      uint32_t e = atomicAdd(&sh_eqc, 1u);
      if (e < 1024u) sh_eq[e] = idx;
    }
  }
  __syncthreads();
  if (tid == 0) {
    const uint32_t C = OUTER - rem;          // #(v > T) is exactly OUTER - rem
    uint32_t eqc = sh_eqc < 1024u ? sh_eqc : 1024u;
    for (uint32_t j = 0; j < rem && j < eqc; ++j) {
      int best = 0x7fffffff, bi = 0;
      for (uint32_t t = 0; t < eqc; ++t)
        if (sh_eq[t] < best) { best = sh_eq[t]; bi = (int)t; }
      Hidx[b * HH + C + j] = best;
      sh_eq[bi] = 0x7fffffff;
    }
  }
  if (tid < INNER) Hidx[b * HH + OUTER + tid] = ia.v[tid];
}

// ======================= fused tail: h5 + logits + log_softmax
__global__ __launch_bounds__(256) void tail_k(const float* __restrict__ npo,
                                              const float* __restrict__ w5,
                                              const float* __restrict__ b5,
                                              const float* __restrict__ g5,
                                              const float* __restrict__ be5,
                                              const float* __restrict__ w6,
                                              const float* __restrict__ b6,
                                              float* __restrict__ out1) {
  __shared__ float W5s[32 * 128];
  __shared__ float H5s[64 * 33];
  __shared__ float W6s[CLS * 32];
  const int tid  = threadIdx.x;
  const int row0 = blockIdx.x * 64;
  for (int i = tid; i < 32 * 128; i += 256) W5s[i] = w5[i];
  for (int i = tid; i < CLS * 32; i += 256) W6s[i] = w6[i];
  __syncthreads();

  const float bnden = sqrtf(1.0f + 1e-5f);
  const int r  = tid >> 2;
  const int jg = (tid & 3) * 8;
  const float* xr = npo + (size_t)(row0 + r) * 128;
  float a[8] = {0.f,0.f,0.f,0.f,0.f,0.f,0.f,0.f};
  for (int c4 = 0; c4 < 128; c4 += 4) {
    const float4 x = *(const float4*)&xr[c4];
    #pragma unroll
    for (int jj = 0; jj < 8; ++jj) {
      const float4 w = *(const float4*)&W5s[(jg + jj) * 128 + c4];
      a[jj] += x.x*w.x + x.y*w.y + x.z*w.z + x.w*w.w;
    }
  }
  #pragma unroll
  for (int jj = 0; jj < 8; ++jj) {
    const int j = jg + jj;
    float v = a[jj] + b5[j];
    v = v * (g5[j] / bnden) + be5[j];
    H5s[r * 33 + j] = fmaxf(v, 0.f);
  }
  __syncthreads();

  if (tid < 64) {
    float h[32];
    #pragma unroll
    for (int j = 0; j < 32; ++j) h[j] = H5s[tid * 33 + j];
    float lg[CLS];
    float m = -3.4e38f;
    #pragma unroll
    for (int o = 0; o < CLS; ++o) {
      float s = b6[o];
      #pragma unroll
      for (int j = 0; j < 32; ++j) s += W6s[o * 32 + j] * h[j];
      lg[o] = s;
      m = fmaxf(m, s);
    }
    float se = 0.f;
    #pragma unroll
    for (int o = 0; o < CLS; ++o) se += __expf(lg[o] - m);
    const float lse = m + __logf(se);
    float* orow = out1 + (size_t)(row0 + tid) * CLS;
    #pragma unroll
    for (int o = 0; o < CLS; ++o) orow[o] = lg[o] - lse;
  }
}

} // anonymous namespace

// ===========================================================================
extern "C" void kernel_launch(void* const* d_in, const int* in_sizes, int n_in,
                              void* d_out, int out_size, void* d_ws, size_t ws_size,
                              hipStream_t stream) {
  const float* xyz1    = (const float*)d_in[0];
  const float* xyz2    = (const float*)d_in[1];
  const float* points1 = (const float*)d_in[2];
  const float* points2 = (const float*)d_in[3];
  const float* lastpred= (const float*)d_in[5];
  const float* w_mlp0  = (const float*)d_in[6];
  const float* b_mlp0  = (const float*)d_in[7];
  const float* g_bn0   = (const float*)d_in[8];
  const float* be_bn0  = (const float*)d_in[9];
  const float* w_mlp1  = (const float*)d_in[10];
  const float* b_mlp1  = (const float*)d_in[11];
  const float* g_bn1   = (const float*)d_in[12];
  const float* be_bn1  = (const float*)d_in[13];
  const float* w_h     = (const float*)d_in[14];
  const float* g_hbn   = (const float*)d_in[15];
  const float* be_hbn  = (const float*)d_in[16];
  const float* w_outm  = (const float*)d_in[17];
  const float* g_obn   = (const float*)d_in[18];
  const float* be_obn  = (const float*)d_in[19];
  const float* w_g     = (const float*)d_in[20];
  const float* b_g     = (const float*)d_in[21];
  const float* w_theta = (const float*)d_in[22];
  const float* b_theta = (const float*)d_in[23];
  const float* w_phi   = (const float*)d_in[24];
  const float* b_phi   = (const float*)d_in[25];
  const float* w_W     = (const float*)d_in[26];
  const float* b_W     = (const float*)d_in[27];
  const float* g_Wbn   = (const float*)d_in[28];
  const float* be_Wbn  = (const float*)d_in[29];
  const float* w5      = (const float*)d_in[30];
  const float* b5      = (const float*)d_in[31];
  const float* g_bn5   = (const float*)d_in[32];
  const float* be_bn5  = (const float*)d_in[33];
  const float* w6      = (const float*)d_in[34];
  const float* b6      = (const float*)d_in[35];
  const int*   idx_1   = (const int*)d_in[36];

  float* out0 = (float*)d_out;
  float* out1 = out0 + (size_t)BB * CO * NN;

  char* base = (char*)d_ws;
  size_t off = 0;
  auto alloc = [&](size_t bytes) -> char* {
    char* p = base + off;
    off += (bytes + 255) & ~(size_t)255;
    return p;
  };
  float* diff   = (float*)alloc((size_t)BB * NN * 4);
  int*   Hidx   = (int*)  alloc((size_t)BB * HH * 4);
  float* preds  = (float*)alloc((size_t)BB * NN * CLS * 4);
  float* xt     = (float*)alloc((size_t)BB * NN * CO * 4);
  u16*   xtb    = (u16*)  alloc((size_t)BB * NN * CO * 2);
  u16*   phib   = (u16*)  alloc((size_t)BB * HH * CO * 2);
  u16*   gxT    = (u16*)  alloc((size_t)BB * CO * 2048 * 2);
  float2* mlbuf = (float2*)alloc((size_t)2 * BB * NN * 8);
  u16*   wbuf   = (u16*)  alloc((size_t)270336 * 2);
  char*  R1     =         alloc((size_t)BB * NN * 512 * 2);     // 33.5MB
  char*  R2     =         alloc((size_t)BB * NN * 256 * 2);     // 16MB
  if (off > ws_size) return;   // insufficient scratch (diagnostic)

  // weight bf16 buffers inside wbuf
  u16* w0b = wbuf;                 // 256x512
  u16* w1b = w0b + 256 * 512;      // 128x256
  u16* whb = w1b + 128 * 256;      // 128x192 (149 padded)
  u16* wgb = whb + 128 * 192;      // 128x128
  u16* wtb = wgb + 128 * 128;
  u16* wpb = wtb + 128 * 128;
  u16* wWb = wpb + 128 * 128;
  u16* wob = wWb + 128 * 128;

  // region aliases (lifetimes disjoint)
  u16*   A0     = (u16*)R1;                                     // prep..mlp0
  u16*   thetab = (u16*)R1;                                     // mlp1..attn (8MB)
  u16*   yp     = (u16*)(R1 + (size_t)8 * 1024 * 1024);         // attn..Wgemm (16MB)
  float* p2t    = (float*)R2;                                   // prep..knn_interp (8MB)
  u16*   x2b    = (u16*)R2;                                     // mlp0..mlp1 (16MB)
  float* npo    = (float*)R2;                                   // Wgemm..tail (16MB)

  // host RNG for inner indices (baked into topsel kernargs)
  InnerArgs ia;
  compute_inner_host(ia.v);

  // 1. merged prep: points2 transpose + points1 cvt + weight cvt
  {
    WcvAll wa;
    wa.e[0] = {w_mlp0, w0b, 256, 512, 512};
    wa.e[1] = {w_mlp1, w1b, 128, 256, 256};
    wa.e[2] = {w_h,    whb, 128, 149, 192};
    wa.e[3] = {w_g,    wgb, 128, 128, 128};
    wa.e[4] = {w_theta,wtb, 128, 128, 128};
    wa.e[5] = {w_phi,  wpb, 128, 128, 128};
    wa.e[6] = {w_W,    wWb, 128, 128, 128};
    wa.e[7] = {w_outm, wob, 128, 128, 128};
    prep1_k<<<6400, 256, 0, stream>>>(points2, p2t, points1, A0, wa);
  }

  // 2. fused 3-NN + interpolation -> A0 cols 256..511 (bf16) + preds f32
  knn_interp_k<<<dim3(NN/16, BB), 256, 0, stream>>>(xyz1, xyz2, p2t, lastpred, A0, preds);

  // 3. mlp0: relu(bn0(W0·A0 + b0)) -> x2b bf16
  {
    MgP p{};
    p.A = A0; p.W = w0b; p.bias = b_mlp0; p.bng = g_bn0; p.bnb = be_bn0;
    p.C = x2b; p.M = BB * NN; p.Nc = 256; p.K = 512; p.act = 1; p.omode = 1;
    mgemm_k<<<dim3(2, 256), 256, 0, stream>>>(p);
  }
  // 4. mlp1 (-> xtb bf16 + xt f32) fused with theta -> thetab   [TF=0, 64-row tiles]
  {
    Mg2P p{};
    p.A = x2b; p.W = w1b; p.bias = b_mlp1; p.bng = g_bn1; p.bnb = be_bn1;
    p.C1 = xtb; p.writeC1 = 1; p.C2f = xt;
    p.M = BB * NN; p.K = 256; p.act = 1; p.n2 = 1;
    p.s2[0] = {wtb, b_theta, nullptr, nullptr, 0, 1, thetab, nullptr};
    mgemm2_k<0><<<dim3(1, 512), 256, 0, stream>>>(p);
  }

  // 5. KNN feature variance score (8 pts/block, 8B loads)
  diff_k<<<BB * NN / 8, 256, 0, stream>>>(xtb, idx_1, diff);

  // 6. per-batch top-1638 set via deterministic radix select
  topsel_k<<<BB, 1024, 0, stream>>>(diff, ia, Hidx);

  // 7. conv_h (A gathered via Hidx) fused with g_x and phi [TF=0, 64-row tiles]
  {
    Mg2P p{};
    p.W = whb; p.bng = g_hbn; p.bnb = be_hbn;
    p.gxtb = xtb; p.gpreds = preds; p.gHidx = Hidx; p.gatherA = 1;
    p.writeC1 = 0; p.M = BB * HH; p.K = 192; p.act = 2; p.n2 = 2;
    p.s2[0] = {wgb, b_g,   nullptr, nullptr, 0, 2, gxT,  nullptr};
    p.s2[1] = {wpb, b_phi, nullptr, nullptr, 0, 1, phib, nullptr};
    mgemm2_k<0><<<dim3(1, 128), 256, 0, stream>>>(p);
  }

  // 8. MFMA flash attention, KV-split x2 -> unnormalized partials
  attn_mfma_k<<<dim3(NN/64, BB, 2), 256, 0, stream>>>(thetab, phib, gxT, yp, mlbuf);

  // 9. combine(yp) -> z = bn_W(W_W·y + b_W) + xt, fused with outm;
  // stage-2 writes npo f32 (for tail) AND out0 transposed. [TF=1, 64-row tiles]
  {
    Mg2P p{};
    p.W = wWb; p.bias = b_W; p.bng = g_Wbn; p.bnb = be_Wbn; p.res = xt;
    p.ypA = yp; p.mlA = mlbuf; p.combA = 1;
    p.writeC1 = 0; p.M = BB * NN; p.K = 128; p.act = 0; p.n2 = 1;
    p.s2[0] = {wob, nullptr, g_obn, be_obn, 2, 0, npo, out0};
    mgemm2_k<1><<<dim3(1, 512), 256, 0, stream>>>(p);
  }

  // 10. fused tail: h5 + logits + log_softmax -> out1
  tail_k<<<BB * NN / 64, 256, 0, stream>>>(npo, w5, b5, g_bn5, be_bn5, w6, b6, out1);
}